// Round 1
// 2894.056 us; speedup vs baseline: 1.2853x; 1.2853x over previous
//
#include <hip/hip_runtime.h>
#include <hip/hip_bf16.h>
#include <cfloat>

using bf16 = __hip_bfloat16;

typedef short short8 __attribute__((ext_vector_type(8)));
typedef float floatx16 __attribute__((ext_vector_type(16)));
union Frag { short8 v; uint2 u2[2]; };
union FragQ { short8 v; uint4 q; uint2 u2[2]; };
union U4b { uint4 q; unsigned short s[8]; };

constexpr int Bb = 8, Nn = 4096, Kk = 20;
constexpr int BN = Bb * Nn;                     // 32768
constexpr int Mrows = BN * Kk;                  // 655360
constexpr float EPSf = 1e-5f;

static __device__ __forceinline__ float b2f(bf16 v){ return __bfloat162float(v); }
static __device__ __forceinline__ bf16 f2b(float v){ return __float2bfloat16(v); }
static __device__ __forceinline__ unsigned short f2bu(float v){
  union { bf16 b; unsigned short u; } cv; cv.b = __float2bfloat16(v); return cv.u;
}
static __device__ __forceinline__ float bits2f(unsigned short u){
  union { unsigned int i; float f; } c; c.i = ((unsigned)u)<<16; return c.f;
}
static __device__ __forceinline__ float ldf(bf16 v){ return b2f(v); }
static __device__ __forceinline__ float ldf(float v){ return v; }
// granule XOR swizzles (float4 granules): conflict-free strided b128 access
static __device__ __forceinline__ int sw4(int g){ return g ^ (g >> 3); }   // 32 granules
static __device__ __forceinline__ int sw6(int g){ return g ^ (g >> 3); }   // 64 granules

// ---------------- zero workspace region ----------------
__global__ void zero_kernel(float* __restrict__ p, int n){
  int i = blockIdx.x*256 + threadIdx.x;
  if (i < n) p[i] = 0.f;
}

// ---------------- W3^T bf16 pack (for MFMA produce in stats4) ----------------
__global__ void w3t_kernel(const float* __restrict__ W3f, bf16* __restrict__ W3T){
  int id = blockIdx.x*256 + threadIdx.x;   // 128*64 = 8192 elems
  if (id >= 128*64) return;
  int n = id >> 6, k = id & 63;
  W3T[id] = f2b(W3f[(size_t)k*128 + n]);
}

// ---------------- KNN phase A ----------------
__global__ __launch_bounds__(256) void knnA_kernel(const float* __restrict__ x,
                                                   float* __restrict__ pv, int* __restrict__ pi){
#pragma clang fp contract(off)
  __shared__ float4 p4[1024];
  int blk = blockIdx.x;
  int stripe = blk & 3;
  int chunk  = (blk >> 2) & 15;
  int b      = blk >> 6;
  const float* xb = x + b*3*Nn;
  int j0 = stripe*1024;
  for (int u = threadIdx.x; u < 1024; u += 256){
    int j = j0 + u;
    float a0 = xb[j];
    float a1 = xb[Nn + j];
    float a2 = xb[2*Nn + j];
    float s = a0*a0; s = s + a1*a1; s = s + a2*a2;
    p4[u] = make_float4(a0, a1, a2, s);
  }
  __syncthreads();
  int i = chunk*256 + threadIdx.x;
  float xi = xb[i], yi = xb[Nn+i], zi = xb[2*Nn+i];
  float ni = xi*xi; ni = ni + yi*yi; ni = ni + zi*zi;
  float mni = -ni;
  float tv[Kk]; int ti[Kk];
  #pragma unroll
  for (int s=0;s<Kk;++s){ tv[s] = -FLT_MAX; ti[s] = 0; }
  for (int u=0; u<1024; ++u){
    float4 p = p4[u];
    float dot = xi*p.x; dot = dot + yi*p.y; dot = dot + zi*p.z;
    float inner = -2.0f*dot;
    float nd = mni - inner; nd = nd - p.w;
    if (nd > tv[Kk-1]){
      #pragma unroll
      for (int s=Kk-1; s>=1; --s){
        bool cs = nd > tv[s];
        bool cp = nd > tv[s-1];
        tv[s] = cs ? (cp ? tv[s-1] : nd) : tv[s];
        ti[s] = cs ? (cp ? ti[s-1] : (j0+u)) : ti[s];
      }
      if (nd > tv[0]){ tv[0] = nd; ti[0] = j0+u; }
    }
  }
  long long base = ((long long)(b*Nn + i)*4 + stripe)*Kk;
  #pragma unroll
  for (int s=0;s<Kk;++s){ pv[base+s] = tv[s]; pi[base+s] = ti[s]; }
}

// ---------------- KNN phase B ----------------
__global__ __launch_bounds__(256) void knnB_kernel(const float* __restrict__ pv,
                                                   const int* __restrict__ pi,
                                                   int* __restrict__ idx){
  int p = blockIdx.x*256 + threadIdx.x;
  if (p >= BN) return;
  long long base = (long long)p*4*Kk;
  float av[Kk]; int ai[Kk];
  #pragma unroll
  for (int s=0;s<Kk;++s){ av[s]=pv[base+s]; ai[s]=pi[base+s]; }
  for (int t=Kk; t<4*Kk; ++t){
    float nd = pv[base+t]; int j = pi[base+t];
    if (nd > av[Kk-1]){
      #pragma unroll
      for (int s=Kk-1;s>=1;--s){
        bool cs = nd > av[s];
        bool cp = nd > av[s-1];
        av[s] = cs ? (cp?av[s-1]:nd) : av[s];
        ai[s] = cs ? (cp?ai[s-1]:j) : ai[s];
      }
      if (nd > av[0]){ av[0]=nd; ai[0]=j; }
    }
  }
  #pragma unroll
  for (int s=0;s<Kk;++s) idx[(long long)p*Kk+s] = ai[s];
}

// ---------------- layer-1 feature stats ----------------
__global__ __launch_bounds__(256) void gramf_kernel(const float* __restrict__ x,
                                                    const int* __restrict__ idx,
                                                    float* __restrict__ part){
  float acc[36]; float s6[6];
  #pragma unroll
  for (int a=0;a<36;++a) acc[a]=0.f;
  #pragma unroll
  for (int a=0;a<6;++a) s6[a]=0.f;
  for (long long row = blockIdx.x*256 + threadIdx.x; row < Mrows; row += (long long)gridDim.x*256){
    int bn = (int)(row / Kk);
    int b = bn >> 12, n = bn & 4095;
    int j = idx[row];
    const float* xb = x + b*3*Nn;
    float f[6];
    f[0]=xb[j];  f[1]=xb[Nn+j];  f[2]=xb[2*Nn+j];
    f[3]=xb[n];  f[4]=xb[Nn+n];  f[5]=xb[2*Nn+n];
    #pragma unroll
    for (int a=0;a<6;++a){
      s6[a] += f[a];
      #pragma unroll
      for (int c=0;c<6;++c) acc[a*6+c] = fmaf(f[a], f[c], acc[a*6+c]);
    }
  }
  __shared__ float red[256];
  for (int v=0; v<42; ++v){
    red[threadIdx.x] = (v<36)? acc[v] : s6[v-36];
    __syncthreads();
    for (int s=128; s>0; s>>=1){
      if (threadIdx.x < s) red[threadIdx.x] += red[threadIdx.x+s];
      __syncthreads();
    }
    if (threadIdx.x==0) part[blockIdx.x*48 + v] = red[0];
    __syncthreads();
  }
}

__global__ void reducef_kernel(const float* __restrict__ part, float* __restrict__ Gf,
                               float* __restrict__ sumf){
  int t = threadIdx.x;
  if (t < 42){
    float s = 0.f;
    for (int i=0;i<256;++i) s += part[i*48 + t];
    if (t<36) Gf[t]=s; else sumf[t-36]=s;
  }
}

// ---------------- MFMA Gram: G = H^T H over bf16 H ----------------
template<int CIN>
__global__ __launch_bounds__(256) void gramM_kernel(const bf16* __restrict__ H, int M,
                                                    float* __restrict__ G){
  constexpr int Tt = CIN/64;
  int tile = blockIdx.x % (Tt*Tt);
  int chunk = blockIdx.x / (Tt*Tt);
  int nchunks = gridDim.x / (Tt*Tt);
  int tr = tile / Tt, tc = tile % Tt;
  bool diag = (tr == tc);
  __shared__ short HTa[64*68];
  __shared__ short HTb[64*68];
  int rpc = M / nchunks;
  int r0 = chunk*rpc;
  int tid = threadIdx.x, lane = tid & 63, w = tid >> 6;
  int mt = w >> 1, nt = w & 1;
  floatx16 acc;
  #pragma unroll
  for (int q=0;q<16;++q) acc[q]=0.f;
  const short* Bbase = diag ? HTa : HTb;
  int arow = (mt*32 + (lane&31))*68;
  int brow = (nt*32 + (lane&31))*68;
  int ko = (lane>>5)*8;
  for (int rb=r0; rb<r0+rpc; rb+=64){
    #pragma unroll
    for (int s=0;s<2;++s){
      int e = tid + s*256;
      int row = e >> 3, c0 = (e & 7)*8;
      U4b va; va.q = *(const uint4*)&H[(size_t)(rb+row)*CIN + tr*64 + c0];
      #pragma unroll
      for (int j=0;j<8;++j) HTa[(c0+j)*68 + row] = (short)va.s[j];
      if (!diag){
        U4b vb; vb.q = *(const uint4*)&H[(size_t)(rb+row)*CIN + tc*64 + c0];
        #pragma unroll
        for (int j=0;j<8;++j) HTb[(c0+j)*68 + row] = (short)vb.s[j];
      }
    }
    __syncthreads();
    #pragma unroll
    for (int kc=0;kc<64;kc+=16){
      Frag a, b;
      const short* ap = &HTa[arow + kc + ko];
      const short* bp = &Bbase[brow + kc + ko];
      a.u2[0] = *(const uint2*)ap;  a.u2[1] = *(const uint2*)(ap+4);
      b.u2[0] = *(const uint2*)bp;  b.u2[1] = *(const uint2*)(bp+4);
      acc = __builtin_amdgcn_mfma_f32_32x32x16_bf16(a.v, b.v, acc, 0, 0, 0);
    }
    __syncthreads();
  }
  int col = lane & 31, rbase = 4*(lane>>5);
  #pragma unroll
  for (int r=0;r<16;++r){
    int row = (r&3) + 8*(r>>2) + rbase;
    atomicAdd(&G[(size_t)(tr*64 + mt*32 + row)*CIN + tc*64 + nt*32 + col], acc[r]);
  }
}

// ---------------- column sums of H ----------------
template<int CIN, typename T>
__global__ __launch_bounds__(256) void colsum_kernel(const T* __restrict__ H, int M,
                                                     float* __restrict__ sumh){
  int rpb = (M + gridDim.x - 1)/gridDim.x;
  int r0 = blockIdx.x*rpb, r1 = min(M, r0+rpb);
  if constexpr (CIN <= 256){
    constexpr int RP = 256/CIN;
    int c = threadIdx.x % CIN;
    int sub = threadIdx.x / CIN;
    float a = 0.f;
    for (int r=r0+sub; r<r1; r+=RP) a += ldf(H[(size_t)r*CIN + c]);
    atomicAdd(&sumh[c], a);
  } else {
    float a0=0.f, a1=0.f;
    for (int r=r0;r<r1;++r){
      a0 += ldf(H[(size_t)r*CIN + threadIdx.x]);
      a1 += ldf(H[(size_t)r*CIN + threadIdx.x + 256]);
    }
    atomicAdd(&sumh[threadIdx.x], a0);
    atomicAdd(&sumh[threadIdx.x+256], a1);
  }
}

// ---------------- P = G @ W ----------------
__global__ void kP_kernel(const float* __restrict__ G, const float* __restrict__ Wf,
                          float* __restrict__ P, int Cin, int Cout){
  int id = blockIdx.x*256 + threadIdx.x;
  if (id >= Cin*Cout) return;
  int i = id / Cout, j = id - i*Cout;
  float s = 0.f;
  for (int k=0;k<Cin;++k) s = fmaf(G[(size_t)i*Cin+k], Wf[(size_t)k*Cout+j], s);
  P[id] = s;
}

// ---------------- scale/shift from Gram-derived BN stats ----------------
__global__ void kFinal_kernel(const float* __restrict__ P, const float* __restrict__ sumh,
                              const float* __restrict__ Wf, const float* __restrict__ g,
                              const float* __restrict__ bb, float* __restrict__ scale,
                              float* __restrict__ shift, int Cin, int Cout, float invM){
  int j = blockIdx.x*256 + threadIdx.x;
  if (j >= Cout) return;
  float mean=0.f, e2=0.f;
  for (int i=0;i<Cin;++i){
    float w = Wf[(size_t)i*Cout + j];
    mean = fmaf(sumh[i], w, mean);
    e2   = fmaf(w, P[(size_t)i*Cout + j], e2);
  }
  mean *= invM; e2 *= invM;
  float var = e2 - mean*mean;
  float inv = rsqrtf(var + EPSf);
  float sc = g[j]*inv;
  scale[j]=sc;
  shift[j]=bb[j] - mean*sc;
}

// ---------------- layer-2 stats: fp32 H1 produce + bf16 MFMA Gram + fused colsum ----------------
__global__ __launch_bounds__(512) void stats2_kernel(const float* __restrict__ x,
    const int* __restrict__ idx, const float* __restrict__ W1f,
    const float* __restrict__ sc1v, const float* __restrict__ sh1v,
    float* __restrict__ G2, float* __restrict__ sum2){
  __shared__ float W1s[6][64];
  __shared__ float fsh[64][8];
  __shared__ short H1T[64*68];
  __shared__ float csum[64];
  int tid = threadIdx.x, lane = tid & 63, w = tid >> 6;   // 8 waves
  if (tid < 384) W1s[tid>>6][tid&63] = W1f[tid];
  if (tid < 64) csum[tid] = 0.f;
  // produce mapping: row-pair rp (2 rows) x 16 colgroups (4 cols)
  int rp = tid >> 4, cq = tid & 15, c0 = cq*4;
  float sca[4], sha[4];
  #pragma unroll
  for (int k=0;k<4;++k){ sca[k]=sc1v[c0+k]; sha[k]=sh1v[c0+k]; }
  // MFMA mapping: 2x2 tiles x 2 k-halves
  int mt = w & 1, nt = (w>>1) & 1, kh = w >> 2;
  int arow = (mt*32 + (lane&31))*68;
  int brow = (nt*32 + (lane&31))*68;
  int ko = (lane>>5)*8;
  floatx16 acc;
  #pragma unroll
  for (int q=0;q<16;++q) acc[q]=0.f;
  float cs[4] = {0.f,0.f,0.f,0.f};
  int rpc = Mrows / gridDim.x;
  int r0 = blockIdx.x * rpc;
  __syncthreads();
  for (int rb=r0; rb<r0+rpc; rb+=64){
    {
      int r = tid>>3, e = tid&7;
      if (e < 6){
        int grow = rb + r;
        int bn = grow / Kk;
        int b = bn >> 12, n = bn & 4095;
        int j = idx[grow];
        const float* xb = x + b*3*Nn;
        fsh[r][e] = (e<3) ? xb[e*Nn + j] : xb[(e-3)*Nn + n];
      }
    }
    __syncthreads();
    {
      float y0[4]={0,0,0,0}, y1[4]={0,0,0,0};
      int ra = rp*2, rbw = rp*2+1;
      #pragma unroll
      for (int i=0;i<6;++i){
        float fa = fsh[ra][i], fb = fsh[rbw][i];
        float4 wv = *(const float4*)&W1s[i][c0];
        y0[0]=fmaf(fa,wv.x,y0[0]); y0[1]=fmaf(fa,wv.y,y0[1]);
        y0[2]=fmaf(fa,wv.z,y0[2]); y0[3]=fmaf(fa,wv.w,y0[3]);
        y1[0]=fmaf(fb,wv.x,y1[0]); y1[1]=fmaf(fb,wv.y,y1[1]);
        y1[2]=fmaf(fb,wv.z,y1[2]); y1[3]=fmaf(fb,wv.w,y1[3]);
      }
      #pragma unroll
      for (int k=0;k<4;++k){
        float va = fmaxf(fmaf(y0[k],sca[k],sha[k]),0.f);
        float vb = fmaxf(fmaf(y1[k],sca[k],sha[k]),0.f);
        cs[k] += va; cs[k] += vb;
        unsigned int pk = f2bu(va) | ((unsigned)f2bu(vb)<<16);
        *(unsigned int*)&H1T[(c0+k)*68 + ra] = pk;
      }
    }
    __syncthreads();
    {
      int kc = kh*32;
      #pragma unroll
      for (int s=0;s<2;++s){
        Frag a, b;
        const short* ap = &H1T[arow + kc + s*16 + ko];
        const short* bp = &H1T[brow + kc + s*16 + ko];
        a.u2[0] = *(const uint2*)ap;  a.u2[1] = *(const uint2*)(ap+4);
        b.u2[0] = *(const uint2*)bp;  b.u2[1] = *(const uint2*)(bp+4);
        acc = __builtin_amdgcn_mfma_f32_32x32x16_bf16(a.v, b.v, acc, 0, 0, 0);
      }
    }
    __syncthreads();
  }
  int col = lane & 63 & 31, rbase = 4*(lane>>5);
  col = lane & 31;
  #pragma unroll
  for (int r=0;r<16;++r){
    int row = (r&3) + 8*(r>>2) + rbase;
    atomicAdd(&G2[(size_t)(mt*32+row)*64 + nt*32+col], acc[r]);
  }
  #pragma unroll
  for (int k=0;k<4;++k) atomicAdd(&csum[c0+k], cs[k]);
  __syncthreads();
  if (tid < 64) atomicAdd(&sum2[tid], csum[tid]);
}

// ---------------- fused layers 1+2 ----------------
__global__ __launch_bounds__(64) void fl12_kernel(const float* __restrict__ x,
    const int* __restrict__ idx, const float* __restrict__ W1f,
    const float* __restrict__ sc1v, const float* __restrict__ sh1v,
    const float* __restrict__ W2f, const float* __restrict__ sc2v,
    const float* __restrict__ sh2v, bf16* __restrict__ H2, bf16* __restrict__ cat){
  __shared__ float fsh[Kk][6];
  __shared__ float h1[Kk][64];
  __shared__ float mm[4][64];
  int bn = blockIdx.x, b = bn>>12, n = bn & 4095;
  int tid = threadIdx.x;
  if (tid < Kk){
    int j = idx[(size_t)bn*Kk + tid];
    const float* xb = x + b*3*Nn;
    fsh[tid][0]=xb[j]; fsh[tid][1]=xb[Nn+j]; fsh[tid][2]=xb[2*Nn+j];
    fsh[tid][3]=xb[n]; fsh[tid][4]=xb[Nn+n]; fsh[tid][5]=xb[2*Nn+n];
  }
  __syncthreads();
  {
    float sc=sc1v[tid], sh=sh1v[tid];
    float w[6];
    #pragma unroll
    for (int i=0;i<6;++i) w[i]=W1f[i*64+tid];
    float mx = 0.f;
    #pragma unroll
    for (int r=0;r<Kk;++r){
      float y=0.f;
      #pragma unroll
      for (int i=0;i<6;++i) y = fmaf(fsh[r][i], w[i], y);
      float v = fmaxf(fmaf(y,sc,sh),0.f);
      h1[r][tid]=v;
      mx = fmaxf(mx,v);
    }
    cat[(size_t)bn*512 + tid] = f2b(mx);
  }
  __syncthreads();
  int q = tid >> 4, c0 = (tid & 15)*4;
  float acc[5][4]={};
  for (int i0=0;i0<64;i0+=4){
    float hv[5][4];
    #pragma unroll
    for (int l=0;l<5;++l){
      float4 t4 = *(const float4*)&h1[q*5+l][i0];
      hv[l][0]=t4.x; hv[l][1]=t4.y; hv[l][2]=t4.z; hv[l][3]=t4.w;
    }
    #pragma unroll
    for (int ii=0;ii<4;++ii){
      const float* wp = W2f + (i0+ii)*64 + c0;
      float w0=wp[0],w1=wp[1],w2=wp[2],w3=wp[3];
      #pragma unroll
      for (int l=0;l<5;++l){
        float hvv=hv[l][ii];
        acc[l][0]=fmaf(hvv,w0,acc[l][0]);
        acc[l][1]=fmaf(hvv,w1,acc[l][1]);
        acc[l][2]=fmaf(hvv,w2,acc[l][2]);
        acc[l][3]=fmaf(hvv,w3,acc[l][3]);
      }
    }
  }
  float sc[4],sh[4];
  #pragma unroll
  for (int cb=0;cb<4;++cb){ sc[cb]=sc2v[c0+cb]; sh[cb]=sh2v[c0+cb]; }
  float mx[4]={0,0,0,0};
  #pragma unroll
  for (int l=0;l<5;++l){
    unsigned short us[4];
    #pragma unroll
    for (int cb=0;cb<4;++cb){
      float v=fmaxf(fmaf(acc[l][cb],sc[cb],sh[cb]),0.f);
      mx[cb]=fmaxf(mx[cb],v);
      us[cb]=f2bu(v);
    }
    uint2 v2; v2.x = us[0]|((unsigned)us[1]<<16); v2.y=us[2]|((unsigned)us[3]<<16);
    *(uint2*)(H2 + ((size_t)bn*Kk + q*5+l)*64 + c0) = v2;
  }
  #pragma unroll
  for (int cb=0;cb<4;++cb) mm[q][c0+cb]=mx[cb];
  __syncthreads();
  {
    float M0 = fmaxf(fmaxf(mm[0][tid],mm[1][tid]),fmaxf(mm[2][tid],mm[3][tid]));
    cat[(size_t)bn*512 + 64 + tid] = f2b(M0);
  }
}

// ---------------- layer-4 stats v2: MFMA produce + MFMA Gram, 2 barriers/iter ----------------
// H3-tile (64x128) = relu(bn3(H2tile @ W3)) computed on matrix cores from bf16 H2
// and pre-packed bf16 W3^T (B-fragments hoisted to registers once per block).
// sum4 reduced per-lane -> LDS -> 128 global atomics/block (was 2048/block onto 8 lines).
__global__ __launch_bounds__(512) void stats4_kernel(const bf16* __restrict__ H2,
    const bf16* __restrict__ W3T, const float* __restrict__ sc3v, const float* __restrict__ sh3v,
    float* __restrict__ G4, float* __restrict__ sum4){
  __shared__ short h2s[64*68];     // 8.5 KB, pad 68 -> 2-way-free strided reads
  __shared__ short H3T[128*68];    // 17 KB
  __shared__ float csum[128];
  int tid = threadIdx.x, lane = tid & 63, w = tid >> 6;   // 8 waves
  if (tid < 128) csum[tid] = 0.f;
  // staging mapping: 8 threads per row, 8 bf16 each
  int trow = tid >> 3, tc0 = (tid & 7)*8;
  // produce mapping: wave -> 32x32 C-tile of the 64x128 H3 tile
  int pl  = lane & 31;
  int ko  = (lane >> 5)*8;
  int pmt = w >> 2, pnt = w & 3;
  int parow = (pmt*32 + pl)*68;       // A-frag row base in h2s (shorts)
  int pcol  = pnt*32 + pl;            // output column
  float psc = sc3v[pcol], psh = sh3v[pcol];
  int prbase = 4*(lane>>5);
  // hoist B-fragments (W3^T bf16, 16 KB L1-resident) into 16 VGPRs
  FragQ bfr[4];
  #pragma unroll
  for (int kq=0;kq<4;++kq)
    bfr[kq].q = *(const uint4*)&W3T[(size_t)pcol*64 + kq*16 + ko];
  // gram mapping (unchanged from v1)
  int gmt = w>>1, gnt0 = (w&1)*2, gnt1 = gnt0+1;
  int garow  = (gmt*32 + pl)*68;
  int gbrow0 = (gnt0*32 + pl)*68;
  int gbrow1 = (gnt1*32 + pl)*68;
  floatx16 acc0, acc1;
  #pragma unroll
  for (int q=0;q<16;++q){ acc0[q]=0.f; acc1[q]=0.f; }
  float cs = 0.f;
  int rpc = Mrows / gridDim.x;
  int r0 = blockIdx.x * rpc;
  uint4 hreg = *(const uint4*)&H2[(size_t)(r0+trow)*64 + tc0];
  for (int rb=r0; rb<r0+rpc; rb+=64){
    // stage h2s from prefetched registers; issue next prefetch
    {
      short* dst = &h2s[trow*68 + tc0];
      *(uint2*)dst       = make_uint2(hreg.x, hreg.y);
      *(uint2*)(dst + 4) = make_uint2(hreg.z, hreg.w);
    }
    if (rb + 64 < r0 + rpc)
      hreg = *(const uint4*)&H2[(size_t)(rb+64+trow)*64 + tc0];
    __syncthreads();                      // h2s ready; also fences prev gram's H3T reads
    // produce: 4 MFMAs -> bn+relu -> pack to H3T (transposed layout for gram)
    {
      floatx16 pacc;
      #pragma unroll
      for (int q=0;q<16;++q) pacc[q]=0.f;
      #pragma unroll
      for (int kq=0;kq<4;++kq){
        Frag a;
        const short* ap = &h2s[parow + kq*16 + ko];
        a.u2[0] = *(const uint2*)ap;  a.u2[1] = *(const uint2*)(ap+4);
        pacc = __builtin_amdgcn_mfma_f32_32x32x16_bf16(a.v, bfr[kq].v, pacc, 0, 0, 0);
      }
      #pragma unroll
      for (int g=0; g<4; ++g){
        unsigned short p[4];
        #pragma unroll
        for (int r=0;r<4;++r){
          float v = fmaxf(fmaf(pacc[g*4+r], psc, psh), 0.f);
          cs += v;
          p[r] = f2bu(v);
        }
        uint2 pk; pk.x = p[0] | ((unsigned)p[1]<<16); pk.y = p[2] | ((unsigned)p[3]<<16);
        *(uint2*)&H3T[pcol*68 + pmt*32 + 8*g + prbase] = pk;
      }
    }
    __syncthreads();                      // H3T ready
    // gram: G4 += H3tile^T @ H3tile
    #pragma unroll
    for (int kc=0;kc<64;kc+=16){
      Frag a, b0, b1;
      const short* ap  = &H3T[garow  + kc + ko];
      const short* bp0 = &H3T[gbrow0 + kc + ko];
      const short* bp1 = &H3T[gbrow1 + kc + ko];
      a.u2[0]  = *(const uint2*)ap;   a.u2[1]  = *(const uint2*)(ap+4);
      b0.u2[0] = *(const uint2*)bp0;  b0.u2[1] = *(const uint2*)(bp0+4);
      b1.u2[0] = *(const uint2*)bp1;  b1.u2[1] = *(const uint2*)(bp1+4);
      acc0 = __builtin_amdgcn_mfma_f32_32x32x16_bf16(a.v, b0.v, acc0, 0, 0, 0);
      acc1 = __builtin_amdgcn_mfma_f32_32x32x16_bf16(a.v, b1.v, acc1, 0, 0, 0);
    }
    // no barrier here: next iter writes only h2s (not read by gram);
    // next produce's H3T writes are fenced by the first barrier above.
  }
  int col = pl;
  #pragma unroll
  for (int r=0;r<16;++r){
    int row = (r&3) + 8*(r>>2) + prbase;
    atomicAdd(&G4[(size_t)(gmt*32+row)*128 + gnt0*32+col], acc0[r]);
    atomicAdd(&G4[(size_t)(gmt*32+row)*128 + gnt1*32+col], acc1[r]);
  }
  atomicAdd(&csum[pcol], cs);             // LDS atomic, 4 contributors/col
  __syncthreads();
  if (tid < 128) atomicAdd(&sum4[tid], csum[tid]);
}

// ---------------- fused layers 3+4 v3: VALU-bound blocking ----------------
__global__ __launch_bounds__(512,2) void fl34_kernel(const bf16* __restrict__ H2,
    const float* __restrict__ W3f, const float* __restrict__ sc3v, const float* __restrict__ sh3v,
    const float* __restrict__ W4f, const float* __restrict__ sc4v, const float* __restrict__ sh4v,
    bf16* __restrict__ cat){
  __shared__ float h2s[4][Kk][64];      // 20 KB
  __shared__ float h3s[4][Kk][128];     // 40 KB
  __shared__ float w4s[16*256];         // 16 KB; swizzled W4 rows; aliased as mm3/mmf
  int tid = threadIdx.x;
  int bn0 = blockIdx.x*4;
  int pt = tid >> 7, tid2 = tid & 127;
  for (int u=tid; u<4*Kk*64; u+=512){
    int p = u / 1280, rem = u - p*1280;
    h2s[p][rem>>6][rem&63] = b2f(H2[((size_t)(bn0+p)*Kk + (rem>>6))*64 + (rem&63)]);
  }
  __syncthreads();
  // stage 1: 5 rows x 4 cols per thread; W3 from global (L1-resident); i-ascending chains
  {
    int rg = tid2 >> 5, cgq = tid2 & 31, c0 = cgq*4;
    float acc[5][4];
    #pragma unroll
    for (int l=0;l<5;++l)
      #pragma unroll
      for (int k=0;k<4;++k) acc[l][k]=0.f;
    for (int i0=0;i0<64;i0+=4){
      float4 h4[5];
      #pragma unroll
      for (int l=0;l<5;++l) h4[l] = *(const float4*)&h2s[pt][rg*5+l][i0];
      #pragma unroll
      for (int ii=0;ii<4;++ii){
        float4 wv = *(const float4*)&W3f[(size_t)(i0+ii)*128 + c0];
        #pragma unroll
        for (int l=0;l<5;++l){
          float hv = h4[l][ii];
          acc[l][0]=fmaf(hv,wv.x,acc[l][0]);
          acc[l][1]=fmaf(hv,wv.y,acc[l][1]);
          acc[l][2]=fmaf(hv,wv.z,acc[l][2]);
          acc[l][3]=fmaf(hv,wv.w,acc[l][3]);
        }
      }
    }
    float sca[4], sha[4];
    #pragma unroll
    for (int k=0;k<4;++k){ sca[k]=sc3v[c0+k]; sha[k]=sh3v[c0+k]; }
    float mx4[4] = {0.f,0.f,0.f,0.f};
    #pragma unroll
    for (int l=0;l<5;++l){
      float4 v4;
      float v0=fmaxf(fmaf(acc[l][0],sca[0],sha[0]),0.f);
      float v1=fmaxf(fmaf(acc[l][1],sca[1],sha[1]),0.f);
      float v2=fmaxf(fmaf(acc[l][2],sca[2],sha[2]),0.f);
      float v3=fmaxf(fmaf(acc[l][3],sca[3],sha[3]),0.f);
      mx4[0]=fmaxf(mx4[0],v0); mx4[1]=fmaxf(mx4[1],v1);
      mx4[2]=fmaxf(mx4[2],v2); mx4[3]=fmaxf(mx4[3],v3);
      v4 = make_float4(v0,v1,v2,v3);
      *(float4*)&h3s[pt][rg*5+l][c0] = v4;
    }
    float* mm3 = w4s;   // [4 pt][4 rg][128]
    #pragma unroll
    for (int k=0;k<4;++k) mm3[((pt*4+rg)<<7) + c0 + k] = mx4[k];
  }
  __syncthreads();
  // x3 maxpool over rowgroups
  {
    const float* mm3 = w4s;
    int p = tid >> 7, c = tid & 127;
    float M0 = fmaxf(fmaxf(mm3[((p*4+0)<<7)+c], mm3[((p*4+1)<<7)+c]),
                     fmaxf(mm3[((p*4+2)<<7)+c], mm3[((p*4+3)<<7)+c]));
    cat[(size_t)(bn0+p)*512 + 128 + c] = f2b(M0);
  }
  __syncthreads();
  // stage 2: 5 rows x 8 consecutive cols; h float4 along k; W4 swizzled b128 pairs
  int q = tid2 >> 5, cg = tid2 & 31, c0 = cg*8;
  int wg0 = sw6(2*cg)*4, wg1 = sw6(2*cg+1)*4;
  float acc[5][8];
  #pragma unroll
  for (int l=0;l<5;++l)
    #pragma unroll
    for (int cb=0;cb<8;++cb) acc[l][cb]=0.f;
  for (int i0=0;i0<128;i0+=16){
    for (int u=tid;u<4096;u+=512){
      int kk=u>>8, c=u&255;
      w4s[kk*256 + sw6(c>>2)*4 + (c&3)] = W4f[(size_t)(i0+kk)*256 + c];
    }
    __syncthreads();
    #pragma unroll
    for (int kk0=0;kk0<16;kk0+=4){
      float4 h4[5];
      #pragma unroll
      for (int l=0;l<5;++l) h4[l] = *(const float4*)&h3s[pt][q*5+l][i0+kk0];
      #pragma unroll
      for (int ii=0;ii<4;++ii){
        float4 wa = *(const float4*)&w4s[(kk0+ii)*256 + wg0];
        float4 wb = *(const float4*)&w4s[(kk0+ii)*256 + wg1];
        float wv[8] = {wa.x,wa.y,wa.z,wa.w,wb.x,wb.y,wb.z,wb.w};
        #pragma unroll
        for (int l=0;l<5;++l){
          float hv = h4[l][ii];
          #pragma unroll
          for (int cb=0;cb<8;++cb) acc[l][cb]=fmaf(hv,wv[cb],acc[l][cb]);
        }
      }
    }
    __syncthreads();
  }
  float sc[8],sh[8];
  #pragma unroll
  for (int cb=0;cb<8;++cb){ sc[cb]=sc4v[c0+cb]; sh[cb]=sh4v[c0+cb]; }
  float mx[8];
  #pragma unroll
  for (int cb=0;cb<8;++cb) mx[cb]=0.f;
  #pragma unroll
  for (int l=0;l<5;++l)
    #pragma unroll
    for (int cb=0;cb<8;++cb){
      float v=fmaxf(fmaf(acc[l][cb],sc[cb],sh[cb]),0.f);
      mx[cb]=fmaxf(mx[cb],v);
    }
  float* mmf = w4s;   // [4 pt][4 q][256]
  #pragma unroll
  for (int cb=0;cb<8;++cb) mmf[((pt*4+q)<<8) + c0 + cb] = mx[cb];
  __syncthreads();
  for (int u=tid; u<1024; u+=512){
    int p = u >> 8, c = u & 255;
    float M0 = fmaxf(fmaxf(mmf[((p*4+0)<<8)+c], mmf[((p*4+1)<<8)+c]),
                     fmaxf(mmf[((p*4+2)<<8)+c], mmf[((p*4+3)<<8)+c]));
    cat[(size_t)(bn0+p)*512 + 256 + c] = f2b(M0);
  }
}

// ---------------- layer 5: 16 rows/block ----------------
__global__ __launch_bounds__(256) void l5_kernel(const bf16* __restrict__ cat,
                                                const float* __restrict__ Wf,
                                                const float* __restrict__ scale,
                                                const float* __restrict__ shift,
                                                float* __restrict__ out){
  __shared__ float cr[16][512];
  __shared__ float ob[16][512];
  int tid = threadIdx.x;
  int bn0 = blockIdx.x*16;
  for (int v=tid; v<1024; v+=256){
    int row = v>>6, c0 = (v&63)*8;
    U4b u; u.q = *(const uint4*)&cat[(size_t)(bn0+row)*512 + c0];
    float f[8];
    #pragma unroll
    for (int j=0;j<8;++j) f[j] = bits2f(u.s[j]);
    *(float4*)&cr[row][c0]   = make_float4(f[0],f[1],f[2],f[3]);
    *(float4*)&cr[row][c0+4] = make_float4(f[4],f[5],f[6],f[7]);
  }
  __syncthreads();
  int rp = tid >> 6, cg = tid & 63, c0 = cg*8;
  int ra = rp*4;
  float acc[4][8];
  #pragma unroll
  for (int r=0;r<4;++r)
    #pragma unroll
    for (int cb=0;cb<8;++cb) acc[r][cb]=0.f;
  for (int i=0;i<512;++i){
    float h0 = cr[ra][i], h1 = cr[ra+1][i], h2v = cr[ra+2][i], h3 = cr[ra+3][i];
    const float* wp = Wf + (size_t)i*512 + c0;
    float4 wa = *(const float4*)wp;
    float4 wb = *(const float4*)(wp+4);
    float w[8] = {wa.x,wa.y,wa.z,wa.w,wb.x,wb.y,wb.z,wb.w};
    #pragma unroll
    for (int k=0;k<8;++k){
      acc[0][k] = fmaf(h0, w[k], acc[0][k]);
      acc[1][k] = fmaf(h1, w[k], acc[1][k]);
      acc[2][k] = fmaf(h2v, w[k], acc[2][k]);
      acc[3][k] = fmaf(h3, w[k], acc[3][k]);
    }
  }
  float sc[8], sh[8];
  #pragma unroll
  for (int k=0;k<8;++k){ sc[k]=scale[c0+k]; sh[k]=shift[c0+k]; }
  #pragma unroll
  for (int r=0;r<4;++r)
    #pragma unroll
    for (int k=0;k<8;++k)
      ob[ra+r][c0+k] = fmaxf(fmaf(acc[r][k], sc[k], sh[k]), 0.f);
  __syncthreads();
  int b = bn0 >> 12, n0 = bn0 & 4095;
  for (int u=tid; u<512; u+=256){
    float* op = out + ((size_t)b*512 + u)*4096 + n0;
    #pragma unroll
    for (int g=0; g<4; ++g){
      float4 v = make_float4(ob[g*4][u], ob[g*4+1][u], ob[g*4+2][u], ob[g*4+3][u]);
      *(float4*)(op + g*4) = v;
    }
  }
}

extern "C" void kernel_launch(void* const* d_in, const int* in_sizes, int n_in,
                              void* d_out, int out_size, void* d_ws, size_t ws_size,
                              hipStream_t stream){
  const float* x   = (const float*)d_in[0];
  const float* W1f = (const float*)d_in[1];
  const float* W2f = (const float*)d_in[2];
  const float* W3f = (const float*)d_in[3];
  const float* W4f = (const float*)d_in[4];
  const float* W5f = (const float*)d_in[5];
  const float* g1=(const float*)d_in[6],  *b1=(const float*)d_in[7];
  const float* g2=(const float*)d_in[8],  *b2=(const float*)d_in[9];
  const float* g3=(const float*)d_in[10], *b3=(const float*)d_in[11];
  const float* g4=(const float*)d_in[12], *b4=(const float*)d_in[13];
  const float* g5=(const float*)d_in[14], *b5=(const float*)d_in[15];
  float* out = (float*)d_out;

  char* w = (char*)d_ws;
  size_t off = 0;
  auto alloc = [&](size_t bytes)->void*{
    void* p = w + off;
    off = (off + bytes + 255) & ~(size_t)255;
    return p;
  };

  int*  idxb = (int*) alloc((size_t)BN*Kk*4);
  bf16* H2   = (bf16*)alloc((size_t)Mrows*64*2);
  bf16* catb = (bf16*)alloc((size_t)BN*512*2);
  bf16* W3T  = (bf16*)alloc((size_t)128*64*2);
  float* pv  = (float*)H2;
  int*   pib = (int*)((char*)H2 + (size_t)BN*4*Kk*4);

  size_t statsStart = off;
  float* partf=(float*)alloc(256*48*4);
  float* Gf=(float*)alloc(36*4);
  float* sumf=(float*)alloc(8*4);
  float* G2=(float*)alloc(4096*4);   float* sum2=(float*)alloc(64*4);
  float* G3=(float*)alloc(4096*4);   float* sum3=(float*)alloc(64*4);
  float* G4=(float*)alloc(16384*4);  float* sum4=(float*)alloc(128*4);
  float* G5=(float*)alloc(262144*4); float* sum5=(float*)alloc(512*4);
  float* P1=(float*)alloc(384*4);
  float* P2=(float*)alloc(4096*4);
  float* P3=(float*)alloc(8192*4);
  float* P4=(float*)alloc(32768*4);
  float* P5=(float*)alloc(262144*4);
  float* sc1=(float*)alloc(64*4);   float* sh1=(float*)alloc(64*4);
  float* sc2=(float*)alloc(64*4);   float* sh2=(float*)alloc(64*4);
  float* sc3=(float*)alloc(128*4);  float* sh3=(float*)alloc(128*4);
  float* sc4=(float*)alloc(256*4);  float* sh4=(float*)alloc(256*4);
  float* sc5=(float*)alloc(512*4);  float* sh5=(float*)alloc(512*4);
  size_t statsEnd = off;

  int statsFloats = (int)((statsEnd - statsStart)/4);
  zero_kernel<<<(statsFloats+255)/256,256,0,stream>>>((float*)(w+statsStart), statsFloats);
  w3t_kernel<<<32,256,0,stream>>>(W3f, W3T);

  knnA_kernel<<<512,256,0,stream>>>(x, pv, pib);
  knnB_kernel<<<BN/256,256,0,stream>>>(pv, pib, idxb);

  const float invM  = 1.0f/(float)Mrows;
  const float invM5 = 1.0f/(float)BN;

  gramf_kernel<<<256,256,0,stream>>>(x, idxb, partf);
  reducef_kernel<<<1,64,0,stream>>>(partf, Gf, sumf);
  kP_kernel<<<2,256,0,stream>>>(Gf, W1f, P1, 6, 64);
  kFinal_kernel<<<1,256,0,stream>>>(P1, sumf, W1f, g1, b1, sc1, sh1, 6, 64, invM);

  stats2_kernel<<<512,512,0,stream>>>(x, idxb, W1f, sc1, sh1, G2, sum2);
  kP_kernel<<<16,256,0,stream>>>(G2, W2f, P2, 64, 64);
  kFinal_kernel<<<1,256,0,stream>>>(P2, sum2, W2f, g2, b2, sc2, sh2, 64, 64, invM);

  fl12_kernel<<<BN,64,0,stream>>>(x, idxb, W1f, sc1, sh1, W2f, sc2, sh2, H2, catb);

  colsum_kernel<64,bf16><<<512,256,0,stream>>>(H2, Mrows, sum3);
  gramM_kernel<64><<<512,256,0,stream>>>(H2, Mrows, G3);
  kP_kernel<<<32,256,0,stream>>>(G3, W3f, P3, 64, 128);
  kFinal_kernel<<<1,256,0,stream>>>(P3, sum3, W3f, g3, b3, sc3, sh3, 64, 128, invM);

  stats4_kernel<<<512,512,0,stream>>>(H2, W3T, sc3, sh3, G4, sum4);
  kP_kernel<<<128,256,0,stream>>>(G4, W4f, P4, 128, 256);
  kFinal_kernel<<<1,256,0,stream>>>(P4, sum4, W4f, g4, b4, sc4, sh4, 128, 256, invM);

  fl34_kernel<<<BN/4,512,0,stream>>>(H2, W3f, sc3, sh3, W4f, sc4, sh4, catb);

  colsum_kernel<512,bf16><<<512,256,0,stream>>>(catb, BN, sum5);
  gramM_kernel<512><<<512,256,0,stream>>>(catb, BN, G5);
  kP_kernel<<<1024,256,0,stream>>>(G5, W5f, P5, 512, 512);
  kFinal_kernel<<<2,256,0,stream>>>(P5, sum5, W5f, g5, b5, sc5, sh5, 512, 512, invM5);
  l5_kernel<<<BN/16,256,0,stream>>>(catb, W5f, sc5, sh5, out);
}

// Round 2
// 2216.398 us; speedup vs baseline: 1.6783x; 1.3057x over previous
//
#include <hip/hip_runtime.h>
#include <hip/hip_bf16.h>
#include <cfloat>

using bf16 = __hip_bfloat16;

typedef short short8 __attribute__((ext_vector_type(8)));
typedef float floatx16 __attribute__((ext_vector_type(16)));
union Frag { short8 v; uint2 u2[2]; };
union FragQ { short8 v; uint4 q; uint2 u2[2]; };
union U4b { uint4 q; unsigned short s[8]; };

constexpr int Bb = 8, Nn = 4096, Kk = 20;
constexpr int BN = Bb * Nn;                     // 32768
constexpr int Mrows = BN * Kk;                  // 655360
constexpr float EPSf = 1e-5f;

static __device__ __forceinline__ float b2f(bf16 v){ return __bfloat162float(v); }
static __device__ __forceinline__ bf16 f2b(float v){ return __float2bfloat16(v); }
static __device__ __forceinline__ unsigned short f2bu(float v){
  union { bf16 b; unsigned short u; } cv; cv.b = __float2bfloat16(v); return cv.u;
}
static __device__ __forceinline__ float bits2f(unsigned short u){
  union { unsigned int i; float f; } c; c.i = ((unsigned)u)<<16; return c.f;
}
static __device__ __forceinline__ float ldf(bf16 v){ return b2f(v); }
static __device__ __forceinline__ float ldf(float v){ return v; }

// ---------------- zero workspace region ----------------
__global__ void zero_kernel(float* __restrict__ p, int n){
  int i = blockIdx.x*256 + threadIdx.x;
  if (i < n) p[i] = 0.f;
}

// ---------------- W3^T bf16 pack ----------------
__global__ void w3t_kernel(const float* __restrict__ W3f, bf16* __restrict__ W3T){
  int id = blockIdx.x*256 + threadIdx.x;   // 128*64 = 8192 elems
  if (id >= 128*64) return;
  int n = id >> 6, k = id & 63;
  W3T[id] = f2b(W3f[(size_t)k*128 + n]);
}

// ---------------- W4^T bf16 pack ----------------
__global__ void w4t_kernel(const float* __restrict__ W4f, bf16* __restrict__ W4T){
  int id = blockIdx.x*256 + threadIdx.x;   // 128*256 = 32768 elems
  if (id >= 128*256) return;
  int k = id >> 8, c = id & 255;           // coalesced read of W4f
  W4T[(size_t)c*128 + k] = f2b(W4f[id]);
}

// ---------------- KNN phase A ----------------
__global__ __launch_bounds__(256) void knnA_kernel(const float* __restrict__ x,
                                                   float* __restrict__ pv, int* __restrict__ pi){
#pragma clang fp contract(off)
  __shared__ float4 p4[1024];
  int blk = blockIdx.x;
  int stripe = blk & 3;
  int chunk  = (blk >> 2) & 15;
  int b      = blk >> 6;
  const float* xb = x + b*3*Nn;
  int j0 = stripe*1024;
  for (int u = threadIdx.x; u < 1024; u += 256){
    int j = j0 + u;
    float a0 = xb[j];
    float a1 = xb[Nn + j];
    float a2 = xb[2*Nn + j];
    float s = a0*a0; s = s + a1*a1; s = s + a2*a2;
    p4[u] = make_float4(a0, a1, a2, s);
  }
  __syncthreads();
  int i = chunk*256 + threadIdx.x;
  float xi = xb[i], yi = xb[Nn+i], zi = xb[2*Nn+i];
  float ni = xi*xi; ni = ni + yi*yi; ni = ni + zi*zi;
  float mni = -ni;
  float tv[Kk]; int ti[Kk];
  #pragma unroll
  for (int s=0;s<Kk;++s){ tv[s] = -FLT_MAX; ti[s] = 0; }
  for (int u=0; u<1024; ++u){
    float4 p = p4[u];
    float dot = xi*p.x; dot = dot + yi*p.y; dot = dot + zi*p.z;
    float inner = -2.0f*dot;
    float nd = mni - inner; nd = nd - p.w;
    if (nd > tv[Kk-1]){
      #pragma unroll
      for (int s=Kk-1; s>=1; --s){
        bool cs = nd > tv[s];
        bool cp = nd > tv[s-1];
        tv[s] = cs ? (cp ? tv[s-1] : nd) : tv[s];
        ti[s] = cs ? (cp ? ti[s-1] : (j0+u)) : ti[s];
      }
      if (nd > tv[0]){ tv[0] = nd; ti[0] = j0+u; }
    }
  }
  long long base = ((long long)(b*Nn + i)*4 + stripe)*Kk;
  #pragma unroll
  for (int s=0;s<Kk;++s){ pv[base+s] = tv[s]; pi[base+s] = ti[s]; }
}

// ---------------- KNN phase B ----------------
__global__ __launch_bounds__(256) void knnB_kernel(const float* __restrict__ pv,
                                                   const int* __restrict__ pi,
                                                   int* __restrict__ idx){
  int p = blockIdx.x*256 + threadIdx.x;
  if (p >= BN) return;
  long long base = (long long)p*4*Kk;
  float av[Kk]; int ai[Kk];
  #pragma unroll
  for (int s=0;s<Kk;++s){ av[s]=pv[base+s]; ai[s]=pi[base+s]; }
  for (int t=Kk; t<4*Kk; ++t){
    float nd = pv[base+t]; int j = pi[base+t];
    if (nd > av[Kk-1]){
      #pragma unroll
      for (int s=Kk-1;s>=1;--s){
        bool cs = nd > av[s];
        bool cp = nd > av[s-1];
        av[s] = cs ? (cp?av[s-1]:nd) : av[s];
        ai[s] = cs ? (cp?ai[s-1]:j) : ai[s];
      }
      if (nd > av[0]){ av[0]=nd; ai[0]=j; }
    }
  }
  #pragma unroll
  for (int s=0;s<Kk;++s) idx[(long long)p*Kk+s] = ai[s];
}

// ---------------- layer-1 feature stats ----------------
__global__ __launch_bounds__(256) void gramf_kernel(const float* __restrict__ x,
                                                    const int* __restrict__ idx,
                                                    float* __restrict__ part){
  float acc[36]; float s6[6];
  #pragma unroll
  for (int a=0;a<36;++a) acc[a]=0.f;
  #pragma unroll
  for (int a=0;a<6;++a) s6[a]=0.f;
  for (long long row = blockIdx.x*256 + threadIdx.x; row < Mrows; row += (long long)gridDim.x*256){
    int bn = (int)(row / Kk);
    int b = bn >> 12, n = bn & 4095;
    int j = idx[row];
    const float* xb = x + b*3*Nn;
    float f[6];
    f[0]=xb[j];  f[1]=xb[Nn+j];  f[2]=xb[2*Nn+j];
    f[3]=xb[n];  f[4]=xb[Nn+n];  f[5]=xb[2*Nn+n];
    #pragma unroll
    for (int a=0;a<6;++a){
      s6[a] += f[a];
      #pragma unroll
      for (int c=0;c<6;++c) acc[a*6+c] = fmaf(f[a], f[c], acc[a*6+c]);
    }
  }
  __shared__ float red[256];
  for (int v=0; v<42; ++v){
    red[threadIdx.x] = (v<36)? acc[v] : s6[v-36];
    __syncthreads();
    for (int s=128; s>0; s>>=1){
      if (threadIdx.x < s) red[threadIdx.x] += red[threadIdx.x+s];
      __syncthreads();
    }
    if (threadIdx.x==0) part[blockIdx.x*48 + v] = red[0];
    __syncthreads();
  }
}

__global__ void reducef_kernel(const float* __restrict__ part, float* __restrict__ Gf,
                               float* __restrict__ sumf){
  int t = threadIdx.x;
  if (t < 42){
    float s = 0.f;
    for (int i=0;i<256;++i) s += part[i*48 + t];
    if (t<36) Gf[t]=s; else sumf[t-36]=s;
  }
}

// ---------------- MFMA Gram: G = H^T H over bf16 H ----------------
template<int CIN>
__global__ __launch_bounds__(256) void gramM_kernel(const bf16* __restrict__ H, int M,
                                                    float* __restrict__ G){
  constexpr int Tt = CIN/64;
  int tile = blockIdx.x % (Tt*Tt);
  int chunk = blockIdx.x / (Tt*Tt);
  int nchunks = gridDim.x / (Tt*Tt);
  int tr = tile / Tt, tc = tile % Tt;
  bool diag = (tr == tc);
  __shared__ short HTa[64*68];
  __shared__ short HTb[64*68];
  int rpc = M / nchunks;
  int r0 = chunk*rpc;
  int tid = threadIdx.x, lane = tid & 63, w = tid >> 6;
  int mt = w >> 1, nt = w & 1;
  floatx16 acc;
  #pragma unroll
  for (int q=0;q<16;++q) acc[q]=0.f;
  const short* Bbase = diag ? HTa : HTb;
  int arow = (mt*32 + (lane&31))*68;
  int brow = (nt*32 + (lane&31))*68;
  int ko = (lane>>5)*8;
  for (int rb=r0; rb<r0+rpc; rb+=64){
    #pragma unroll
    for (int s=0;s<2;++s){
      int e = tid + s*256;
      int row = e >> 3, c0 = (e & 7)*8;
      U4b va; va.q = *(const uint4*)&H[(size_t)(rb+row)*CIN + tr*64 + c0];
      #pragma unroll
      for (int j=0;j<8;++j) HTa[(c0+j)*68 + row] = (short)va.s[j];
      if (!diag){
        U4b vb; vb.q = *(const uint4*)&H[(size_t)(rb+row)*CIN + tc*64 + c0];
        #pragma unroll
        for (int j=0;j<8;++j) HTb[(c0+j)*68 + row] = (short)vb.s[j];
      }
    }
    __syncthreads();
    #pragma unroll
    for (int kc=0;kc<64;kc+=16){
      Frag a, b;
      const short* ap = &HTa[arow + kc + ko];
      const short* bp = &Bbase[brow + kc + ko];
      a.u2[0] = *(const uint2*)ap;  a.u2[1] = *(const uint2*)(ap+4);
      b.u2[0] = *(const uint2*)bp;  b.u2[1] = *(const uint2*)(bp+4);
      acc = __builtin_amdgcn_mfma_f32_32x32x16_bf16(a.v, b.v, acc, 0, 0, 0);
    }
    __syncthreads();
  }
  int col = lane & 31, rbase = 4*(lane>>5);
  #pragma unroll
  for (int r=0;r<16;++r){
    int row = (r&3) + 8*(r>>2) + rbase;
    atomicAdd(&G[(size_t)(tr*64 + mt*32 + row)*CIN + tc*64 + nt*32 + col], acc[r]);
  }
}

// ---------------- column sums of H ----------------
template<int CIN, typename T>
__global__ __launch_bounds__(256) void colsum_kernel(const T* __restrict__ H, int M,
                                                     float* __restrict__ sumh){
  int rpb = (M + gridDim.x - 1)/gridDim.x;
  int r0 = blockIdx.x*rpb, r1 = min(M, r0+rpb);
  if constexpr (CIN <= 256){
    constexpr int RP = 256/CIN;
    int c = threadIdx.x % CIN;
    int sub = threadIdx.x / CIN;
    float a = 0.f;
    for (int r=r0+sub; r<r1; r+=RP) a += ldf(H[(size_t)r*CIN + c]);
    atomicAdd(&sumh[c], a);
  } else {
    float a0=0.f, a1=0.f;
    for (int r=r0;r<r1;++r){
      a0 += ldf(H[(size_t)r*CIN + threadIdx.x]);
      a1 += ldf(H[(size_t)r*CIN + threadIdx.x + 256]);
    }
    atomicAdd(&sumh[threadIdx.x], a0);
    atomicAdd(&sumh[threadIdx.x+256], a1);
  }
}

// ---------------- P = G @ W ----------------
__global__ void kP_kernel(const float* __restrict__ G, const float* __restrict__ Wf,
                          float* __restrict__ P, int Cin, int Cout){
  int id = blockIdx.x*256 + threadIdx.x;
  if (id >= Cin*Cout) return;
  int i = id / Cout, j = id - i*Cout;
  float s = 0.f;
  for (int k=0;k<Cin;++k) s = fmaf(G[(size_t)i*Cin+k], Wf[(size_t)k*Cout+j], s);
  P[id] = s;
}

// ---------------- scale/shift from Gram-derived BN stats ----------------
__global__ void kFinal_kernel(const float* __restrict__ P, const float* __restrict__ sumh,
                              const float* __restrict__ Wf, const float* __restrict__ g,
                              const float* __restrict__ bb, float* __restrict__ scale,
                              float* __restrict__ shift, int Cin, int Cout, float invM){
  int j = blockIdx.x*256 + threadIdx.x;
  if (j >= Cout) return;
  float mean=0.f, e2=0.f;
  for (int i=0;i<Cin;++i){
    float w = Wf[(size_t)i*Cout + j];
    mean = fmaf(sumh[i], w, mean);
    e2   = fmaf(w, P[(size_t)i*Cout + j], e2);
  }
  mean *= invM; e2 *= invM;
  float var = e2 - mean*mean;
  float inv = rsqrtf(var + EPSf);
  float sc = g[j]*inv;
  scale[j]=sc;
  shift[j]=bb[j] - mean*sc;
}

// ---------------- layer-2 stats ----------------
__global__ __launch_bounds__(512) void stats2_kernel(const float* __restrict__ x,
    const int* __restrict__ idx, const float* __restrict__ W1f,
    const float* __restrict__ sc1v, const float* __restrict__ sh1v,
    float* __restrict__ G2, float* __restrict__ sum2){
  __shared__ float W1s[6][64];
  __shared__ float fsh[64][8];
  __shared__ short H1T[64*68];
  __shared__ float csum[64];
  int tid = threadIdx.x, lane = tid & 63, w = tid >> 6;   // 8 waves
  if (tid < 384) W1s[tid>>6][tid&63] = W1f[tid];
  if (tid < 64) csum[tid] = 0.f;
  int rp = tid >> 4, cq = tid & 15, c0 = cq*4;
  float sca[4], sha[4];
  #pragma unroll
  for (int k=0;k<4;++k){ sca[k]=sc1v[c0+k]; sha[k]=sh1v[c0+k]; }
  int mt = w & 1, nt = (w>>1) & 1, kh = w >> 2;
  int arow = (mt*32 + (lane&31))*68;
  int brow = (nt*32 + (lane&31))*68;
  int ko = (lane>>5)*8;
  floatx16 acc;
  #pragma unroll
  for (int q=0;q<16;++q) acc[q]=0.f;
  float cs[4] = {0.f,0.f,0.f,0.f};
  int rpc = Mrows / gridDim.x;
  int r0 = blockIdx.x * rpc;
  __syncthreads();
  for (int rb=r0; rb<r0+rpc; rb+=64){
    {
      int r = tid>>3, e = tid&7;
      if (e < 6){
        int grow = rb + r;
        int bn = grow / Kk;
        int b = bn >> 12, n = bn & 4095;
        int j = idx[grow];
        const float* xb = x + b*3*Nn;
        fsh[r][e] = (e<3) ? xb[e*Nn + j] : xb[(e-3)*Nn + n];
      }
    }
    __syncthreads();
    {
      float y0[4]={0,0,0,0}, y1[4]={0,0,0,0};
      int ra = rp*2, rbw = rp*2+1;
      #pragma unroll
      for (int i=0;i<6;++i){
        float fa = fsh[ra][i], fb = fsh[rbw][i];
        float4 wv = *(const float4*)&W1s[i][c0];
        y0[0]=fmaf(fa,wv.x,y0[0]); y0[1]=fmaf(fa,wv.y,y0[1]);
        y0[2]=fmaf(fa,wv.z,y0[2]); y0[3]=fmaf(fa,wv.w,y0[3]);
        y1[0]=fmaf(fb,wv.x,y1[0]); y1[1]=fmaf(fb,wv.y,y1[1]);
        y1[2]=fmaf(fb,wv.z,y1[2]); y1[3]=fmaf(fb,wv.w,y1[3]);
      }
      #pragma unroll
      for (int k=0;k<4;++k){
        float va = fmaxf(fmaf(y0[k],sca[k],sha[k]),0.f);
        float vb = fmaxf(fmaf(y1[k],sca[k],sha[k]),0.f);
        cs[k] += va; cs[k] += vb;
        unsigned int pk = f2bu(va) | ((unsigned)f2bu(vb)<<16);
        *(unsigned int*)&H1T[(c0+k)*68 + ra] = pk;
      }
    }
    __syncthreads();
    {
      int kc = kh*32;
      #pragma unroll
      for (int s=0;s<2;++s){
        Frag a, b;
        const short* ap = &H1T[arow + kc + s*16 + ko];
        const short* bp = &H1T[brow + kc + s*16 + ko];
        a.u2[0] = *(const uint2*)ap;  a.u2[1] = *(const uint2*)(ap+4);
        b.u2[0] = *(const uint2*)bp;  b.u2[1] = *(const uint2*)(bp+4);
        acc = __builtin_amdgcn_mfma_f32_32x32x16_bf16(a.v, b.v, acc, 0, 0, 0);
      }
    }
    __syncthreads();
  }
  int col = lane & 31, rbase = 4*(lane>>5);
  #pragma unroll
  for (int r=0;r<16;++r){
    int row = (r&3) + 8*(r>>2) + rbase;
    atomicAdd(&G2[(size_t)(mt*32+row)*64 + nt*32+col], acc[r]);
  }
  #pragma unroll
  for (int k=0;k<4;++k) atomicAdd(&csum[c0+k], cs[k]);
  __syncthreads();
  if (tid < 64) atomicAdd(&sum2[tid], csum[tid]);
}

// ---------------- fused layers 1+2 ----------------
__global__ __launch_bounds__(64) void fl12_kernel(const float* __restrict__ x,
    const int* __restrict__ idx, const float* __restrict__ W1f,
    const float* __restrict__ sc1v, const float* __restrict__ sh1v,
    const float* __restrict__ W2f, const float* __restrict__ sc2v,
    const float* __restrict__ sh2v, bf16* __restrict__ H2, bf16* __restrict__ cat){
  __shared__ float fsh[Kk][6];
  __shared__ float h1[Kk][64];
  __shared__ float mm[4][64];
  int bn = blockIdx.x, b = bn>>12, n = bn & 4095;
  int tid = threadIdx.x;
  if (tid < Kk){
    int j = idx[(size_t)bn*Kk + tid];
    const float* xb = x + b*3*Nn;
    fsh[tid][0]=xb[j]; fsh[tid][1]=xb[Nn+j]; fsh[tid][2]=xb[2*Nn+j];
    fsh[tid][3]=xb[n]; fsh[tid][4]=xb[Nn+n]; fsh[tid][5]=xb[2*Nn+n];
  }
  __syncthreads();
  {
    float sc=sc1v[tid], sh=sh1v[tid];
    float w[6];
    #pragma unroll
    for (int i=0;i<6;++i) w[i]=W1f[i*64+tid];
    float mx = 0.f;
    #pragma unroll
    for (int r=0;r<Kk;++r){
      float y=0.f;
      #pragma unroll
      for (int i=0;i<6;++i) y = fmaf(fsh[r][i], w[i], y);
      float v = fmaxf(fmaf(y,sc,sh),0.f);
      h1[r][tid]=v;
      mx = fmaxf(mx,v);
    }
    cat[(size_t)bn*512 + tid] = f2b(mx);
  }
  __syncthreads();
  int q = tid >> 4, c0 = (tid & 15)*4;
  float acc[5][4]={};
  for (int i0=0;i0<64;i0+=4){
    float hv[5][4];
    #pragma unroll
    for (int l=0;l<5;++l){
      float4 t4 = *(const float4*)&h1[q*5+l][i0];
      hv[l][0]=t4.x; hv[l][1]=t4.y; hv[l][2]=t4.z; hv[l][3]=t4.w;
    }
    #pragma unroll
    for (int ii=0;ii<4;++ii){
      const float* wp = W2f + (i0+ii)*64 + c0;
      float w0=wp[0],w1=wp[1],w2=wp[2],w3=wp[3];
      #pragma unroll
      for (int l=0;l<5;++l){
        float hvv=hv[l][ii];
        acc[l][0]=fmaf(hvv,w0,acc[l][0]);
        acc[l][1]=fmaf(hvv,w1,acc[l][1]);
        acc[l][2]=fmaf(hvv,w2,acc[l][2]);
        acc[l][3]=fmaf(hvv,w3,acc[l][3]);
      }
    }
  }
  float sc[4],sh[4];
  #pragma unroll
  for (int cb=0;cb<4;++cb){ sc[cb]=sc2v[c0+cb]; sh[cb]=sh2v[c0+cb]; }
  float mx[4]={0,0,0,0};
  #pragma unroll
  for (int l=0;l<5;++l){
    unsigned short us[4];
    #pragma unroll
    for (int cb=0;cb<4;++cb){
      float v=fmaxf(fmaf(acc[l][cb],sc[cb],sh[cb]),0.f);
      mx[cb]=fmaxf(mx[cb],v);
      us[cb]=f2bu(v);
    }
    uint2 v2; v2.x = us[0]|((unsigned)us[1]<<16); v2.y=us[2]|((unsigned)us[3]<<16);
    *(uint2*)(H2 + ((size_t)bn*Kk + q*5+l)*64 + c0) = v2;
  }
  #pragma unroll
  for (int cb=0;cb<4;++cb) mm[q][c0+cb]=mx[cb];
  __syncthreads();
  {
    float M0 = fmaxf(fmaxf(mm[0][tid],mm[1][tid]),fmaxf(mm[2][tid],mm[3][tid]));
    cat[(size_t)bn*512 + 64 + tid] = f2b(M0);
  }
}

// ---------------- layer-4 stats: MFMA produce + MFMA Gram ----------------
__global__ __launch_bounds__(512) void stats4_kernel(const bf16* __restrict__ H2,
    const bf16* __restrict__ W3T, const float* __restrict__ sc3v, const float* __restrict__ sh3v,
    float* __restrict__ G4, float* __restrict__ sum4){
  __shared__ short h2s[64*68];
  __shared__ short H3T[128*68];
  __shared__ float csum[128];
  int tid = threadIdx.x, lane = tid & 63, w = tid >> 6;   // 8 waves
  if (tid < 128) csum[tid] = 0.f;
  int trow = tid >> 3, tc0 = (tid & 7)*8;
  int pl  = lane & 31;
  int ko  = (lane >> 5)*8;
  int pmt = w >> 2, pnt = w & 3;
  int parow = (pmt*32 + pl)*68;
  int pcol  = pnt*32 + pl;
  float psc = sc3v[pcol], psh = sh3v[pcol];
  int prbase = 4*(lane>>5);
  FragQ bfr[4];
  #pragma unroll
  for (int kq=0;kq<4;++kq)
    bfr[kq].q = *(const uint4*)&W3T[(size_t)pcol*64 + kq*16 + ko];
  int gmt = w>>1, gnt0 = (w&1)*2, gnt1 = gnt0+1;
  int garow  = (gmt*32 + pl)*68;
  int gbrow0 = (gnt0*32 + pl)*68;
  int gbrow1 = (gnt1*32 + pl)*68;
  floatx16 acc0, acc1;
  #pragma unroll
  for (int q=0;q<16;++q){ acc0[q]=0.f; acc1[q]=0.f; }
  float cs = 0.f;
  int rpc = Mrows / gridDim.x;
  int r0 = blockIdx.x * rpc;
  uint4 hreg = *(const uint4*)&H2[(size_t)(r0+trow)*64 + tc0];
  for (int rb=r0; rb<r0+rpc; rb+=64){
    {
      short* dst = &h2s[trow*68 + tc0];
      *(uint2*)dst       = make_uint2(hreg.x, hreg.y);
      *(uint2*)(dst + 4) = make_uint2(hreg.z, hreg.w);
    }
    if (rb + 64 < r0 + rpc)
      hreg = *(const uint4*)&H2[(size_t)(rb+64+trow)*64 + tc0];
    __syncthreads();
    {
      floatx16 pacc;
      #pragma unroll
      for (int q=0;q<16;++q) pacc[q]=0.f;
      #pragma unroll
      for (int kq=0;kq<4;++kq){
        Frag a;
        const short* ap = &h2s[parow + kq*16 + ko];
        a.u2[0] = *(const uint2*)ap;  a.u2[1] = *(const uint2*)(ap+4);
        pacc = __builtin_amdgcn_mfma_f32_32x32x16_bf16(a.v, bfr[kq].v, pacc, 0, 0, 0);
      }
      #pragma unroll
      for (int g=0; g<4; ++g){
        unsigned short p[4];
        #pragma unroll
        for (int r=0;r<4;++r){
          float v = fmaxf(fmaf(pacc[g*4+r], psc, psh), 0.f);
          cs += v;
          p[r] = f2bu(v);
        }
        uint2 pk; pk.x = p[0] | ((unsigned)p[1]<<16); pk.y = p[2] | ((unsigned)p[3]<<16);
        *(uint2*)&H3T[pcol*68 + pmt*32 + 8*g + prbase] = pk;
      }
    }
    __syncthreads();
    #pragma unroll
    for (int kc=0;kc<64;kc+=16){
      Frag a, b0, b1;
      const short* ap  = &H3T[garow  + kc + ko];
      const short* bp0 = &H3T[gbrow0 + kc + ko];
      const short* bp1 = &H3T[gbrow1 + kc + ko];
      a.u2[0]  = *(const uint2*)ap;   a.u2[1]  = *(const uint2*)(ap+4);
      b0.u2[0] = *(const uint2*)bp0;  b0.u2[1] = *(const uint2*)(bp0+4);
      b1.u2[0] = *(const uint2*)bp1;  b1.u2[1] = *(const uint2*)(bp1+4);
      acc0 = __builtin_amdgcn_mfma_f32_32x32x16_bf16(a.v, b0.v, acc0, 0, 0, 0);
      acc1 = __builtin_amdgcn_mfma_f32_32x32x16_bf16(a.v, b1.v, acc1, 0, 0, 0);
    }
  }
  int col = pl;
  #pragma unroll
  for (int r=0;r<16;++r){
    int row = (r&3) + 8*(r>>2) + prbase;
    atomicAdd(&G4[(size_t)(gmt*32+row)*128 + gnt0*32+col], acc0[r]);
    atomicAdd(&G4[(size_t)(gmt*32+row)*128 + gnt1*32+col], acc1[r]);
  }
  atomicAdd(&csum[pcol], cs);
  __syncthreads();
  if (tid < 128) atomicAdd(&sum4[tid], csum[tid]);
}

// ---------------- fused layers 3+4 v4: MFMA produce chain + col-owner maxpool ----------------
// Block = 320 rows = 16 points; 5 tiles of 64 rows; 8 waves.
// Per tile: stage H2 -> produce3 (MFMA, bf16 H3 row-major LDS) -> produce4 (MFMA)
// -> bn+relu bf16 H4 LDS -> per-column maxpool scan (u16 bf16 bit-compare, relu => order-iso).
__global__ __launch_bounds__(512,4) void fl34_kernel(const bf16* __restrict__ H2,
    const bf16* __restrict__ W3T, const float* __restrict__ sc3v, const float* __restrict__ sh3v,
    const bf16* __restrict__ W4T, const float* __restrict__ sc4v, const float* __restrict__ sh4v,
    bf16* __restrict__ cat){
  __shared__ short h2s[64*68];             // 8.5 KB
  __shared__ short h3s[64*132];            // 16.5 KB (ld 132 shorts = 66 dw -> 2-way free strided)
  __shared__ unsigned short h4s[64*256];   // 32 KB
  __shared__ unsigned short mx3u[16*128];  // 4 KB
  __shared__ unsigned short mx4u[16*256];  // 8 KB
  int tid = threadIdx.x, lane = tid & 63, w = tid >> 6;
  int pl = lane & 31;
  int ko = (lane >> 5)*8;
  int rbase = 4*(lane>>5);
  // init running-max buffers (covered by first barrier chain before any scan)
  {
    unsigned* p4 = (unsigned*)mx4u;
    for (int u=tid; u<2048; u+=512) p4[u]=0u;
    unsigned* p3 = (unsigned*)mx3u;
    for (int u=tid; u<1024; u+=512) p3[u]=0u;
  }
  // produce3 mapping: wave -> (mt3 rows, ct3 cols)
  int mt3 = w >> 2, ct3 = w & 3;
  int c3 = ct3*32 + pl;
  float sc3 = sc3v[c3], sh3 = sh3v[c3];
  int a3row = (mt3*32 + pl)*68;
  // produce4 mapping: wave -> col-tile w (c4 = 32w..32w+31), mt4 looped
  int c4 = w*32 + pl;
  float sc4 = sc4v[c4], sh4 = sh4v[c4];
  // staging mapping
  int trow = tid >> 3, tc0 = (tid & 7)*8;
  int r0 = blockIdx.x * 320;
  uint4 hreg = *(const uint4*)&H2[(size_t)(r0+trow)*64 + tc0];
  // stage tile 0
  {
    short* dst = &h2s[trow*68 + tc0];
    *(uint2*)dst       = make_uint2(hreg.x, hreg.y);
    *(uint2*)(dst + 4) = make_uint2(hreg.z, hreg.w);
  }
  hreg = *(const uint4*)&H2[(size_t)(r0 + 64 + trow)*64 + tc0];
  __syncthreads();
  for (int t=0; t<5; ++t){
    // ---- produce3: H3tile(64x128) = relu(bn3(H2tile @ W3)) ----
    {
      floatx16 pa;
      #pragma unroll
      for (int q=0;q<16;++q) pa[q]=0.f;
      #pragma unroll
      for (int kq=0;kq<4;++kq){
        Frag a; FragQ b;
        const short* ap = &h2s[a3row + kq*16 + ko];
        a.u2[0] = *(const uint2*)ap;  a.u2[1] = *(const uint2*)(ap+4);
        b.q = *(const uint4*)&W3T[(size_t)c3*64 + kq*16 + ko];
        pa = __builtin_amdgcn_mfma_f32_32x32x16_bf16(a.v, b.v, pa, 0, 0, 0);
      }
      #pragma unroll
      for (int r=0;r<16;++r){
        int m = mt3*32 + (r&3) + 8*(r>>2) + rbase;
        float v = fmaxf(fmaf(pa[r], sc3, sh3), 0.f);
        h3s[m*132 + c3] = (short)f2bu(v);
      }
    }
    __syncthreads();
    // ---- produce4: H4tile(64x256) = relu(bn4(H3tile @ W4)) ----
    #pragma unroll
    for (int mt4=0; mt4<2; ++mt4){
      floatx16 acc;
      #pragma unroll
      for (int q=0;q<16;++q) acc[q]=0.f;
      int a4row = (mt4*32 + pl)*132;
      #pragma unroll
      for (int kq=0;kq<8;++kq){
        Frag a; FragQ b;
        const short* ap = &h3s[a4row + kq*16 + ko];
        a.u2[0] = *(const uint2*)ap;  a.u2[1] = *(const uint2*)(ap+4);
        b.q = *(const uint4*)&W4T[(size_t)c4*128 + kq*16 + ko];
        acc = __builtin_amdgcn_mfma_f32_32x32x16_bf16(a.v, b.v, acc, 0, 0, 0);
      }
      #pragma unroll
      for (int r=0;r<16;++r){
        int m = mt4*32 + (r&3) + 8*(r>>2) + rbase;
        float v = fmaxf(fmaf(acc[r], sc4, sh4), 0.f);
        h4s[m*256 + c4] = f2bu(v);
      }
    }
    __syncthreads();
    // ---- stage tile t+1 (overlapped with scan) ----
    if (t < 4){
      short* dst = &h2s[trow*68 + tc0];
      *(uint2*)dst       = make_uint2(hreg.x, hreg.y);
      *(uint2*)(dst + 4) = make_uint2(hreg.z, hreg.w);
      if (t < 3) hreg = *(const uint4*)&H2[(size_t)(r0 + (t+2)*64 + trow)*64 + tc0];
    }
    // ---- per-column maxpool scan (single owner per column -> no races/atomics) ----
    {
      int lr0 = t*64;
      if (tid < 256){
        int c = tid;
        int p = lr0/20;
        int nb = (p+1)*20 - lr0;
        unsigned ml = 0;
        for (int r=0;r<64;++r){
          unsigned v = h4s[r*256 + c];
          ml = v > ml ? v : ml;
          if (--nb == 0){
            unsigned short* mp = &mx4u[p*256 + c];
            unsigned cur = *mp;
            if (ml > cur) *mp = (unsigned short)ml;
            ml = 0; ++p; nb = 20;
          }
        }
        if (nb != 20){
          unsigned short* mp = &mx4u[p*256 + c];
          unsigned cur = *mp;
          if (ml > cur) *mp = (unsigned short)ml;
        }
      } else if (tid < 384){
        int c = tid - 256;
        int p = lr0/20;
        int nb = (p+1)*20 - lr0;
        unsigned ml = 0;
        for (int r=0;r<64;++r){
          unsigned v = (unsigned)(unsigned short)h3s[r*132 + c];
          ml = v > ml ? v : ml;
          if (--nb == 0){
            unsigned short* mp = &mx3u[p*128 + c];
            unsigned cur = *mp;
            if (ml > cur) *mp = (unsigned short)ml;
            ml = 0; ++p; nb = 20;
          }
        }
        if (nb != 20){
          unsigned short* mp = &mx3u[p*128 + c];
          unsigned cur = *mp;
          if (ml > cur) *mp = (unsigned short)ml;
        }
      }
    }
    __syncthreads();
  }
  // ---- write x3/x4 maxima to cat ----
  int bn0 = blockIdx.x*16;
  {
    int p = tid >> 5, c0 = (tid & 31)*8;
    uint4 v = *(const uint4*)&mx4u[p*256 + c0];
    *(uint4*)&cat[(size_t)(bn0+p)*512 + 256 + c0] = v;
  }
  if (tid < 256){
    int p = tid >> 4, c0 = (tid & 15)*8;
    uint4 v = *(const uint4*)&mx3u[p*128 + c0];
    *(uint4*)&cat[(size_t)(bn0+p)*512 + 128 + c0] = v;
  }
}

// ---------------- layer 5: 16 rows/block ----------------
__global__ __launch_bounds__(256) void l5_kernel(const bf16* __restrict__ cat,
                                                const float* __restrict__ Wf,
                                                const float* __restrict__ scale,
                                                const float* __restrict__ shift,
                                                float* __restrict__ out){
  __shared__ float cr[16][512];
  __shared__ float ob[16][512];
  int tid = threadIdx.x;
  int bn0 = blockIdx.x*16;
  for (int v=tid; v<1024; v+=256){
    int row = v>>6, c0 = (v&63)*8;
    U4b u; u.q = *(const uint4*)&cat[(size_t)(bn0+row)*512 + c0];
    float f[8];
    #pragma unroll
    for (int j=0;j<8;++j) f[j] = bits2f(u.s[j]);
    *(float4*)&cr[row][c0]   = make_float4(f[0],f[1],f[2],f[3]);
    *(float4*)&cr[row][c0+4] = make_float4(f[4],f[5],f[6],f[7]);
  }
  __syncthreads();
  int rp = tid >> 6, cg = tid & 63, c0 = cg*8;
  int ra = rp*4;
  float acc[4][8];
  #pragma unroll
  for (int r=0;r<4;++r)
    #pragma unroll
    for (int cb=0;cb<8;++cb) acc[r][cb]=0.f;
  for (int i=0;i<512;++i){
    float h0 = cr[ra][i], h1 = cr[ra+1][i], h2v = cr[ra+2][i], h3 = cr[ra+3][i];
    const float* wp = Wf + (size_t)i*512 + c0;
    float4 wa = *(const float4*)wp;
    float4 wb = *(const float4*)(wp+4);
    float w[8] = {wa.x,wa.y,wa.z,wa.w,wb.x,wb.y,wb.z,wb.w};
    #pragma unroll
    for (int k=0;k<8;++k){
      acc[0][k] = fmaf(h0, w[k], acc[0][k]);
      acc[1][k] = fmaf(h1, w[k], acc[1][k]);
      acc[2][k] = fmaf(h2v, w[k], acc[2][k]);
      acc[3][k] = fmaf(h3, w[k], acc[3][k]);
    }
  }
  float sc[8], sh[8];
  #pragma unroll
  for (int k=0;k<8;++k){ sc[k]=scale[c0+k]; sh[k]=shift[c0+k]; }
  #pragma unroll
  for (int r=0;r<4;++r)
    #pragma unroll
    for (int k=0;k<8;++k)
      ob[ra+r][c0+k] = fmaxf(fmaf(acc[r][k], sc[k], sh[k]), 0.f);
  __syncthreads();
  int b = bn0 >> 12, n0 = bn0 & 4095;
  for (int u=tid; u<512; u+=256){
    float* op = out + ((size_t)b*512 + u)*4096 + n0;
    #pragma unroll
    for (int g=0; g<4; ++g){
      float4 v = make_float4(ob[g*4][u], ob[g*4+1][u], ob[g*4+2][u], ob[g*4+3][u]);
      *(float4*)(op + g*4) = v;
    }
  }
}

extern "C" void kernel_launch(void* const* d_in, const int* in_sizes, int n_in,
                              void* d_out, int out_size, void* d_ws, size_t ws_size,
                              hipStream_t stream){
  const float* x   = (const float*)d_in[0];
  const float* W1f = (const float*)d_in[1];
  const float* W2f = (const float*)d_in[2];
  const float* W3f = (const float*)d_in[3];
  const float* W4f = (const float*)d_in[4];
  const float* W5f = (const float*)d_in[5];
  const float* g1=(const float*)d_in[6],  *b1=(const float*)d_in[7];
  const float* g2=(const float*)d_in[8],  *b2=(const float*)d_in[9];
  const float* g3=(const float*)d_in[10], *b3=(const float*)d_in[11];
  const float* g4=(const float*)d_in[12], *b4=(const float*)d_in[13];
  const float* g5=(const float*)d_in[14], *b5=(const float*)d_in[15];
  float* out = (float*)d_out;

  char* w = (char*)d_ws;
  size_t off = 0;
  auto alloc = [&](size_t bytes)->void*{
    void* p = w + off;
    off = (off + bytes + 255) & ~(size_t)255;
    return p;
  };

  int*  idxb = (int*) alloc((size_t)BN*Kk*4);
  bf16* H2   = (bf16*)alloc((size_t)Mrows*64*2);
  bf16* catb = (bf16*)alloc((size_t)BN*512*2);
  bf16* W3T  = (bf16*)alloc((size_t)128*64*2);
  bf16* W4T  = (bf16*)alloc((size_t)256*128*2);
  float* pv  = (float*)H2;
  int*   pib = (int*)((char*)H2 + (size_t)BN*4*Kk*4);

  size_t statsStart = off;
  float* partf=(float*)alloc(256*48*4);
  float* Gf=(float*)alloc(36*4);
  float* sumf=(float*)alloc(8*4);
  float* G2=(float*)alloc(4096*4);   float* sum2=(float*)alloc(64*4);
  float* G3=(float*)alloc(4096*4);   float* sum3=(float*)alloc(64*4);
  float* G4=(float*)alloc(16384*4);  float* sum4=(float*)alloc(128*4);
  float* G5=(float*)alloc(262144*4); float* sum5=(float*)alloc(512*4);
  float* P1=(float*)alloc(384*4);
  float* P2=(float*)alloc(4096*4);
  float* P3=(float*)alloc(8192*4);
  float* P4=(float*)alloc(32768*4);
  float* P5=(float*)alloc(262144*4);
  float* sc1=(float*)alloc(64*4);   float* sh1=(float*)alloc(64*4);
  float* sc2=(float*)alloc(64*4);   float* sh2=(float*)alloc(64*4);
  float* sc3=(float*)alloc(128*4);  float* sh3=(float*)alloc(128*4);
  float* sc4=(float*)alloc(256*4);  float* sh4=(float*)alloc(256*4);
  float* sc5=(float*)alloc(512*4);  float* sh5=(float*)alloc(512*4);
  size_t statsEnd = off;

  int statsFloats = (int)((statsEnd - statsStart)/4);
  zero_kernel<<<(statsFloats+255)/256,256,0,stream>>>((float*)(w+statsStart), statsFloats);
  w3t_kernel<<<32,256,0,stream>>>(W3f, W3T);
  w4t_kernel<<<128,256,0,stream>>>(W4f, W4T);

  knnA_kernel<<<512,256,0,stream>>>(x, pv, pib);
  knnB_kernel<<<BN/256,256,0,stream>>>(pv, pib, idxb);

  const float invM  = 1.0f/(float)Mrows;
  const float invM5 = 1.0f/(float)BN;

  gramf_kernel<<<256,256,0,stream>>>(x, idxb, partf);
  reducef_kernel<<<1,64,0,stream>>>(partf, Gf, sumf);
  kP_kernel<<<2,256,0,stream>>>(Gf, W1f, P1, 6, 64);
  kFinal_kernel<<<1,256,0,stream>>>(P1, sumf, W1f, g1, b1, sc1, sh1, 6, 64, invM);

  stats2_kernel<<<512,512,0,stream>>>(x, idxb, W1f, sc1, sh1, G2, sum2);
  kP_kernel<<<16,256,0,stream>>>(G2, W2f, P2, 64, 64);
  kFinal_kernel<<<1,256,0,stream>>>(P2, sum2, W2f, g2, b2, sc2, sh2, 64, 64, invM);

  fl12_kernel<<<BN,64,0,stream>>>(x, idxb, W1f, sc1, sh1, W2f, sc2, sh2, H2, catb);

  colsum_kernel<64,bf16><<<512,256,0,stream>>>(H2, Mrows, sum3);
  gramM_kernel<64><<<512,256,0,stream>>>(H2, Mrows, G3);
  kP_kernel<<<32,256,0,stream>>>(G3, W3f, P3, 64, 128);
  kFinal_kernel<<<1,256,0,stream>>>(P3, sum3, W3f, g3, b3, sc3, sh3, 64, 128, invM);

  stats4_kernel<<<512,512,0,stream>>>(H2, W3T, sc3, sh3, G4, sum4);
  kP_kernel<<<128,256,0,stream>>>(G4, W4f, P4, 128, 256);
  kFinal_kernel<<<1,256,0,stream>>>(P4, sum4, W4f, g4, b4, sc4, sh4, 128, 256, invM);

  fl34_kernel<<<Mrows/320,512,0,stream>>>(H2, W3T, sc3, sh3, W4T, sc4, sh4, catb);

  colsum_kernel<512,bf16><<<512,256,0,stream>>>(catb, BN, sum5);
  gramM_kernel<512><<<512,256,0,stream>>>(catb, BN, G5);
  kP_kernel<<<1024,256,0,stream>>>(G5, W5f, P5, 512, 512);
  kFinal_kernel<<<2,256,0,stream>>>(P5, sum5, W5f, g5, b5, sc5, sh5, 512, 512, invM5);
  l5_kernel<<<BN/16,256,0,stream>>>(catb, W5f, sc5, sh5, out);
}

// Round 3
// 1746.256 us; speedup vs baseline: 2.1301x; 1.2692x over previous
//
#include <hip/hip_runtime.h>
#include <hip/hip_bf16.h>
#include <cfloat>

using bf16 = __hip_bfloat16;

typedef short short8 __attribute__((ext_vector_type(8)));
typedef float floatx16 __attribute__((ext_vector_type(16)));
union Frag { short8 v; uint2 u2[2]; };
union FragQ { short8 v; uint4 q; uint2 u2[2]; };
union U4b { uint4 q; unsigned short s[8]; };

constexpr int Bb = 8, Nn = 4096, Kk = 20;
constexpr int BN = Bb * Nn;                     // 32768
constexpr int Mrows = BN * Kk;                  // 655360
constexpr float EPSf = 1e-5f;

static __device__ __forceinline__ float b2f(bf16 v){ return __bfloat162float(v); }
static __device__ __forceinline__ bf16 f2b(float v){ return __float2bfloat16(v); }
static __device__ __forceinline__ unsigned short f2bu(float v){
  union { bf16 b; unsigned short u; } cv; cv.b = __float2bfloat16(v); return cv.u;
}
static __device__ __forceinline__ float bits2f(unsigned short u){
  union { unsigned int i; float f; } c; c.i = ((unsigned)u)<<16; return c.f;
}
static __device__ __forceinline__ float ldf(bf16 v){ return b2f(v); }
static __device__ __forceinline__ float ldf(float v){ return v; }

// ---------------- zero workspace region ----------------
__global__ void zero_kernel(float* __restrict__ p, int n){
  int i = blockIdx.x*256 + threadIdx.x;
  if (i < n) p[i] = 0.f;
}

// ---------------- W3^T bf16 pack ----------------
__global__ void w3t_kernel(const float* __restrict__ W3f, bf16* __restrict__ W3T){
  int id = blockIdx.x*256 + threadIdx.x;   // 128*64 = 8192 elems
  if (id >= 128*64) return;
  int n = id >> 6, k = id & 63;
  W3T[id] = f2b(W3f[(size_t)k*128 + n]);
}

// ---------------- W4^T bf16 pack ----------------
__global__ void w4t_kernel(const float* __restrict__ W4f, bf16* __restrict__ W4T){
  int id = blockIdx.x*256 + threadIdx.x;   // 128*256 = 32768 elems
  if (id >= 128*256) return;
  int k = id >> 8, c = id & 255;           // coalesced read of W4f
  W4T[(size_t)c*128 + k] = f2b(W4f[id]);
}

// ---------------- KNN phase A v2: value-only min/max top-20 + threshold index pass ----
// 8 stripes of 512 candidates; grid 1024 (4 blocks/CU). Pass A keeps top-20 VALUES as
// sortable-u32 via a branchless min/max insert network (39 ops, depth 2, no index chain).
// Pass B rescans with thr=tv[19], collecting local indices (ascending order => stable
// lowest-index tie-break, matching jax top_k). Final: exact (val,idx) insertion sort of
// the ~20 collected entries.
__global__ __launch_bounds__(256) void knnA_kernel(const float* __restrict__ x,
                                                   float* __restrict__ pv, int* __restrict__ pi){
#pragma clang fp contract(off)
  __shared__ float4 p4[512];
  __shared__ unsigned short lst[256*33];
  int blk = blockIdx.x;
  int stripe = blk & 7;
  int chunk  = (blk >> 3) & 15;
  int b      = blk >> 7;
  const float* xb = x + b*3*Nn;
  int j0 = stripe*512;
  for (int u = threadIdx.x; u < 512; u += 256){
    int j = j0 + u;
    float a0 = xb[j];
    float a1 = xb[Nn + j];
    float a2 = xb[2*Nn + j];
    float s = a0*a0; s = s + a1*a1; s = s + a2*a2;
    p4[u] = make_float4(a0, a1, a2, s);
  }
  __syncthreads();
  int i = chunk*256 + threadIdx.x;
  float xi = xb[i], yi = xb[Nn+i], zi = xb[2*Nn+i];
  float ni = xi*xi; ni = ni + yi*yi; ni = ni + zi*zi;
  float mni = -ni;
  // ---- pass A: top-20 values (sortable u32), branchless ----
  unsigned tv[Kk];
  #pragma unroll
  for (int s=0;s<Kk;++s) tv[s] = 0u;
  for (int u=0; u<512; ++u){
    float4 p = p4[u];
    float dot = xi*p.x; dot = dot + yi*p.y; dot = dot + zi*p.z;
    float inner = -2.0f*dot;
    float nd = mni - inner; nd = nd - p.w;
    unsigned ub = __float_as_uint(nd);
    unsigned key = ub ^ (((unsigned)(((int)ub) >> 31)) | 0x80000000u);
    #pragma unroll
    for (int s=Kk-1; s>=1; --s){
      unsigned m = min(tv[s-1], key);
      tv[s] = max(tv[s], m);
    }
    tv[0] = max(tv[0], key);
  }
  // ---- pass B: collect indices with key >= threshold (ascending j => stable) ----
  unsigned thr = tv[Kk-1];
  unsigned short* ml = &lst[threadIdx.x*33];
  int cnt = 0;
  for (int u=0; u<512; ++u){
    float4 p = p4[u];
    float dot = xi*p.x; dot = dot + yi*p.y; dot = dot + zi*p.z;
    float inner = -2.0f*dot;
    float nd = mni - inner; nd = nd - p.w;
    unsigned ub = __float_as_uint(nd);
    unsigned key = ub ^ (((unsigned)(((int)ub) >> 31)) | 0x80000000u);
    if (key >= thr && cnt < 32){ ml[cnt] = (unsigned short)u; ++cnt; }
  }
  // ---- final: exact (val,idx) insertion sort of collected entries ----
  float av[Kk]; int ai[Kk];
  #pragma unroll
  for (int s=0;s<Kk;++s){ av[s] = -FLT_MAX; ai[s] = 0; }
  for (int t=0; t<cnt; ++t){
    int lj = ml[t];
    float4 p = p4[lj];
    float dot = xi*p.x; dot = dot + yi*p.y; dot = dot + zi*p.z;
    float inner = -2.0f*dot;
    float nd = mni - inner; nd = nd - p.w;
    if (nd > av[Kk-1]){
      #pragma unroll
      for (int s=Kk-1; s>=1; --s){
        bool cs = nd > av[s];
        bool cp = nd > av[s-1];
        av[s] = cs ? (cp ? av[s-1] : nd) : av[s];
        ai[s] = cs ? (cp ? ai[s-1] : (j0+lj)) : ai[s];
      }
      if (nd > av[0]){ av[0] = nd; ai[0] = j0+lj; }
    }
  }
  long long base = ((long long)(b*Nn + i)*8 + stripe)*Kk;
  #pragma unroll
  for (int s=0;s<Kk;++s){ pv[base+s] = av[s]; pi[base+s] = ai[s]; }
}

// ---------------- KNN phase B: merge 8 stripes ----------------
__global__ __launch_bounds__(256) void knnB_kernel(const float* __restrict__ pv,
                                                   const int* __restrict__ pi,
                                                   int* __restrict__ idx){
  int p = blockIdx.x*256 + threadIdx.x;
  if (p >= BN) return;
  long long base = (long long)p*8*Kk;
  float av[Kk]; int ai[Kk];
  #pragma unroll
  for (int s=0;s<Kk;++s){ av[s]=pv[base+s]; ai[s]=pi[base+s]; }
  for (int t=Kk; t<8*Kk; ++t){
    float nd = pv[base+t]; int j = pi[base+t];
    if (nd > av[Kk-1]){
      #pragma unroll
      for (int s=Kk-1;s>=1;--s){
        bool cs = nd > av[s];
        bool cp = nd > av[s-1];
        av[s] = cs ? (cp?av[s-1]:nd) : av[s];
        ai[s] = cs ? (cp?ai[s-1]:j) : ai[s];
      }
      if (nd > av[0]){ av[0]=nd; ai[0]=j; }
    }
  }
  #pragma unroll
  for (int s=0;s<Kk;++s) idx[(long long)p*Kk+s] = ai[s];
}

// ---------------- layer-1 feature stats ----------------
__global__ __launch_bounds__(256) void gramf_kernel(const float* __restrict__ x,
                                                    const int* __restrict__ idx,
                                                    float* __restrict__ part){
  float acc[36]; float s6[6];
  #pragma unroll
  for (int a=0;a<36;++a) acc[a]=0.f;
  #pragma unroll
  for (int a=0;a<6;++a) s6[a]=0.f;
  for (long long row = blockIdx.x*256 + threadIdx.x; row < Mrows; row += (long long)gridDim.x*256){
    int bn = (int)(row / Kk);
    int b = bn >> 12, n = bn & 4095;
    int j = idx[row];
    const float* xb = x + b*3*Nn;
    float f[6];
    f[0]=xb[j];  f[1]=xb[Nn+j];  f[2]=xb[2*Nn+j];
    f[3]=xb[n];  f[4]=xb[Nn+n];  f[5]=xb[2*Nn+n];
    #pragma unroll
    for (int a=0;a<6;++a){
      s6[a] += f[a];
      #pragma unroll
      for (int c=0;c<6;++c) acc[a*6+c] = fmaf(f[a], f[c], acc[a*6+c]);
    }
  }
  __shared__ float red[256];
  for (int v=0; v<42; ++v){
    red[threadIdx.x] = (v<36)? acc[v] : s6[v-36];
    __syncthreads();
    for (int s=128; s>0; s>>=1){
      if (threadIdx.x < s) red[threadIdx.x] += red[threadIdx.x+s];
      __syncthreads();
    }
    if (threadIdx.x==0) part[blockIdx.x*48 + v] = red[0];
    __syncthreads();
  }
}

__global__ void reducef_kernel(const float* __restrict__ part, float* __restrict__ Gf,
                               float* __restrict__ sumf){
  int t = threadIdx.x;
  if (t < 42){
    float s = 0.f;
    for (int i=0;i<256;++i) s += part[i*48 + t];
    if (t<36) Gf[t]=s; else sumf[t-36]=s;
  }
}

// ---------------- MFMA Gram: G = H^T H over bf16 H ----------------
template<int CIN>
__global__ __launch_bounds__(256) void gramM_kernel(const bf16* __restrict__ H, int M,
                                                    float* __restrict__ G){
  constexpr int Tt = CIN/64;
  int tile = blockIdx.x % (Tt*Tt);
  int chunk = blockIdx.x / (Tt*Tt);
  int nchunks = gridDim.x / (Tt*Tt);
  int tr = tile / Tt, tc = tile % Tt;
  bool diag = (tr == tc);
  __shared__ short HTa[64*68];
  __shared__ short HTb[64*68];
  int rpc = M / nchunks;
  int r0 = chunk*rpc;
  int tid = threadIdx.x, lane = tid & 63, w = tid >> 6;
  int mt = w >> 1, nt = w & 1;
  floatx16 acc;
  #pragma unroll
  for (int q=0;q<16;++q) acc[q]=0.f;
  const short* Bbase = diag ? HTa : HTb;
  int arow = (mt*32 + (lane&31))*68;
  int brow = (nt*32 + (lane&31))*68;
  int ko = (lane>>5)*8;
  for (int rb=r0; rb<r0+rpc; rb+=64){
    #pragma unroll
    for (int s=0;s<2;++s){
      int e = tid + s*256;
      int row = e >> 3, c0 = (e & 7)*8;
      U4b va; va.q = *(const uint4*)&H[(size_t)(rb+row)*CIN + tr*64 + c0];
      #pragma unroll
      for (int j=0;j<8;++j) HTa[(c0+j)*68 + row] = (short)va.s[j];
      if (!diag){
        U4b vb; vb.q = *(const uint4*)&H[(size_t)(rb+row)*CIN + tc*64 + c0];
        #pragma unroll
        for (int j=0;j<8;++j) HTb[(c0+j)*68 + row] = (short)vb.s[j];
      }
    }
    __syncthreads();
    #pragma unroll
    for (int kc=0;kc<64;kc+=16){
      Frag a, b;
      const short* ap = &HTa[arow + kc + ko];
      const short* bp = &Bbase[brow + kc + ko];
      a.u2[0] = *(const uint2*)ap;  a.u2[1] = *(const uint2*)(ap+4);
      b.u2[0] = *(const uint2*)bp;  b.u2[1] = *(const uint2*)(bp+4);
      acc = __builtin_amdgcn_mfma_f32_32x32x16_bf16(a.v, b.v, acc, 0, 0, 0);
    }
    __syncthreads();
  }
  int col = lane & 31, rbase = 4*(lane>>5);
  #pragma unroll
  for (int r=0;r<16;++r){
    int row = (r&3) + 8*(r>>2) + rbase;
    atomicAdd(&G[(size_t)(tr*64 + mt*32 + row)*CIN + tc*64 + nt*32 + col], acc[r]);
  }
}

// ---------------- column sums of H ----------------
template<int CIN, typename T>
__global__ __launch_bounds__(256) void colsum_kernel(const T* __restrict__ H, int M,
                                                     float* __restrict__ sumh){
  int rpb = (M + gridDim.x - 1)/gridDim.x;
  int r0 = blockIdx.x*rpb, r1 = min(M, r0+rpb);
  if constexpr (CIN <= 256){
    constexpr int RP = 256/CIN;
    int c = threadIdx.x % CIN;
    int sub = threadIdx.x / CIN;
    float a = 0.f;
    for (int r=r0+sub; r<r1; r+=RP) a += ldf(H[(size_t)r*CIN + c]);
    atomicAdd(&sumh[c], a);
  } else {
    float a0=0.f, a1=0.f;
    for (int r=r0;r<r1;++r){
      a0 += ldf(H[(size_t)r*CIN + threadIdx.x]);
      a1 += ldf(H[(size_t)r*CIN + threadIdx.x + 256]);
    }
    atomicAdd(&sumh[threadIdx.x], a0);
    atomicAdd(&sumh[threadIdx.x+256], a1);
  }
}

// ---------------- P = G @ W ----------------
__global__ void kP_kernel(const float* __restrict__ G, const float* __restrict__ Wf,
                          float* __restrict__ P, int Cin, int Cout){
  int id = blockIdx.x*256 + threadIdx.x;
  if (id >= Cin*Cout) return;
  int i = id / Cout, j = id - i*Cout;
  float s = 0.f;
  for (int k=0;k<Cin;++k) s = fmaf(G[(size_t)i*Cin+k], Wf[(size_t)k*Cout+j], s);
  P[id] = s;
}

// ---------------- scale/shift from Gram-derived BN stats ----------------
__global__ void kFinal_kernel(const float* __restrict__ P, const float* __restrict__ sumh,
                              const float* __restrict__ Wf, const float* __restrict__ g,
                              const float* __restrict__ bb, float* __restrict__ scale,
                              float* __restrict__ shift, int Cin, int Cout, float invM){
  int j = blockIdx.x*256 + threadIdx.x;
  if (j >= Cout) return;
  float mean=0.f, e2=0.f;
  for (int i=0;i<Cin;++i){
    float w = Wf[(size_t)i*Cout + j];
    mean = fmaf(sumh[i], w, mean);
    e2   = fmaf(w, P[(size_t)i*Cout + j], e2);
  }
  mean *= invM; e2 *= invM;
  float var = e2 - mean*mean;
  float inv = rsqrtf(var + EPSf);
  float sc = g[j]*inv;
  scale[j]=sc;
  shift[j]=bb[j] - mean*sc;
}

// ---------------- layer-2 stats ----------------
__global__ __launch_bounds__(512) void stats2_kernel(const float* __restrict__ x,
    const int* __restrict__ idx, const float* __restrict__ W1f,
    const float* __restrict__ sc1v, const float* __restrict__ sh1v,
    float* __restrict__ G2, float* __restrict__ sum2){
  __shared__ float W1s[6][64];
  __shared__ float fsh[64][8];
  __shared__ short H1T[64*68];
  __shared__ float csum[64];
  int tid = threadIdx.x, lane = tid & 63, w = tid >> 6;   // 8 waves
  if (tid < 384) W1s[tid>>6][tid&63] = W1f[tid];
  if (tid < 64) csum[tid] = 0.f;
  int rp = tid >> 4, cq = tid & 15, c0 = cq*4;
  float sca[4], sha[4];
  #pragma unroll
  for (int k=0;k<4;++k){ sca[k]=sc1v[c0+k]; sha[k]=sh1v[c0+k]; }
  int mt = w & 1, nt = (w>>1) & 1, kh = w >> 2;
  int arow = (mt*32 + (lane&31))*68;
  int brow = (nt*32 + (lane&31))*68;
  int ko = (lane>>5)*8;
  floatx16 acc;
  #pragma unroll
  for (int q=0;q<16;++q) acc[q]=0.f;
  float cs[4] = {0.f,0.f,0.f,0.f};
  int rpc = Mrows / gridDim.x;
  int r0 = blockIdx.x * rpc;
  __syncthreads();
  for (int rb=r0; rb<r0+rpc; rb+=64){
    {
      int r = tid>>3, e = tid&7;
      if (e < 6){
        int grow = rb + r;
        int bn = grow / Kk;
        int b = bn >> 12, n = bn & 4095;
        int j = idx[grow];
        const float* xb = x + b*3*Nn;
        fsh[r][e] = (e<3) ? xb[e*Nn + j] : xb[(e-3)*Nn + n];
      }
    }
    __syncthreads();
    {
      float y0[4]={0,0,0,0}, y1[4]={0,0,0,0};
      int ra = rp*2, rbw = rp*2+1;
      #pragma unroll
      for (int i=0;i<6;++i){
        float fa = fsh[ra][i], fb = fsh[rbw][i];
        float4 wv = *(const float4*)&W1s[i][c0];
        y0[0]=fmaf(fa,wv.x,y0[0]); y0[1]=fmaf(fa,wv.y,y0[1]);
        y0[2]=fmaf(fa,wv.z,y0[2]); y0[3]=fmaf(fa,wv.w,y0[3]);
        y1[0]=fmaf(fb,wv.x,y1[0]); y1[1]=fmaf(fb,wv.y,y1[1]);
        y1[2]=fmaf(fb,wv.z,y1[2]); y1[3]=fmaf(fb,wv.w,y1[3]);
      }
      #pragma unroll
      for (int k=0;k<4;++k){
        float va = fmaxf(fmaf(y0[k],sca[k],sha[k]),0.f);
        float vb = fmaxf(fmaf(y1[k],sca[k],sha[k]),0.f);
        cs[k] += va; cs[k] += vb;
        unsigned int pk = f2bu(va) | ((unsigned)f2bu(vb)<<16);
        *(unsigned int*)&H1T[(c0+k)*68 + ra] = pk;
      }
    }
    __syncthreads();
    {
      int kc = kh*32;
      #pragma unroll
      for (int s=0;s<2;++s){
        Frag a, b;
        const short* ap = &H1T[arow + kc + s*16 + ko];
        const short* bp = &H1T[brow + kc + s*16 + ko];
        a.u2[0] = *(const uint2*)ap;  a.u2[1] = *(const uint2*)(ap+4);
        b.u2[0] = *(const uint2*)bp;  b.u2[1] = *(const uint2*)(bp+4);
        acc = __builtin_amdgcn_mfma_f32_32x32x16_bf16(a.v, b.v, acc, 0, 0, 0);
      }
    }
    __syncthreads();
  }
  int col = lane & 31, rbase = 4*(lane>>5);
  #pragma unroll
  for (int r=0;r<16;++r){
    int row = (r&3) + 8*(r>>2) + rbase;
    atomicAdd(&G2[(size_t)(mt*32+row)*64 + nt*32+col], acc[r]);
  }
  #pragma unroll
  for (int k=0;k<4;++k) atomicAdd(&csum[c0+k], cs[k]);
  __syncthreads();
  if (tid < 64) atomicAdd(&sum2[tid], csum[tid]);
}

// ---------------- fused layers 1+2 ----------------
__global__ __launch_bounds__(64) void fl12_kernel(const float* __restrict__ x,
    const int* __restrict__ idx, const float* __restrict__ W1f,
    const float* __restrict__ sc1v, const float* __restrict__ sh1v,
    const float* __restrict__ W2f, const float* __restrict__ sc2v,
    const float* __restrict__ sh2v, bf16* __restrict__ H2, bf16* __restrict__ cat){
  __shared__ float fsh[Kk][6];
  __shared__ float h1[Kk][64];
  __shared__ float mm[4][64];
  int bn = blockIdx.x, b = bn>>12, n = bn & 4095;
  int tid = threadIdx.x;
  if (tid < Kk){
    int j = idx[(size_t)bn*Kk + tid];
    const float* xb = x + b*3*Nn;
    fsh[tid][0]=xb[j]; fsh[tid][1]=xb[Nn+j]; fsh[tid][2]=xb[2*Nn+j];
    fsh[tid][3]=xb[n]; fsh[tid][4]=xb[Nn+n]; fsh[tid][5]=xb[2*Nn+n];
  }
  __syncthreads();
  {
    float sc=sc1v[tid], sh=sh1v[tid];
    float w[6];
    #pragma unroll
    for (int i=0;i<6;++i) w[i]=W1f[i*64+tid];
    float mx = 0.f;
    #pragma unroll
    for (int r=0;r<Kk;++r){
      float y=0.f;
      #pragma unroll
      for (int i=0;i<6;++i) y = fmaf(fsh[r][i], w[i], y);
      float v = fmaxf(fmaf(y,sc,sh),0.f);
      h1[r][tid]=v;
      mx = fmaxf(mx,v);
    }
    cat[(size_t)bn*512 + tid] = f2b(mx);
  }
  __syncthreads();
  int q = tid >> 4, c0 = (tid & 15)*4;
  float acc[5][4]={};
  for (int i0=0;i0<64;i0+=4){
    float hv[5][4];
    #pragma unroll
    for (int l=0;l<5;++l){
      float4 t4 = *(const float4*)&h1[q*5+l][i0];
      hv[l][0]=t4.x; hv[l][1]=t4.y; hv[l][2]=t4.z; hv[l][3]=t4.w;
    }
    #pragma unroll
    for (int ii=0;ii<4;++ii){
      const float* wp = W2f + (i0+ii)*64 + c0;
      float w0=wp[0],w1=wp[1],w2=wp[2],w3=wp[3];
      #pragma unroll
      for (int l=0;l<5;++l){
        float hvv=hv[l][ii];
        acc[l][0]=fmaf(hvv,w0,acc[l][0]);
        acc[l][1]=fmaf(hvv,w1,acc[l][1]);
        acc[l][2]=fmaf(hvv,w2,acc[l][2]);
        acc[l][3]=fmaf(hvv,w3,acc[l][3]);
      }
    }
  }
  float sc[4],sh[4];
  #pragma unroll
  for (int cb=0;cb<4;++cb){ sc[cb]=sc2v[c0+cb]; sh[cb]=sh2v[c0+cb]; }
  float mx[4]={0,0,0,0};
  #pragma unroll
  for (int l=0;l<5;++l){
    unsigned short us[4];
    #pragma unroll
    for (int cb=0;cb<4;++cb){
      float v=fmaxf(fmaf(acc[l][cb],sc[cb],sh[cb]),0.f);
      mx[cb]=fmaxf(mx[cb],v);
      us[cb]=f2bu(v);
    }
    uint2 v2; v2.x = us[0]|((unsigned)us[1]<<16); v2.y=us[2]|((unsigned)us[3]<<16);
    *(uint2*)(H2 + ((size_t)bn*Kk + q*5+l)*64 + c0) = v2;
  }
  #pragma unroll
  for (int cb=0;cb<4;++cb) mm[q][c0+cb]=mx[cb];
  __syncthreads();
  {
    float M0 = fmaxf(fmaxf(mm[0][tid],mm[1][tid]),fmaxf(mm[2][tid],mm[3][tid]));
    cat[(size_t)bn*512 + 64 + tid] = f2b(M0);
  }
}

// ---------------- layer-4 stats: MFMA produce + MFMA Gram ----------------
__global__ __launch_bounds__(512) void stats4_kernel(const bf16* __restrict__ H2,
    const bf16* __restrict__ W3T, const float* __restrict__ sc3v, const float* __restrict__ sh3v,
    float* __restrict__ G4, float* __restrict__ sum4){
  __shared__ short h2s[64*68];
  __shared__ short H3T[128*68];
  __shared__ float csum[128];
  int tid = threadIdx.x, lane = tid & 63, w = tid >> 6;   // 8 waves
  if (tid < 128) csum[tid] = 0.f;
  int trow = tid >> 3, tc0 = (tid & 7)*8;
  int pl  = lane & 31;
  int ko  = (lane >> 5)*8;
  int pmt = w >> 2, pnt = w & 3;
  int parow = (pmt*32 + pl)*68;
  int pcol  = pnt*32 + pl;
  float psc = sc3v[pcol], psh = sh3v[pcol];
  int prbase = 4*(lane>>5);
  FragQ bfr[4];
  #pragma unroll
  for (int kq=0;kq<4;++kq)
    bfr[kq].q = *(const uint4*)&W3T[(size_t)pcol*64 + kq*16 + ko];
  int gmt = w>>1, gnt0 = (w&1)*2, gnt1 = gnt0+1;
  int garow  = (gmt*32 + pl)*68;
  int gbrow0 = (gnt0*32 + pl)*68;
  int gbrow1 = (gnt1*32 + pl)*68;
  floatx16 acc0, acc1;
  #pragma unroll
  for (int q=0;q<16;++q){ acc0[q]=0.f; acc1[q]=0.f; }
  float cs = 0.f;
  int rpc = Mrows / gridDim.x;
  int r0 = blockIdx.x * rpc;
  uint4 hreg = *(const uint4*)&H2[(size_t)(r0+trow)*64 + tc0];
  for (int rb=r0; rb<r0+rpc; rb+=64){
    {
      short* dst = &h2s[trow*68 + tc0];
      *(uint2*)dst       = make_uint2(hreg.x, hreg.y);
      *(uint2*)(dst + 4) = make_uint2(hreg.z, hreg.w);
    }
    if (rb + 64 < r0 + rpc)
      hreg = *(const uint4*)&H2[(size_t)(rb+64+trow)*64 + tc0];
    __syncthreads();
    {
      floatx16 pacc;
      #pragma unroll
      for (int q=0;q<16;++q) pacc[q]=0.f;
      #pragma unroll
      for (int kq=0;kq<4;++kq){
        Frag a;
        const short* ap = &h2s[parow + kq*16 + ko];
        a.u2[0] = *(const uint2*)ap;  a.u2[1] = *(const uint2*)(ap+4);
        pacc = __builtin_amdgcn_mfma_f32_32x32x16_bf16(a.v, bfr[kq].v, pacc, 0, 0, 0);
      }
      #pragma unroll
      for (int g=0; g<4; ++g){
        unsigned short p[4];
        #pragma unroll
        for (int r=0;r<4;++r){
          float v = fmaxf(fmaf(pacc[g*4+r], psc, psh), 0.f);
          cs += v;
          p[r] = f2bu(v);
        }
        uint2 pk; pk.x = p[0] | ((unsigned)p[1]<<16); pk.y = p[2] | ((unsigned)p[3]<<16);
        *(uint2*)&H3T[pcol*68 + pmt*32 + 8*g + prbase] = pk;
      }
    }
    __syncthreads();
    #pragma unroll
    for (int kc=0;kc<64;kc+=16){
      Frag a, b0, b1;
      const short* ap  = &H3T[garow  + kc + ko];
      const short* bp0 = &H3T[gbrow0 + kc + ko];
      const short* bp1 = &H3T[gbrow1 + kc + ko];
      a.u2[0]  = *(const uint2*)ap;   a.u2[1]  = *(const uint2*)(ap+4);
      b0.u2[0] = *(const uint2*)bp0;  b0.u2[1] = *(const uint2*)(bp0+4);
      b1.u2[0] = *(const uint2*)bp1;  b1.u2[1] = *(const uint2*)(bp1+4);
      acc0 = __builtin_amdgcn_mfma_f32_32x32x16_bf16(a.v, b0.v, acc0, 0, 0, 0);
      acc1 = __builtin_amdgcn_mfma_f32_32x32x16_bf16(a.v, b1.v, acc1, 0, 0, 0);
    }
  }
  int col = pl;
  #pragma unroll
  for (int r=0;r<16;++r){
    int row = (r&3) + 8*(r>>2) + prbase;
    atomicAdd(&G4[(size_t)(gmt*32+row)*128 + gnt0*32+col], acc0[r]);
    atomicAdd(&G4[(size_t)(gmt*32+row)*128 + gnt1*32+col], acc1[r]);
  }
  atomicAdd(&csum[pcol], cs);
  __syncthreads();
  if (tid < 128) atomicAdd(&sum4[tid], csum[tid]);
}

// ---------------- fused layers 3+4: MFMA produce chain + col-owner maxpool ----------------
__global__ __launch_bounds__(512,4) void fl34_kernel(const bf16* __restrict__ H2,
    const bf16* __restrict__ W3T, const float* __restrict__ sc3v, const float* __restrict__ sh3v,
    const bf16* __restrict__ W4T, const float* __restrict__ sc4v, const float* __restrict__ sh4v,
    bf16* __restrict__ cat){
  __shared__ short h2s[64*68];             // 8.5 KB
  __shared__ short h3s[64*132];            // 16.5 KB
  __shared__ unsigned short h4s[64*256];   // 32 KB
  __shared__ unsigned short mx3u[16*128];  // 4 KB
  __shared__ unsigned short mx4u[16*256];  // 8 KB
  int tid = threadIdx.x, lane = tid & 63, w = tid >> 6;
  int pl = lane & 31;
  int ko = (lane >> 5)*8;
  int rbase = 4*(lane>>5);
  {
    unsigned* p4 = (unsigned*)mx4u;
    for (int u=tid; u<2048; u+=512) p4[u]=0u;
    unsigned* p3 = (unsigned*)mx3u;
    for (int u=tid; u<1024; u+=512) p3[u]=0u;
  }
  int mt3 = w >> 2, ct3 = w & 3;
  int c3 = ct3*32 + pl;
  float sc3 = sc3v[c3], sh3 = sh3v[c3];
  int a3row = (mt3*32 + pl)*68;
  int c4 = w*32 + pl;
  float sc4 = sc4v[c4], sh4 = sh4v[c4];
  int trow = tid >> 3, tc0 = (tid & 7)*8;
  int r0 = blockIdx.x * 320;
  uint4 hreg = *(const uint4*)&H2[(size_t)(r0+trow)*64 + tc0];
  {
    short* dst = &h2s[trow*68 + tc0];
    *(uint2*)dst       = make_uint2(hreg.x, hreg.y);
    *(uint2*)(dst + 4) = make_uint2(hreg.z, hreg.w);
  }
  hreg = *(const uint4*)&H2[(size_t)(r0 + 64 + trow)*64 + tc0];
  __syncthreads();
  for (int t=0; t<5; ++t){
    {
      floatx16 pa;
      #pragma unroll
      for (int q=0;q<16;++q) pa[q]=0.f;
      #pragma unroll
      for (int kq=0;kq<4;++kq){
        Frag a; FragQ b;
        const short* ap = &h2s[a3row + kq*16 + ko];
        a.u2[0] = *(const uint2*)ap;  a.u2[1] = *(const uint2*)(ap+4);
        b.q = *(const uint4*)&W3T[(size_t)c3*64 + kq*16 + ko];
        pa = __builtin_amdgcn_mfma_f32_32x32x16_bf16(a.v, b.v, pa, 0, 0, 0);
      }
      #pragma unroll
      for (int r=0;r<16;++r){
        int m = mt3*32 + (r&3) + 8*(r>>2) + rbase;
        float v = fmaxf(fmaf(pa[r], sc3, sh3), 0.f);
        h3s[m*132 + c3] = (short)f2bu(v);
      }
    }
    __syncthreads();
    #pragma unroll
    for (int mt4=0; mt4<2; ++mt4){
      floatx16 acc;
      #pragma unroll
      for (int q=0;q<16;++q) acc[q]=0.f;
      int a4row = (mt4*32 + pl)*132;
      #pragma unroll
      for (int kq=0;kq<8;++kq){
        Frag a; FragQ b;
        const short* ap = &h3s[a4row + kq*16 + ko];
        a.u2[0] = *(const uint2*)ap;  a.u2[1] = *(const uint2*)(ap+4);
        b.q = *(const uint4*)&W4T[(size_t)c4*128 + kq*16 + ko];
        acc = __builtin_amdgcn_mfma_f32_32x32x16_bf16(a.v, b.v, acc, 0, 0, 0);
      }
      #pragma unroll
      for (int r=0;r<16;++r){
        int m = mt4*32 + (r&3) + 8*(r>>2) + rbase;
        float v = fmaxf(fmaf(acc[r], sc4, sh4), 0.f);
        h4s[m*256 + c4] = f2bu(v);
      }
    }
    __syncthreads();
    if (t < 4){
      short* dst = &h2s[trow*68 + tc0];
      *(uint2*)dst       = make_uint2(hreg.x, hreg.y);
      *(uint2*)(dst + 4) = make_uint2(hreg.z, hreg.w);
      if (t < 3) hreg = *(const uint4*)&H2[(size_t)(r0 + (t+2)*64 + trow)*64 + tc0];
    }
    {
      int lr0 = t*64;
      if (tid < 256){
        int c = tid;
        int p = lr0/20;
        int nb = (p+1)*20 - lr0;
        unsigned ml = 0;
        for (int r=0;r<64;++r){
          unsigned v = h4s[r*256 + c];
          ml = v > ml ? v : ml;
          if (--nb == 0){
            unsigned short* mp = &mx4u[p*256 + c];
            unsigned cur = *mp;
            if (ml > cur) *mp = (unsigned short)ml;
            ml = 0; ++p; nb = 20;
          }
        }
        if (nb != 20){
          unsigned short* mp = &mx4u[p*256 + c];
          unsigned cur = *mp;
          if (ml > cur) *mp = (unsigned short)ml;
        }
      } else if (tid < 384){
        int c = tid - 256;
        int p = lr0/20;
        int nb = (p+1)*20 - lr0;
        unsigned ml = 0;
        for (int r=0;r<64;++r){
          unsigned v = (unsigned)(unsigned short)h3s[r*132 + c];
          ml = v > ml ? v : ml;
          if (--nb == 0){
            unsigned short* mp = &mx3u[p*128 + c];
            unsigned cur = *mp;
            if (ml > cur) *mp = (unsigned short)ml;
            ml = 0; ++p; nb = 20;
          }
        }
        if (nb != 20){
          unsigned short* mp = &mx3u[p*128 + c];
          unsigned cur = *mp;
          if (ml > cur) *mp = (unsigned short)ml;
        }
      }
    }
    __syncthreads();
  }
  int bn0 = blockIdx.x*16;
  {
    int p = tid >> 5, c0 = (tid & 31)*8;
    uint4 v = *(const uint4*)&mx4u[p*256 + c0];
    *(uint4*)&cat[(size_t)(bn0+p)*512 + 256 + c0] = v;
  }
  if (tid < 256){
    int p = tid >> 4, c0 = (tid & 15)*8;
    uint4 v = *(const uint4*)&mx3u[p*128 + c0];
    *(uint4*)&cat[(size_t)(bn0+p)*512 + 128 + c0] = v;
  }
}

// ---------------- layer 5: 16 rows/block ----------------
__global__ __launch_bounds__(256) void l5_kernel(const bf16* __restrict__ cat,
                                                const float* __restrict__ Wf,
                                                const float* __restrict__ scale,
                                                const float* __restrict__ shift,
                                                float* __restrict__ out){
  __shared__ float cr[16][512];
  __shared__ float ob[16][512];
  int tid = threadIdx.x;
  int bn0 = blockIdx.x*16;
  for (int v=tid; v<1024; v+=256){
    int row = v>>6, c0 = (v&63)*8;
    U4b u; u.q = *(const uint4*)&cat[(size_t)(bn0+row)*512 + c0];
    float f[8];
    #pragma unroll
    for (int j=0;j<8;++j) f[j] = bits2f(u.s[j]);
    *(float4*)&cr[row][c0]   = make_float4(f[0],f[1],f[2],f[3]);
    *(float4*)&cr[row][c0+4] = make_float4(f[4],f[5],f[6],f[7]);
  }
  __syncthreads();
  int rp = tid >> 6, cg = tid & 63, c0 = cg*8;
  int ra = rp*4;
  float acc[4][8];
  #pragma unroll
  for (int r=0;r<4;++r)
    #pragma unroll
    for (int cb=0;cb<8;++cb) acc[r][cb]=0.f;
  for (int i=0;i<512;++i){
    float h0 = cr[ra][i], h1 = cr[ra+1][i], h2v = cr[ra+2][i], h3 = cr[ra+3][i];
    const float* wp = Wf + (size_t)i*512 + c0;
    float4 wa = *(const float4*)wp;
    float4 wb = *(const float4*)(wp+4);
    float w[8] = {wa.x,wa.y,wa.z,wa.w,wb.x,wb.y,wb.z,wb.w};
    #pragma unroll
    for (int k=0;k<8;++k){
      acc[0][k] = fmaf(h0, w[k], acc[0][k]);
      acc[1][k] = fmaf(h1, w[k], acc[1][k]);
      acc[2][k] = fmaf(h2v, w[k], acc[2][k]);
      acc[3][k] = fmaf(h3, w[k], acc[3][k]);
    }
  }
  float sc[8], sh[8];
  #pragma unroll
  for (int k=0;k<8;++k){ sc[k]=scale[c0+k]; sh[k]=shift[c0+k]; }
  #pragma unroll
  for (int r=0;r<4;++r)
    #pragma unroll
    for (int k=0;k<8;++k)
      ob[ra+r][c0+k] = fmaxf(fmaf(acc[r][k], sc[k], sh[k]), 0.f);
  __syncthreads();
  int b = bn0 >> 12, n0 = bn0 & 4095;
  for (int u=tid; u<512; u+=256){
    float* op = out + ((size_t)b*512 + u)*4096 + n0;
    #pragma unroll
    for (int g=0; g<4; ++g){
      float4 v = make_float4(ob[g*4][u], ob[g*4+1][u], ob[g*4+2][u], ob[g*4+3][u]);
      *(float4*)(op + g*4) = v;
    }
  }
}

extern "C" void kernel_launch(void* const* d_in, const int* in_sizes, int n_in,
                              void* d_out, int out_size, void* d_ws, size_t ws_size,
                              hipStream_t stream){
  const float* x   = (const float*)d_in[0];
  const float* W1f = (const float*)d_in[1];
  const float* W2f = (const float*)d_in[2];
  const float* W3f = (const float*)d_in[3];
  const float* W4f = (const float*)d_in[4];
  const float* W5f = (const float*)d_in[5];
  const float* g1=(const float*)d_in[6],  *b1=(const float*)d_in[7];
  const float* g2=(const float*)d_in[8],  *b2=(const float*)d_in[9];
  const float* g3=(const float*)d_in[10], *b3=(const float*)d_in[11];
  const float* g4=(const float*)d_in[12], *b4=(const float*)d_in[13];
  const float* g5=(const float*)d_in[14], *b5=(const float*)d_in[15];
  float* out = (float*)d_out;

  char* w = (char*)d_ws;
  size_t off = 0;
  auto alloc = [&](size_t bytes)->void*{
    void* p = w + off;
    off = (off + bytes + 255) & ~(size_t)255;
    return p;
  };

  int*  idxb = (int*) alloc((size_t)BN*Kk*4);
  bf16* H2   = (bf16*)alloc((size_t)Mrows*64*2);
  bf16* catb = (bf16*)alloc((size_t)BN*512*2);
  bf16* W3T  = (bf16*)alloc((size_t)128*64*2);
  bf16* W4T  = (bf16*)alloc((size_t)256*128*2);
  float* pv  = (float*)H2;
  int*   pib = (int*)((char*)H2 + (size_t)BN*8*Kk*4);

  size_t statsStart = off;
  float* partf=(float*)alloc(256*48*4);
  float* Gf=(float*)alloc(36*4);
  float* sumf=(float*)alloc(8*4);
  float* G2=(float*)alloc(4096*4);   float* sum2=(float*)alloc(64*4);
  float* G3=(float*)alloc(4096*4);   float* sum3=(float*)alloc(64*4);
  float* G4=(float*)alloc(16384*4);  float* sum4=(float*)alloc(128*4);
  float* G5=(float*)alloc(262144*4); float* sum5=(float*)alloc(512*4);
  float* P1=(float*)alloc(384*4);
  float* P2=(float*)alloc(4096*4);
  float* P3=(float*)alloc(8192*4);
  float* P4=(float*)alloc(32768*4);
  float* P5=(float*)alloc(262144*4);
  float* sc1=(float*)alloc(64*4);   float* sh1=(float*)alloc(64*4);
  float* sc2=(float*)alloc(64*4);   float* sh2=(float*)alloc(64*4);
  float* sc3=(float*)alloc(128*4);  float* sh3=(float*)alloc(128*4);
  float* sc4=(float*)alloc(256*4);  float* sh4=(float*)alloc(256*4);
  float* sc5=(float*)alloc(512*4);  float* sh5=(float*)alloc(512*4);
  size_t statsEnd = off;

  int statsFloats = (int)((statsEnd - statsStart)/4);
  zero_kernel<<<(statsFloats+255)/256,256,0,stream>>>((float*)(w+statsStart), statsFloats);
  w3t_kernel<<<32,256,0,stream>>>(W3f, W3T);
  w4t_kernel<<<128,256,0,stream>>>(W4f, W4T);

  knnA_kernel<<<1024,256,0,stream>>>(x, pv, pib);
  knnB_kernel<<<BN/256,256,0,stream>>>(pv, pib, idxb);

  const float invM  = 1.0f/(float)Mrows;
  const float invM5 = 1.0f/(float)BN;

  gramf_kernel<<<256,256,0,stream>>>(x, idxb, partf);
  reducef_kernel<<<1,64,0,stream>>>(partf, Gf, sumf);
  kP_kernel<<<2,256,0,stream>>>(Gf, W1f, P1, 6, 64);
  kFinal_kernel<<<1,256,0,stream>>>(P1, sumf, W1f, g1, b1, sc1, sh1, 6, 64, invM);

  stats2_kernel<<<512,512,0,stream>>>(x, idxb, W1f, sc1, sh1, G2, sum2);
  kP_kernel<<<16,256,0,stream>>>(G2, W2f, P2, 64, 64);
  kFinal_kernel<<<1,256,0,stream>>>(P2, sum2, W2f, g2, b2, sc2, sh2, 64, 64, invM);

  fl12_kernel<<<BN,64,0,stream>>>(x, idxb, W1f, sc1, sh1, W2f, sc2, sh2, H2, catb);

  colsum_kernel<64,bf16><<<512,256,0,stream>>>(H2, Mrows, sum3);
  gramM_kernel<64><<<512,256,0,stream>>>(H2, Mrows, G3);
  kP_kernel<<<32,256,0,stream>>>(G3, W3f, P3, 64, 128);
  kFinal_kernel<<<1,256,0,stream>>>(P3, sum3, W3f, g3, b3, sc3, sh3, 64, 128, invM);

  stats4_kernel<<<512,512,0,stream>>>(H2, W3T, sc3, sh3, G4, sum4);
  kP_kernel<<<128,256,0,stream>>>(G4, W4f, P4, 128, 256);
  kFinal_kernel<<<1,256,0,stream>>>(P4, sum4, W4f, g4, b4, sc4, sh4, 128, 256, invM);

  fl34_kernel<<<Mrows/320,512,0,stream>>>(H2, W3T, sc3, sh3, W4T, sc4, sh4, catb);

  colsum_kernel<512,bf16><<<512,256,0,stream>>>(catb, BN, sum5);
  gramM_kernel<512><<<512,256,0,stream>>>(catb, BN, G5);
  kP_kernel<<<1024,256,0,stream>>>(G5, W5f, P5, 512, 512);
  kFinal_kernel<<<2,256,0,stream>>>(P5, sum5, W5f, g5, b5, sc5, sh5, 512, 512, invM5);
  l5_kernel<<<BN/16,256,0,stream>>>(catb, W5f, sc5, sh5, out);
}

// Round 4
// 1563.927 us; speedup vs baseline: 2.3785x; 1.1166x over previous
//
#include <hip/hip_runtime.h>
#include <hip/hip_bf16.h>
#include <cfloat>

using bf16 = __hip_bfloat16;

typedef short short8 __attribute__((ext_vector_type(8)));
typedef float floatx16 __attribute__((ext_vector_type(16)));
union Frag { short8 v; uint2 u2[2]; };
union FragQ { short8 v; uint4 q; uint2 u2[2]; };
union U4b { uint4 q; unsigned short s[8]; };

constexpr int Bb = 8, Nn = 4096, Kk = 20;
constexpr int BN = Bb * Nn;                     // 32768
constexpr int Mrows = BN * Kk;                  // 655360
constexpr float EPSf = 1e-5f;

static __device__ __forceinline__ float b2f(bf16 v){ return __bfloat162float(v); }
static __device__ __forceinline__ bf16 f2b(float v){ return __float2bfloat16(v); }
static __device__ __forceinline__ unsigned short f2bu(float v){
  union { bf16 b; unsigned short u; } cv; cv.b = __float2bfloat16(v); return cv.u;
}
static __device__ __forceinline__ float bits2f(unsigned short u){
  union { unsigned int i; float f; } c; c.i = ((unsigned)u)<<16; return c.f;
}
static __device__ __forceinline__ float ldf(bf16 v){ return b2f(v); }
static __device__ __forceinline__ float ldf(float v){ return v; }

// ---------------- zero workspace region ----------------
__global__ void zero_kernel(float* __restrict__ p, int n){
  int i = blockIdx.x*256 + threadIdx.x;
  if (i < n) p[i] = 0.f;
}

// ---------------- W3^T bf16 pack ----------------
__global__ void w3t_kernel(const float* __restrict__ W3f, bf16* __restrict__ W3T){
  int id = blockIdx.x*256 + threadIdx.x;   // 128*64 = 8192 elems
  if (id >= 128*64) return;
  int n = id >> 6, k = id & 63;
  W3T[id] = f2b(W3f[(size_t)k*128 + n]);
}

// ---------------- W4^T bf16 pack ----------------
__global__ void w4t_kernel(const float* __restrict__ W4f, bf16* __restrict__ W4T){
  int id = blockIdx.x*256 + threadIdx.x;   // 128*256 = 32768 elems
  if (id >= 128*256) return;
  int k = id >> 8, c = id & 255;           // coalesced read of W4f
  W4T[(size_t)c*128 + k] = f2b(W4f[id]);
}

// ---------------- W5^T bf16 pack ----------------
__global__ void w5t_kernel(const float* __restrict__ W5f, bf16* __restrict__ W5T){
  int id = blockIdx.x*256 + threadIdx.x;   // 512*512 = 262144 elems
  if (id >= 512*512) return;
  int k = id >> 9, c = id & 511;           // coalesced read of W5f
  W5T[(size_t)c*512 + k] = f2b(W5f[id]);
}

// ---------------- KNN phase A v2: value-only min/max top-20 + threshold index pass ----
__global__ __launch_bounds__(256) void knnA_kernel(const float* __restrict__ x,
                                                   float* __restrict__ pv, int* __restrict__ pi){
#pragma clang fp contract(off)
  __shared__ float4 p4[512];
  __shared__ unsigned short lst[256*33];
  int blk = blockIdx.x;
  int stripe = blk & 7;
  int chunk  = (blk >> 3) & 15;
  int b      = blk >> 7;
  const float* xb = x + b*3*Nn;
  int j0 = stripe*512;
  for (int u = threadIdx.x; u < 512; u += 256){
    int j = j0 + u;
    float a0 = xb[j];
    float a1 = xb[Nn + j];
    float a2 = xb[2*Nn + j];
    float s = a0*a0; s = s + a1*a1; s = s + a2*a2;
    p4[u] = make_float4(a0, a1, a2, s);
  }
  __syncthreads();
  int i = chunk*256 + threadIdx.x;
  float xi = xb[i], yi = xb[Nn+i], zi = xb[2*Nn+i];
  float ni = xi*xi; ni = ni + yi*yi; ni = ni + zi*zi;
  float mni = -ni;
  unsigned tv[Kk];
  #pragma unroll
  for (int s=0;s<Kk;++s) tv[s] = 0u;
  for (int u=0; u<512; ++u){
    float4 p = p4[u];
    float dot = xi*p.x; dot = dot + yi*p.y; dot = dot + zi*p.z;
    float inner = -2.0f*dot;
    float nd = mni - inner; nd = nd - p.w;
    unsigned ub = __float_as_uint(nd);
    unsigned key = ub ^ (((unsigned)(((int)ub) >> 31)) | 0x80000000u);
    #pragma unroll
    for (int s=Kk-1; s>=1; --s){
      unsigned m = min(tv[s-1], key);
      tv[s] = max(tv[s], m);
    }
    tv[0] = max(tv[0], key);
  }
  unsigned thr = tv[Kk-1];
  unsigned short* ml = &lst[threadIdx.x*33];
  int cnt = 0;
  for (int u=0; u<512; ++u){
    float4 p = p4[u];
    float dot = xi*p.x; dot = dot + yi*p.y; dot = dot + zi*p.z;
    float inner = -2.0f*dot;
    float nd = mni - inner; nd = nd - p.w;
    unsigned ub = __float_as_uint(nd);
    unsigned key = ub ^ (((unsigned)(((int)ub) >> 31)) | 0x80000000u);
    if (key >= thr && cnt < 32){ ml[cnt] = (unsigned short)u; ++cnt; }
  }
  float av[Kk]; int ai[Kk];
  #pragma unroll
  for (int s=0;s<Kk;++s){ av[s] = -FLT_MAX; ai[s] = 0; }
  for (int t=0; t<cnt; ++t){
    int lj = ml[t];
    float4 p = p4[lj];
    float dot = xi*p.x; dot = dot + yi*p.y; dot = dot + zi*p.z;
    float inner = -2.0f*dot;
    float nd = mni - inner; nd = nd - p.w;
    if (nd > av[Kk-1]){
      #pragma unroll
      for (int s=Kk-1; s>=1; --s){
        bool cs = nd > av[s];
        bool cp = nd > av[s-1];
        av[s] = cs ? (cp ? av[s-1] : nd) : av[s];
        ai[s] = cs ? (cp ? ai[s-1] : (j0+lj)) : ai[s];
      }
      if (nd > av[0]){ av[0] = nd; ai[0] = j0+lj; }
    }
  }
  long long base = ((long long)(b*Nn + i)*8 + stripe)*Kk;
  #pragma unroll
  for (int s=0;s<Kk;++s){ pv[base+s] = av[s]; pi[base+s] = ai[s]; }
}

// ---------------- KNN phase B: merge 8 stripes ----------------
__global__ __launch_bounds__(256) void knnB_kernel(const float* __restrict__ pv,
                                                   const int* __restrict__ pi,
                                                   int* __restrict__ idx){
  int p = blockIdx.x*256 + threadIdx.x;
  if (p >= BN) return;
  long long base = (long long)p*8*Kk;
  float av[Kk]; int ai[Kk];
  #pragma unroll
  for (int s=0;s<Kk;++s){ av[s]=pv[base+s]; ai[s]=pi[base+s]; }
  for (int t=Kk; t<8*Kk; ++t){
    float nd = pv[base+t]; int j = pi[base+t];
    if (nd > av[Kk-1]){
      #pragma unroll
      for (int s=Kk-1;s>=1;--s){
        bool cs = nd > av[s];
        bool cp = nd > av[s-1];
        av[s] = cs ? (cp?av[s-1]:nd) : av[s];
        ai[s] = cs ? (cp?ai[s-1]:j) : ai[s];
      }
      if (nd > av[0]){ av[0]=nd; ai[0]=j; }
    }
  }
  #pragma unroll
  for (int s=0;s<Kk;++s) idx[(long long)p*Kk+s] = ai[s];
}

// ---------------- layer-1 feature stats ----------------
__global__ __launch_bounds__(256) void gramf_kernel(const float* __restrict__ x,
                                                    const int* __restrict__ idx,
                                                    float* __restrict__ part){
  float acc[36]; float s6[6];
  #pragma unroll
  for (int a=0;a<36;++a) acc[a]=0.f;
  #pragma unroll
  for (int a=0;a<6;++a) s6[a]=0.f;
  for (long long row = blockIdx.x*256 + threadIdx.x; row < Mrows; row += (long long)gridDim.x*256){
    int bn = (int)(row / Kk);
    int b = bn >> 12, n = bn & 4095;
    int j = idx[row];
    const float* xb = x + b*3*Nn;
    float f[6];
    f[0]=xb[j];  f[1]=xb[Nn+j];  f[2]=xb[2*Nn+j];
    f[3]=xb[n];  f[4]=xb[Nn+n];  f[5]=xb[2*Nn+n];
    #pragma unroll
    for (int a=0;a<6;++a){
      s6[a] += f[a];
      #pragma unroll
      for (int c=0;c<6;++c) acc[a*6+c] = fmaf(f[a], f[c], acc[a*6+c]);
    }
  }
  __shared__ float red[256];
  for (int v=0; v<42; ++v){
    red[threadIdx.x] = (v<36)? acc[v] : s6[v-36];
    __syncthreads();
    for (int s=128; s>0; s>>=1){
      if (threadIdx.x < s) red[threadIdx.x] += red[threadIdx.x+s];
      __syncthreads();
    }
    if (threadIdx.x==0) part[blockIdx.x*48 + v] = red[0];
    __syncthreads();
  }
}

__global__ void reducef_kernel(const float* __restrict__ part, float* __restrict__ Gf,
                               float* __restrict__ sumf){
  int t = threadIdx.x;
  if (t < 42){
    float s = 0.f;
    for (int i=0;i<256;++i) s += part[i*48 + t];
    if (t<36) Gf[t]=s; else sumf[t-36]=s;
  }
}

// ---------------- MFMA Gram: G = H^T H over bf16 H ----------------
template<int CIN>
__global__ __launch_bounds__(256) void gramM_kernel(const bf16* __restrict__ H, int M,
                                                    float* __restrict__ G){
  constexpr int Tt = CIN/64;
  int tile = blockIdx.x % (Tt*Tt);
  int chunk = blockIdx.x / (Tt*Tt);
  int nchunks = gridDim.x / (Tt*Tt);
  int tr = tile / Tt, tc = tile % Tt;
  bool diag = (tr == tc);
  __shared__ short HTa[64*68];
  __shared__ short HTb[64*68];
  int rpc = M / nchunks;
  int r0 = chunk*rpc;
  int tid = threadIdx.x, lane = tid & 63, w = tid >> 6;
  int mt = w >> 1, nt = w & 1;
  floatx16 acc;
  #pragma unroll
  for (int q=0;q<16;++q) acc[q]=0.f;
  const short* Bbase = diag ? HTa : HTb;
  int arow = (mt*32 + (lane&31))*68;
  int brow = (nt*32 + (lane&31))*68;
  int ko = (lane>>5)*8;
  for (int rb=r0; rb<r0+rpc; rb+=64){
    #pragma unroll
    for (int s=0;s<2;++s){
      int e = tid + s*256;
      int row = e >> 3, c0 = (e & 7)*8;
      U4b va; va.q = *(const uint4*)&H[(size_t)(rb+row)*CIN + tr*64 + c0];
      #pragma unroll
      for (int j=0;j<8;++j) HTa[(c0+j)*68 + row] = (short)va.s[j];
      if (!diag){
        U4b vb; vb.q = *(const uint4*)&H[(size_t)(rb+row)*CIN + tc*64 + c0];
        #pragma unroll
        for (int j=0;j<8;++j) HTb[(c0+j)*68 + row] = (short)vb.s[j];
      }
    }
    __syncthreads();
    #pragma unroll
    for (int kc=0;kc<64;kc+=16){
      Frag a, b;
      const short* ap = &HTa[arow + kc + ko];
      const short* bp = &Bbase[brow + kc + ko];
      a.u2[0] = *(const uint2*)ap;  a.u2[1] = *(const uint2*)(ap+4);
      b.u2[0] = *(const uint2*)bp;  b.u2[1] = *(const uint2*)(bp+4);
      acc = __builtin_amdgcn_mfma_f32_32x32x16_bf16(a.v, b.v, acc, 0, 0, 0);
    }
    __syncthreads();
  }
  int col = lane & 31, rbase = 4*(lane>>5);
  #pragma unroll
  for (int r=0;r<16;++r){
    int row = (r&3) + 8*(r>>2) + rbase;
    atomicAdd(&G[(size_t)(tr*64 + mt*32 + row)*CIN + tc*64 + nt*32 + col], acc[r]);
  }
}

// ---------------- column sums of H ----------------
template<int CIN, typename T>
__global__ __launch_bounds__(256) void colsum_kernel(const T* __restrict__ H, int M,
                                                     float* __restrict__ sumh){
  int rpb = (M + gridDim.x - 1)/gridDim.x;
  int r0 = blockIdx.x*rpb, r1 = min(M, r0+rpb);
  if constexpr (CIN <= 256){
    constexpr int RP = 256/CIN;
    int c = threadIdx.x % CIN;
    int sub = threadIdx.x / CIN;
    float a = 0.f;
    for (int r=r0+sub; r<r1; r+=RP) a += ldf(H[(size_t)r*CIN + c]);
    atomicAdd(&sumh[c], a);
  } else {
    float a0=0.f, a1=0.f;
    for (int r=r0;r<r1;++r){
      a0 += ldf(H[(size_t)r*CIN + threadIdx.x]);
      a1 += ldf(H[(size_t)r*CIN + threadIdx.x + 256]);
    }
    atomicAdd(&sumh[threadIdx.x], a0);
    atomicAdd(&sumh[threadIdx.x+256], a1);
  }
}

// ---------------- P = G @ W ----------------
__global__ void kP_kernel(const float* __restrict__ G, const float* __restrict__ Wf,
                          float* __restrict__ P, int Cin, int Cout){
  int id = blockIdx.x*256 + threadIdx.x;
  if (id >= Cin*Cout) return;
  int i = id / Cout, j = id - i*Cout;
  float s = 0.f;
  for (int k=0;k<Cin;++k) s = fmaf(G[(size_t)i*Cin+k], Wf[(size_t)k*Cout+j], s);
  P[id] = s;
}

// ---------------- scale/shift from Gram-derived BN stats ----------------
__global__ void kFinal_kernel(const float* __restrict__ P, const float* __restrict__ sumh,
                              const float* __restrict__ Wf, const float* __restrict__ g,
                              const float* __restrict__ bb, float* __restrict__ scale,
                              float* __restrict__ shift, int Cin, int Cout, float invM){
  int j = blockIdx.x*256 + threadIdx.x;
  if (j >= Cout) return;
  float mean=0.f, e2=0.f;
  for (int i=0;i<Cin;++i){
    float w = Wf[(size_t)i*Cout + j];
    mean = fmaf(sumh[i], w, mean);
    e2   = fmaf(w, P[(size_t)i*Cout + j], e2);
  }
  mean *= invM; e2 *= invM;
  float var = e2 - mean*mean;
  float inv = rsqrtf(var + EPSf);
  float sc = g[j]*inv;
  scale[j]=sc;
  shift[j]=bb[j] - mean*sc;
}

// ---------------- layer-2 stats ----------------
__global__ __launch_bounds__(512) void stats2_kernel(const float* __restrict__ x,
    const int* __restrict__ idx, const float* __restrict__ W1f,
    const float* __restrict__ sc1v, const float* __restrict__ sh1v,
    float* __restrict__ G2, float* __restrict__ sum2){
  __shared__ float W1s[6][64];
  __shared__ float fsh[64][8];
  __shared__ short H1T[64*68];
  __shared__ float csum[64];
  int tid = threadIdx.x, lane = tid & 63, w = tid >> 6;   // 8 waves
  if (tid < 384) W1s[tid>>6][tid&63] = W1f[tid];
  if (tid < 64) csum[tid] = 0.f;
  int rp = tid >> 4, cq = tid & 15, c0 = cq*4;
  float sca[4], sha[4];
  #pragma unroll
  for (int k=0;k<4;++k){ sca[k]=sc1v[c0+k]; sha[k]=sh1v[c0+k]; }
  int mt = w & 1, nt = (w>>1) & 1, kh = w >> 2;
  int arow = (mt*32 + (lane&31))*68;
  int brow = (nt*32 + (lane&31))*68;
  int ko = (lane>>5)*8;
  floatx16 acc;
  #pragma unroll
  for (int q=0;q<16;++q) acc[q]=0.f;
  float cs[4] = {0.f,0.f,0.f,0.f};
  int rpc = Mrows / gridDim.x;
  int r0 = blockIdx.x * rpc;
  __syncthreads();
  for (int rb=r0; rb<r0+rpc; rb+=64){
    {
      int r = tid>>3, e = tid&7;
      if (e < 6){
        int grow = rb + r;
        int bn = grow / Kk;
        int b = bn >> 12, n = bn & 4095;
        int j = idx[grow];
        const float* xb = x + b*3*Nn;
        fsh[r][e] = (e<3) ? xb[e*Nn + j] : xb[(e-3)*Nn + n];
      }
    }
    __syncthreads();
    {
      float y0[4]={0,0,0,0}, y1[4]={0,0,0,0};
      int ra = rp*2, rbw = rp*2+1;
      #pragma unroll
      for (int i=0;i<6;++i){
        float fa = fsh[ra][i], fb = fsh[rbw][i];
        float4 wv = *(const float4*)&W1s[i][c0];
        y0[0]=fmaf(fa,wv.x,y0[0]); y0[1]=fmaf(fa,wv.y,y0[1]);
        y0[2]=fmaf(fa,wv.z,y0[2]); y0[3]=fmaf(fa,wv.w,y0[3]);
        y1[0]=fmaf(fb,wv.x,y1[0]); y1[1]=fmaf(fb,wv.y,y1[1]);
        y1[2]=fmaf(fb,wv.z,y1[2]); y1[3]=fmaf(fb,wv.w,y1[3]);
      }
      #pragma unroll
      for (int k=0;k<4;++k){
        float va = fmaxf(fmaf(y0[k],sca[k],sha[k]),0.f);
        float vb = fmaxf(fmaf(y1[k],sca[k],sha[k]),0.f);
        cs[k] += va; cs[k] += vb;
        unsigned int pk = f2bu(va) | ((unsigned)f2bu(vb)<<16);
        *(unsigned int*)&H1T[(c0+k)*68 + ra] = pk;
      }
    }
    __syncthreads();
    {
      int kc = kh*32;
      #pragma unroll
      for (int s=0;s<2;++s){
        Frag a, b;
        const short* ap = &H1T[arow + kc + s*16 + ko];
        const short* bp = &H1T[brow + kc + s*16 + ko];
        a.u2[0] = *(const uint2*)ap;  a.u2[1] = *(const uint2*)(ap+4);
        b.u2[0] = *(const uint2*)bp;  b.u2[1] = *(const uint2*)(bp+4);
        acc = __builtin_amdgcn_mfma_f32_32x32x16_bf16(a.v, b.v, acc, 0, 0, 0);
      }
    }
    __syncthreads();
  }
  int col = lane & 31, rbase = 4*(lane>>5);
  #pragma unroll
  for (int r=0;r<16;++r){
    int row = (r&3) + 8*(r>>2) + rbase;
    atomicAdd(&G2[(size_t)(mt*32+row)*64 + nt*32+col], acc[r]);
  }
  #pragma unroll
  for (int k=0;k<4;++k) atomicAdd(&csum[c0+k], cs[k]);
  __syncthreads();
  if (tid < 64) atomicAdd(&sum2[tid], csum[tid]);
}

// ---------------- fused layers 1+2 ----------------
__global__ __launch_bounds__(64) void fl12_kernel(const float* __restrict__ x,
    const int* __restrict__ idx, const float* __restrict__ W1f,
    const float* __restrict__ sc1v, const float* __restrict__ sh1v,
    const float* __restrict__ W2f, const float* __restrict__ sc2v,
    const float* __restrict__ sh2v, bf16* __restrict__ H2, bf16* __restrict__ cat){
  __shared__ float fsh[Kk][6];
  __shared__ float h1[Kk][64];
  __shared__ float mm[4][64];
  int bn = blockIdx.x, b = bn>>12, n = bn & 4095;
  int tid = threadIdx.x;
  if (tid < Kk){
    int j = idx[(size_t)bn*Kk + tid];
    const float* xb = x + b*3*Nn;
    fsh[tid][0]=xb[j]; fsh[tid][1]=xb[Nn+j]; fsh[tid][2]=xb[2*Nn+j];
    fsh[tid][3]=xb[n]; fsh[tid][4]=xb[Nn+n]; fsh[tid][5]=xb[2*Nn+n];
  }
  __syncthreads();
  {
    float sc=sc1v[tid], sh=sh1v[tid];
    float w[6];
    #pragma unroll
    for (int i=0;i<6;++i) w[i]=W1f[i*64+tid];
    float mx = 0.f;
    #pragma unroll
    for (int r=0;r<Kk;++r){
      float y=0.f;
      #pragma unroll
      for (int i=0;i<6;++i) y = fmaf(fsh[r][i], w[i], y);
      float v = fmaxf(fmaf(y,sc,sh),0.f);
      h1[r][tid]=v;
      mx = fmaxf(mx,v);
    }
    cat[(size_t)bn*512 + tid] = f2b(mx);
  }
  __syncthreads();
  int q = tid >> 4, c0 = (tid & 15)*4;
  float acc[5][4]={};
  for (int i0=0;i0<64;i0+=4){
    float hv[5][4];
    #pragma unroll
    for (int l=0;l<5;++l){
      float4 t4 = *(const float4*)&h1[q*5+l][i0];
      hv[l][0]=t4.x; hv[l][1]=t4.y; hv[l][2]=t4.z; hv[l][3]=t4.w;
    }
    #pragma unroll
    for (int ii=0;ii<4;++ii){
      const float* wp = W2f + (i0+ii)*64 + c0;
      float w0=wp[0],w1=wp[1],w2=wp[2],w3=wp[3];
      #pragma unroll
      for (int l=0;l<5;++l){
        float hvv=hv[l][ii];
        acc[l][0]=fmaf(hvv,w0,acc[l][0]);
        acc[l][1]=fmaf(hvv,w1,acc[l][1]);
        acc[l][2]=fmaf(hvv,w2,acc[l][2]);
        acc[l][3]=fmaf(hvv,w3,acc[l][3]);
      }
    }
  }
  float sc[4],sh[4];
  #pragma unroll
  for (int cb=0;cb<4;++cb){ sc[cb]=sc2v[c0+cb]; sh[cb]=sh2v[c0+cb]; }
  float mx[4]={0,0,0,0};
  #pragma unroll
  for (int l=0;l<5;++l){
    unsigned short us[4];
    #pragma unroll
    for (int cb=0;cb<4;++cb){
      float v=fmaxf(fmaf(acc[l][cb],sc[cb],sh[cb]),0.f);
      mx[cb]=fmaxf(mx[cb],v);
      us[cb]=f2bu(v);
    }
    uint2 v2; v2.x = us[0]|((unsigned)us[1]<<16); v2.y=us[2]|((unsigned)us[3]<<16);
    *(uint2*)(H2 + ((size_t)bn*Kk + q*5+l)*64 + c0) = v2;
  }
  #pragma unroll
  for (int cb=0;cb<4;++cb) mm[q][c0+cb]=mx[cb];
  __syncthreads();
  {
    float M0 = fmaxf(fmaxf(mm[0][tid],mm[1][tid]),fmaxf(mm[2][tid],mm[3][tid]));
    cat[(size_t)bn*512 + 64 + tid] = f2b(M0);
  }
}

// ---------------- layer-4 stats: MFMA produce + MFMA Gram ----------------
__global__ __launch_bounds__(512) void stats4_kernel(const bf16* __restrict__ H2,
    const bf16* __restrict__ W3T, const float* __restrict__ sc3v, const float* __restrict__ sh3v,
    float* __restrict__ G4, float* __restrict__ sum4){
  __shared__ short h2s[64*68];
  __shared__ short H3T[128*68];
  __shared__ float csum[128];
  int tid = threadIdx.x, lane = tid & 63, w = tid >> 6;   // 8 waves
  if (tid < 128) csum[tid] = 0.f;
  int trow = tid >> 3, tc0 = (tid & 7)*8;
  int pl  = lane & 31;
  int ko  = (lane >> 5)*8;
  int pmt = w >> 2, pnt = w & 3;
  int parow = (pmt*32 + pl)*68;
  int pcol  = pnt*32 + pl;
  float psc = sc3v[pcol], psh = sh3v[pcol];
  int prbase = 4*(lane>>5);
  FragQ bfr[4];
  #pragma unroll
  for (int kq=0;kq<4;++kq)
    bfr[kq].q = *(const uint4*)&W3T[(size_t)pcol*64 + kq*16 + ko];
  int gmt = w>>1, gnt0 = (w&1)*2, gnt1 = gnt0+1;
  int garow  = (gmt*32 + pl)*68;
  int gbrow0 = (gnt0*32 + pl)*68;
  int gbrow1 = (gnt1*32 + pl)*68;
  floatx16 acc0, acc1;
  #pragma unroll
  for (int q=0;q<16;++q){ acc0[q]=0.f; acc1[q]=0.f; }
  float cs = 0.f;
  int rpc = Mrows / gridDim.x;
  int r0 = blockIdx.x * rpc;
  uint4 hreg = *(const uint4*)&H2[(size_t)(r0+trow)*64 + tc0];
  for (int rb=r0; rb<r0+rpc; rb+=64){
    {
      short* dst = &h2s[trow*68 + tc0];
      *(uint2*)dst       = make_uint2(hreg.x, hreg.y);
      *(uint2*)(dst + 4) = make_uint2(hreg.z, hreg.w);
    }
    if (rb + 64 < r0 + rpc)
      hreg = *(const uint4*)&H2[(size_t)(rb+64+trow)*64 + tc0];
    __syncthreads();
    {
      floatx16 pacc;
      #pragma unroll
      for (int q=0;q<16;++q) pacc[q]=0.f;
      #pragma unroll
      for (int kq=0;kq<4;++kq){
        Frag a;
        const short* ap = &h2s[parow + kq*16 + ko];
        a.u2[0] = *(const uint2*)ap;  a.u2[1] = *(const uint2*)(ap+4);
        pacc = __builtin_amdgcn_mfma_f32_32x32x16_bf16(a.v, bfr[kq].v, pacc, 0, 0, 0);
      }
      #pragma unroll
      for (int g=0; g<4; ++g){
        unsigned short p[4];
        #pragma unroll
        for (int r=0;r<4;++r){
          float v = fmaxf(fmaf(pacc[g*4+r], psc, psh), 0.f);
          cs += v;
          p[r] = f2bu(v);
        }
        uint2 pk; pk.x = p[0] | ((unsigned)p[1]<<16); pk.y = p[2] | ((unsigned)p[3]<<16);
        *(uint2*)&H3T[pcol*68 + pmt*32 + 8*g + prbase] = pk;
      }
    }
    __syncthreads();
    #pragma unroll
    for (int kc=0;kc<64;kc+=16){
      Frag a, b0, b1;
      const short* ap  = &H3T[garow  + kc + ko];
      const short* bp0 = &H3T[gbrow0 + kc + ko];
      const short* bp1 = &H3T[gbrow1 + kc + ko];
      a.u2[0]  = *(const uint2*)ap;   a.u2[1]  = *(const uint2*)(ap+4);
      b0.u2[0] = *(const uint2*)bp0;  b0.u2[1] = *(const uint2*)(bp0+4);
      b1.u2[0] = *(const uint2*)bp1;  b1.u2[1] = *(const uint2*)(bp1+4);
      acc0 = __builtin_amdgcn_mfma_f32_32x32x16_bf16(a.v, b0.v, acc0, 0, 0, 0);
      acc1 = __builtin_amdgcn_mfma_f32_32x32x16_bf16(a.v, b1.v, acc1, 0, 0, 0);
    }
  }
  int col = pl;
  #pragma unroll
  for (int r=0;r<16;++r){
    int row = (r&3) + 8*(r>>2) + prbase;
    atomicAdd(&G4[(size_t)(gmt*32+row)*128 + gnt0*32+col], acc0[r]);
    atomicAdd(&G4[(size_t)(gmt*32+row)*128 + gnt1*32+col], acc1[r]);
  }
  atomicAdd(&csum[pcol], cs);
  __syncthreads();
  if (tid < 128) atomicAdd(&sum4[tid], csum[tid]);
}

// ---------------- fused layers 3+4: MFMA produce chain + col-owner maxpool ----------------
__global__ __launch_bounds__(512,4) void fl34_kernel(const bf16* __restrict__ H2,
    const bf16* __restrict__ W3T, const float* __restrict__ sc3v, const float* __restrict__ sh3v,
    const bf16* __restrict__ W4T, const float* __restrict__ sc4v, const float* __restrict__ sh4v,
    bf16* __restrict__ cat){
  __shared__ short h2s[64*68];             // 8.5 KB
  __shared__ short h3s[64*132];            // 16.5 KB
  __shared__ unsigned short h4s[64*256];   // 32 KB
  __shared__ unsigned short mx3u[16*128];  // 4 KB
  __shared__ unsigned short mx4u[16*256];  // 8 KB
  int tid = threadIdx.x, lane = tid & 63, w = tid >> 6;
  int pl = lane & 31;
  int ko = (lane >> 5)*8;
  int rbase = 4*(lane>>5);
  {
    unsigned* p4 = (unsigned*)mx4u;
    for (int u=tid; u<2048; u+=512) p4[u]=0u;
    unsigned* p3 = (unsigned*)mx3u;
    for (int u=tid; u<1024; u+=512) p3[u]=0u;
  }
  int mt3 = w >> 2, ct3 = w & 3;
  int c3 = ct3*32 + pl;
  float sc3 = sc3v[c3], sh3 = sh3v[c3];
  int a3row = (mt3*32 + pl)*68;
  int c4 = w*32 + pl;
  float sc4 = sc4v[c4], sh4 = sh4v[c4];
  int trow = tid >> 3, tc0 = (tid & 7)*8;
  int r0 = blockIdx.x * 320;
  uint4 hreg = *(const uint4*)&H2[(size_t)(r0+trow)*64 + tc0];
  {
    short* dst = &h2s[trow*68 + tc0];
    *(uint2*)dst       = make_uint2(hreg.x, hreg.y);
    *(uint2*)(dst + 4) = make_uint2(hreg.z, hreg.w);
  }
  hreg = *(const uint4*)&H2[(size_t)(r0 + 64 + trow)*64 + tc0];
  __syncthreads();
  for (int t=0; t<5; ++t){
    {
      floatx16 pa;
      #pragma unroll
      for (int q=0;q<16;++q) pa[q]=0.f;
      #pragma unroll
      for (int kq=0;kq<4;++kq){
        Frag a; FragQ b;
        const short* ap = &h2s[a3row + kq*16 + ko];
        a.u2[0] = *(const uint2*)ap;  a.u2[1] = *(const uint2*)(ap+4);
        b.q = *(const uint4*)&W3T[(size_t)c3*64 + kq*16 + ko];
        pa = __builtin_amdgcn_mfma_f32_32x32x16_bf16(a.v, b.v, pa, 0, 0, 0);
      }
      #pragma unroll
      for (int r=0;r<16;++r){
        int m = mt3*32 + (r&3) + 8*(r>>2) + rbase;
        float v = fmaxf(fmaf(pa[r], sc3, sh3), 0.f);
        h3s[m*132 + c3] = (short)f2bu(v);
      }
    }
    __syncthreads();
    #pragma unroll
    for (int mt4=0; mt4<2; ++mt4){
      floatx16 acc;
      #pragma unroll
      for (int q=0;q<16;++q) acc[q]=0.f;
      int a4row = (mt4*32 + pl)*132;
      #pragma unroll
      for (int kq=0;kq<8;++kq){
        Frag a; FragQ b;
        const short* ap = &h3s[a4row + kq*16 + ko];
        a.u2[0] = *(const uint2*)ap;  a.u2[1] = *(const uint2*)(ap+4);
        b.q = *(const uint4*)&W4T[(size_t)c4*128 + kq*16 + ko];
        acc = __builtin_amdgcn_mfma_f32_32x32x16_bf16(a.v, b.v, acc, 0, 0, 0);
      }
      #pragma unroll
      for (int r=0;r<16;++r){
        int m = mt4*32 + (r&3) + 8*(r>>2) + rbase;
        float v = fmaxf(fmaf(acc[r], sc4, sh4), 0.f);
        h4s[m*256 + c4] = f2bu(v);
      }
    }
    __syncthreads();
    if (t < 4){
      short* dst = &h2s[trow*68 + tc0];
      *(uint2*)dst       = make_uint2(hreg.x, hreg.y);
      *(uint2*)(dst + 4) = make_uint2(hreg.z, hreg.w);
      if (t < 3) hreg = *(const uint4*)&H2[(size_t)(r0 + (t+2)*64 + trow)*64 + tc0];
    }
    {
      int lr0 = t*64;
      if (tid < 256){
        int c = tid;
        int p = lr0/20;
        int nb = (p+1)*20 - lr0;
        unsigned ml = 0;
        for (int r=0;r<64;++r){
          unsigned v = h4s[r*256 + c];
          ml = v > ml ? v : ml;
          if (--nb == 0){
            unsigned short* mp = &mx4u[p*256 + c];
            unsigned cur = *mp;
            if (ml > cur) *mp = (unsigned short)ml;
            ml = 0; ++p; nb = 20;
          }
        }
        if (nb != 20){
          unsigned short* mp = &mx4u[p*256 + c];
          unsigned cur = *mp;
          if (ml > cur) *mp = (unsigned short)ml;
        }
      } else if (tid < 384){
        int c = tid - 256;
        int p = lr0/20;
        int nb = (p+1)*20 - lr0;
        unsigned ml = 0;
        for (int r=0;r<64;++r){
          unsigned v = (unsigned)(unsigned short)h3s[r*132 + c];
          ml = v > ml ? v : ml;
          if (--nb == 0){
            unsigned short* mp = &mx3u[p*128 + c];
            unsigned cur = *mp;
            if (ml > cur) *mp = (unsigned short)ml;
            ml = 0; ++p; nb = 20;
          }
        }
        if (nb != 20){
          unsigned short* mp = &mx3u[p*128 + c];
          unsigned cur = *mp;
          if (ml > cur) *mp = (unsigned short)ml;
        }
      }
    }
    __syncthreads();
  }
  int bn0 = blockIdx.x*16;
  {
    int p = tid >> 5, c0 = (tid & 31)*8;
    uint4 v = *(const uint4*)&mx4u[p*256 + c0];
    *(uint4*)&cat[(size_t)(bn0+p)*512 + 256 + c0] = v;
  }
  if (tid < 256){
    int p = tid >> 4, c0 = (tid & 15)*8;
    uint4 v = *(const uint4*)&mx3u[p*128 + c0];
    *(uint4*)&cat[(size_t)(bn0+p)*512 + 128 + c0] = v;
  }
}

// ---------------- layer 5 v2: MFMA GEMM, direct transposed float4 epilogue ----------------
// C = relu(bn5(cat @ W5)): M=BN rows, K=512, N=512. Block = 64 rows, 8 waves.
// Each wave owns 4 of the 32 (mt,nt) 32x32 C-subtiles. K staged in 8 chunks of 64
// (reg-prefetch -> LDS, stats4 pattern). B-frags streamed from bf16 W5T (L2-resident).
// Epilogue: acc quads are 4 consecutive rows of one output channel -> float4 stores
// straight into out[(b*512+c)*4096+n], no LDS transpose.
__global__ __launch_bounds__(512) void l5_kernel(const bf16* __restrict__ cat,
                                                const bf16* __restrict__ W5T,
                                                const float* __restrict__ scale,
                                                const float* __restrict__ shift,
                                                float* __restrict__ out){
  __shared__ short cs[64*68];
  int tid = threadIdx.x, lane = tid & 63, w = tid >> 6;
  int pl = lane & 31;
  int ko = (lane >> 5)*8;
  int rbase = 4*(lane>>5);
  int mt = w & 1, ntb = w >> 1;          // nt = ntb + 4*s, s=0..3
  int arow = (mt*32 + pl)*68;
  int trow = tid >> 3, tc0 = (tid & 7)*8;
  int r0 = blockIdx.x*64;
  floatx16 acc[4];
  #pragma unroll
  for (int s=0;s<4;++s)
    #pragma unroll
    for (int q=0;q<16;++q) acc[s][q]=0.f;
  const bf16* arow_g = cat + (size_t)(r0+trow)*512 + tc0;
  uint4 hreg = *(const uint4*)arow_g;
  for (int kc8=0; kc8<8; ++kc8){
    {
      short* dst = &cs[trow*68 + tc0];
      *(uint2*)dst       = make_uint2(hreg.x, hreg.y);
      *(uint2*)(dst + 4) = make_uint2(hreg.z, hreg.w);
    }
    if (kc8 < 7) hreg = *(const uint4*)(arow_g + (kc8+1)*64);
    __syncthreads();
    #pragma unroll
    for (int kq=0;kq<4;++kq){
      Frag a;
      const short* ap = &cs[arow + kq*16 + ko];
      a.u2[0] = *(const uint2*)ap;  a.u2[1] = *(const uint2*)(ap+4);
      #pragma unroll
      for (int s=0;s<4;++s){
        FragQ b;
        int col = (ntb + 4*s)*32 + pl;
        b.q = *(const uint4*)&W5T[(size_t)col*512 + kc8*64 + kq*16 + ko];
        acc[s] = __builtin_amdgcn_mfma_f32_32x32x16_bf16(a.v, b.v, acc[s], 0, 0, 0);
      }
    }
    __syncthreads();
  }
  int b = r0 >> 12, n0 = r0 & 4095;
  int mrow = mt*32 + rbase;
  #pragma unroll
  for (int s=0;s<4;++s){
    int col = (ntb + 4*s)*32 + pl;
    float sc = scale[col], sh = shift[col];
    float* op = out + ((size_t)b*512 + col)*4096 + n0 + mrow;
    #pragma unroll
    for (int g=0; g<4; ++g){
      float4 v;
      v.x = fmaxf(fmaf(acc[s][g*4+0], sc, sh), 0.f);
      v.y = fmaxf(fmaf(acc[s][g*4+1], sc, sh), 0.f);
      v.z = fmaxf(fmaf(acc[s][g*4+2], sc, sh), 0.f);
      v.w = fmaxf(fmaf(acc[s][g*4+3], sc, sh), 0.f);
      *(float4*)(op + 8*g) = v;
    }
  }
}

extern "C" void kernel_launch(void* const* d_in, const int* in_sizes, int n_in,
                              void* d_out, int out_size, void* d_ws, size_t ws_size,
                              hipStream_t stream){
  const float* x   = (const float*)d_in[0];
  const float* W1f = (const float*)d_in[1];
  const float* W2f = (const float*)d_in[2];
  const float* W3f = (const float*)d_in[3];
  const float* W4f = (const float*)d_in[4];
  const float* W5f = (const float*)d_in[5];
  const float* g1=(const float*)d_in[6],  *b1=(const float*)d_in[7];
  const float* g2=(const float*)d_in[8],  *b2=(const float*)d_in[9];
  const float* g3=(const float*)d_in[10], *b3=(const float*)d_in[11];
  const float* g4=(const float*)d_in[12], *b4=(const float*)d_in[13];
  const float* g5=(const float*)d_in[14], *b5=(const float*)d_in[15];
  float* out = (float*)d_out;

  char* w = (char*)d_ws;
  size_t off = 0;
  auto alloc = [&](size_t bytes)->void*{
    void* p = w + off;
    off = (off + bytes + 255) & ~(size_t)255;
    return p;
  };

  int*  idxb = (int*) alloc((size_t)BN*Kk*4);
  bf16* H2   = (bf16*)alloc((size_t)Mrows*64*2);
  bf16* catb = (bf16*)alloc((size_t)BN*512*2);
  bf16* W3T  = (bf16*)alloc((size_t)128*64*2);
  bf16* W4T  = (bf16*)alloc((size_t)256*128*2);
  bf16* W5T  = (bf16*)alloc((size_t)512*512*2);
  float* pv  = (float*)H2;
  int*   pib = (int*)((char*)H2 + (size_t)BN*8*Kk*4);

  size_t statsStart = off;
  float* partf=(float*)alloc(256*48*4);
  float* Gf=(float*)alloc(36*4);
  float* sumf=(float*)alloc(8*4);
  float* G2=(float*)alloc(4096*4);   float* sum2=(float*)alloc(64*4);
  float* G3=(float*)alloc(4096*4);   float* sum3=(float*)alloc(64*4);
  float* G4=(float*)alloc(16384*4);  float* sum4=(float*)alloc(128*4);
  float* G5=(float*)alloc(262144*4); float* sum5=(float*)alloc(512*4);
  float* P1=(float*)alloc(384*4);
  float* P2=(float*)alloc(4096*4);
  float* P3=(float*)alloc(8192*4);
  float* P4=(float*)alloc(32768*4);
  float* P5=(float*)alloc(262144*4);
  float* sc1=(float*)alloc(64*4);   float* sh1=(float*)alloc(64*4);
  float* sc2=(float*)alloc(64*4);   float* sh2=(float*)alloc(64*4);
  float* sc3=(float*)alloc(128*4);  float* sh3=(float*)alloc(128*4);
  float* sc4=(float*)alloc(256*4);  float* sh4=(float*)alloc(256*4);
  float* sc5=(float*)alloc(512*4);  float* sh5=(float*)alloc(512*4);
  size_t statsEnd = off;

  int statsFloats = (int)((statsEnd - statsStart)/4);
  zero_kernel<<<(statsFloats+255)/256,256,0,stream>>>((float*)(w+statsStart), statsFloats);
  w3t_kernel<<<32,256,0,stream>>>(W3f, W3T);
  w4t_kernel<<<128,256,0,stream>>>(W4f, W4T);
  w5t_kernel<<<1024,256,0,stream>>>(W5f, W5T);

  knnA_kernel<<<1024,256,0,stream>>>(x, pv, pib);
  knnB_kernel<<<BN/256,256,0,stream>>>(pv, pib, idxb);

  const float invM  = 1.0f/(float)Mrows;
  const float invM5 = 1.0f/(float)BN;

  gramf_kernel<<<256,256,0,stream>>>(x, idxb, partf);
  reducef_kernel<<<1,64,0,stream>>>(partf, Gf, sumf);
  kP_kernel<<<2,256,0,stream>>>(Gf, W1f, P1, 6, 64);
  kFinal_kernel<<<1,256,0,stream>>>(P1, sumf, W1f, g1, b1, sc1, sh1, 6, 64, invM);

  stats2_kernel<<<512,512,0,stream>>>(x, idxb, W1f, sc1, sh1, G2, sum2);
  kP_kernel<<<16,256,0,stream>>>(G2, W2f, P2, 64, 64);
  kFinal_kernel<<<1,256,0,stream>>>(P2, sum2, W2f, g2, b2, sc2, sh2, 64, 64, invM);

  fl12_kernel<<<BN,64,0,stream>>>(x, idxb, W1f, sc1, sh1, W2f, sc2, sh2, H2, catb);

  colsum_kernel<64,bf16><<<512,256,0,stream>>>(H2, Mrows, sum3);
  gramM_kernel<64><<<512,256,0,stream>>>(H2, Mrows, G3);
  kP_kernel<<<32,256,0,stream>>>(G3, W3f, P3, 64, 128);
  kFinal_kernel<<<1,256,0,stream>>>(P3, sum3, W3f, g3, b3, sc3, sh3, 64, 128, invM);

  stats4_kernel<<<512,512,0,stream>>>(H2, W3T, sc3, sh3, G4, sum4);
  kP_kernel<<<128,256,0,stream>>>(G4, W4f, P4, 128, 256);
  kFinal_kernel<<<1,256,0,stream>>>(P4, sum4, W4f, g4, b4, sc4, sh4, 128, 256, invM);

  fl34_kernel<<<Mrows/320,512,0,stream>>>(H2, W3T, sc3, sh3, W4T, sc4, sh4, catb);

  colsum_kernel<512,bf16><<<512,256,0,stream>>>(catb, BN, sum5);
  gramM_kernel<512><<<512,256,0,stream>>>(catb, BN, G5);
  kP_kernel<<<1024,256,0,stream>>>(G5, W5f, P5, 512, 512);
  kFinal_kernel<<<2,256,0,stream>>>(P5, sum5, W5f, g5, b5, sc5, sh5, 512, 512, invM5);
  l5_kernel<<<BN/64,512,0,stream>>>(catb, W5T, sc5, sh5, out);
}

// Round 5
// 1454.485 us; speedup vs baseline: 2.5574x; 1.0752x over previous
//
#include <hip/hip_runtime.h>
#include <hip/hip_bf16.h>
#include <cfloat>

using bf16 = __hip_bfloat16;

typedef short short8 __attribute__((ext_vector_type(8)));
typedef float floatx16 __attribute__((ext_vector_type(16)));
union Frag { short8 v; uint2 u2[2]; };
union FragQ { short8 v; uint4 q; uint2 u2[2]; };
union U4b { uint4 q; unsigned short s[8]; };

constexpr int Bb = 8, Nn = 4096, Kk = 20;
constexpr int BN = Bb * Nn;                     // 32768
constexpr int Mrows = BN * Kk;                  // 655360
constexpr float EPSf = 1e-5f;

static __device__ __forceinline__ float b2f(bf16 v){ return __bfloat162float(v); }
static __device__ __forceinline__ bf16 f2b(float v){ return __float2bfloat16(v); }
static __device__ __forceinline__ unsigned short f2bu(float v){
  union { bf16 b; unsigned short u; } cv; cv.b = __float2bfloat16(v); return cv.u;
}
static __device__ __forceinline__ float bits2f(unsigned short u){
  union { unsigned int i; float f; } c; c.i = ((unsigned)u)<<16; return c.f;
}
static __device__ __forceinline__ float ldf(bf16 v){ return b2f(v); }
static __device__ __forceinline__ float ldf(float v){ return v; }

// ---------------- zero workspace region ----------------
__global__ void zero_kernel(float* __restrict__ p, int n){
  int i = blockIdx.x*256 + threadIdx.x;
  if (i < n) p[i] = 0.f;
}

// ---------------- W3^T bf16 pack ----------------
__global__ void w3t_kernel(const float* __restrict__ W3f, bf16* __restrict__ W3T){
  int id = blockIdx.x*256 + threadIdx.x;   // 128*64 = 8192 elems
  if (id >= 128*64) return;
  int n = id >> 6, k = id & 63;
  W3T[id] = f2b(W3f[(size_t)k*128 + n]);
}

// ---------------- W4^T bf16 pack ----------------
__global__ void w4t_kernel(const float* __restrict__ W4f, bf16* __restrict__ W4T){
  int id = blockIdx.x*256 + threadIdx.x;   // 128*256 = 32768 elems
  if (id >= 128*256) return;
  int k = id >> 8, c = id & 255;           // coalesced read of W4f
  W4T[(size_t)c*128 + k] = f2b(W4f[id]);
}

// ---------------- W5^T bf16 pack ----------------
__global__ void w5t_kernel(const float* __restrict__ W5f, bf16* __restrict__ W5T){
  int id = blockIdx.x*256 + threadIdx.x;   // 512*512 = 262144 elems
  if (id >= 512*512) return;
  int k = id >> 9, c = id & 511;           // coalesced read of W5f
  W5T[(size_t)c*512 + k] = f2b(W5f[id]);
}

// ---------------- KNN phase A v3: group-max threshold + index pass ----------------
// thr = 20th-largest of 64 group-maxes (groups of 8). k-th(subset) <= k-th(full) =>
// thr <= true 20th => all true top-20 pass. Pass B collects candidate indices with
// nd >= thr (expected ~23, CAP=48, 5.2-sigma). Exact branchy fallback if a lane
// saturates its buffer (correct for ALL inputs; ~never taken on random data).
// Final: exact (val,idx) insertion sort of collected entries (stable => jax tie-break).
__global__ __launch_bounds__(256) void knnA_kernel(const float* __restrict__ x,
                                                   float* __restrict__ pv, int* __restrict__ pi){
#pragma clang fp contract(off)
  __shared__ float4 p4[512];
  __shared__ unsigned short lst[256*48];
  int blk = blockIdx.x;
  int stripe = blk & 7;
  int chunk  = (blk >> 3) & 15;
  int b      = blk >> 7;
  const float* xb = x + b*3*Nn;
  int j0 = stripe*512;
  for (int u = threadIdx.x; u < 512; u += 256){
    int j = j0 + u;
    float a0 = xb[j];
    float a1 = xb[Nn + j];
    float a2 = xb[2*Nn + j];
    float s = a0*a0; s = s + a1*a1; s = s + a2*a2;
    p4[u] = make_float4(a0, a1, a2, s);
  }
  __syncthreads();
  int i = chunk*256 + threadIdx.x;
  float xi = xb[i], yi = xb[Nn+i], zi = xb[2*Nn+i];
  float ni = xi*xi; ni = ni + yi*yi; ni = ni + zi*zi;
  float mni = -ni;
  // ---- pass A: 64 group-maxes -> top-20 float min/max network ----
  float tv[Kk];
  #pragma unroll
  for (int s=0;s<Kk;++s) tv[s] = -FLT_MAX;
  for (int g=0; g<64; ++g){
    float gm = -FLT_MAX;
    #pragma unroll
    for (int e=0;e<8;++e){
      float4 p = p4[g*8+e];
      float dot = xi*p.x; dot = dot + yi*p.y; dot = dot + zi*p.z;
      float inner = -2.0f*dot;
      float nd = mni - inner; nd = nd - p.w;
      gm = fmaxf(gm, nd);
    }
    #pragma unroll
    for (int s=Kk-1; s>=1; --s)
      tv[s] = fmaxf(tv[s], fminf(tv[s-1], gm));
    tv[0] = fmaxf(tv[0], gm);
  }
  float thr = tv[Kk-1];
  // ---- pass B: collect indices with nd >= thr (ascending u => stable) ----
  unsigned short* ml = &lst[threadIdx.x*48];
  int cnt = 0;
  for (int u=0; u<512; ++u){
    float4 p = p4[u];
    float dot = xi*p.x; dot = dot + yi*p.y; dot = dot + zi*p.z;
    float inner = -2.0f*dot;
    float nd = mni - inner; nd = nd - p.w;
    if (nd >= thr && cnt < 48){ ml[cnt] = (unsigned short)u; ++cnt; }
  }
  // ---- final: exact (val,idx) insertion sort ----
  float av[Kk]; int ai[Kk];
  #pragma unroll
  for (int s=0;s<Kk;++s){ av[s] = -FLT_MAX; ai[s] = 0; }
  if (cnt >= 48){
    // exact fallback: full branchy scan (rare; correctness guarantee)
    for (int u=0; u<512; ++u){
      float4 p = p4[u];
      float dot = xi*p.x; dot = dot + yi*p.y; dot = dot + zi*p.z;
      float inner = -2.0f*dot;
      float nd = mni - inner; nd = nd - p.w;
      if (nd > av[Kk-1]){
        #pragma unroll
        for (int s=Kk-1; s>=1; --s){
          bool cs = nd > av[s];
          bool cp = nd > av[s-1];
          av[s] = cs ? (cp ? av[s-1] : nd) : av[s];
          ai[s] = cs ? (cp ? ai[s-1] : (j0+u)) : ai[s];
        }
        if (nd > av[0]){ av[0] = nd; ai[0] = j0+u; }
      }
    }
  } else {
    for (int t=0; t<cnt; ++t){
      int lj = ml[t];
      float4 p = p4[lj];
      float dot = xi*p.x; dot = dot + yi*p.y; dot = dot + zi*p.z;
      float inner = -2.0f*dot;
      float nd = mni - inner; nd = nd - p.w;
      if (nd > av[Kk-1]){
        #pragma unroll
        for (int s=Kk-1; s>=1; --s){
          bool cs = nd > av[s];
          bool cp = nd > av[s-1];
          av[s] = cs ? (cp ? av[s-1] : nd) : av[s];
          ai[s] = cs ? (cp ? ai[s-1] : (j0+lj)) : ai[s];
        }
        if (nd > av[0]){ av[0] = nd; ai[0] = j0+lj; }
      }
    }
  }
  long long base = ((long long)(b*Nn + i)*8 + stripe)*Kk;
  #pragma unroll
  for (int s=0;s<Kk;++s){ pv[base+s] = av[s]; pi[base+s] = ai[s]; }
}

// ---------------- KNN phase B: merge 8 stripes ----------------
__global__ __launch_bounds__(256) void knnB_kernel(const float* __restrict__ pv,
                                                   const int* __restrict__ pi,
                                                   int* __restrict__ idx){
  int p = blockIdx.x*256 + threadIdx.x;
  if (p >= BN) return;
  long long base = (long long)p*8*Kk;
  float av[Kk]; int ai[Kk];
  #pragma unroll
  for (int s=0;s<Kk;++s){ av[s]=pv[base+s]; ai[s]=pi[base+s]; }
  for (int t=Kk; t<8*Kk; ++t){
    float nd = pv[base+t]; int j = pi[base+t];
    if (nd > av[Kk-1]){
      #pragma unroll
      for (int s=Kk-1;s>=1;--s){
        bool cs = nd > av[s];
        bool cp = nd > av[s-1];
        av[s] = cs ? (cp?av[s-1]:nd) : av[s];
        ai[s] = cs ? (cp?ai[s-1]:j) : ai[s];
      }
      if (nd > av[0]){ av[0]=nd; ai[0]=j; }
    }
  }
  #pragma unroll
  for (int s=0;s<Kk;++s) idx[(long long)p*Kk+s] = ai[s];
}

// ---------------- layer-1 feature stats ----------------
__global__ __launch_bounds__(256) void gramf_kernel(const float* __restrict__ x,
                                                    const int* __restrict__ idx,
                                                    float* __restrict__ part){
  float acc[36]; float s6[6];
  #pragma unroll
  for (int a=0;a<36;++a) acc[a]=0.f;
  #pragma unroll
  for (int a=0;a<6;++a) s6[a]=0.f;
  for (long long row = blockIdx.x*256 + threadIdx.x; row < Mrows; row += (long long)gridDim.x*256){
    int bn = (int)(row / Kk);
    int b = bn >> 12, n = bn & 4095;
    int j = idx[row];
    const float* xb = x + b*3*Nn;
    float f[6];
    f[0]=xb[j];  f[1]=xb[Nn+j];  f[2]=xb[2*Nn+j];
    f[3]=xb[n];  f[4]=xb[Nn+n];  f[5]=xb[2*Nn+n];
    #pragma unroll
    for (int a=0;a<6;++a){
      s6[a] += f[a];
      #pragma unroll
      for (int c=0;c<6;++c) acc[a*6+c] = fmaf(f[a], f[c], acc[a*6+c]);
    }
  }
  __shared__ float red[256];
  for (int v=0; v<42; ++v){
    red[threadIdx.x] = (v<36)? acc[v] : s6[v-36];
    __syncthreads();
    for (int s=128; s>0; s>>=1){
      if (threadIdx.x < s) red[threadIdx.x] += red[threadIdx.x+s];
      __syncthreads();
    }
    if (threadIdx.x==0) part[blockIdx.x*48 + v] = red[0];
    __syncthreads();
  }
}

__global__ void reducef_kernel(const float* __restrict__ part, float* __restrict__ Gf,
                               float* __restrict__ sumf){
  int t = threadIdx.x;
  if (t < 42){
    float s = 0.f;
    for (int i=0;i<256;++i) s += part[i*48 + t];
    if (t<36) Gf[t]=s; else sumf[t-36]=s;
  }
}

// ---------------- MFMA Gram: G = H^T H over bf16 H ----------------
template<int CIN>
__global__ __launch_bounds__(256) void gramM_kernel(const bf16* __restrict__ H, int M,
                                                    float* __restrict__ G){
  constexpr int Tt = CIN/64;
  int tile = blockIdx.x % (Tt*Tt);
  int chunk = blockIdx.x / (Tt*Tt);
  int nchunks = gridDim.x / (Tt*Tt);
  int tr = tile / Tt, tc = tile % Tt;
  bool diag = (tr == tc);
  __shared__ short HTa[64*68];
  __shared__ short HTb[64*68];
  int rpc = M / nchunks;
  int r0 = chunk*rpc;
  int tid = threadIdx.x, lane = tid & 63, w = tid >> 6;
  int mt = w >> 1, nt = w & 1;
  floatx16 acc;
  #pragma unroll
  for (int q=0;q<16;++q) acc[q]=0.f;
  const short* Bbase = diag ? HTa : HTb;
  int arow = (mt*32 + (lane&31))*68;
  int brow = (nt*32 + (lane&31))*68;
  int ko = (lane>>5)*8;
  for (int rb=r0; rb<r0+rpc; rb+=64){
    #pragma unroll
    for (int s=0;s<2;++s){
      int e = tid + s*256;
      int row = e >> 3, c0 = (e & 7)*8;
      U4b va; va.q = *(const uint4*)&H[(size_t)(rb+row)*CIN + tr*64 + c0];
      #pragma unroll
      for (int j=0;j<8;++j) HTa[(c0+j)*68 + row] = (short)va.s[j];
      if (!diag){
        U4b vb; vb.q = *(const uint4*)&H[(size_t)(rb+row)*CIN + tc*64 + c0];
        #pragma unroll
        for (int j=0;j<8;++j) HTb[(c0+j)*68 + row] = (short)vb.s[j];
      }
    }
    __syncthreads();
    #pragma unroll
    for (int kc=0;kc<64;kc+=16){
      Frag a, b;
      const short* ap = &HTa[arow + kc + ko];
      const short* bp = &Bbase[brow + kc + ko];
      a.u2[0] = *(const uint2*)ap;  a.u2[1] = *(const uint2*)(ap+4);
      b.u2[0] = *(const uint2*)bp;  b.u2[1] = *(const uint2*)(bp+4);
      acc = __builtin_amdgcn_mfma_f32_32x32x16_bf16(a.v, b.v, acc, 0, 0, 0);
    }
    __syncthreads();
  }
  int col = lane & 31, rbase = 4*(lane>>5);
  #pragma unroll
  for (int r=0;r<16;++r){
    int row = (r&3) + 8*(r>>2) + rbase;
    atomicAdd(&G[(size_t)(tr*64 + mt*32 + row)*CIN + tc*64 + nt*32 + col], acc[r]);
  }
}

// ---------------- column sums of H ----------------
template<int CIN, typename T>
__global__ __launch_bounds__(256) void colsum_kernel(const T* __restrict__ H, int M,
                                                     float* __restrict__ sumh){
  int rpb = (M + gridDim.x - 1)/gridDim.x;
  int r0 = blockIdx.x*rpb, r1 = min(M, r0+rpb);
  if constexpr (CIN <= 256){
    constexpr int RP = 256/CIN;
    int c = threadIdx.x % CIN;
    int sub = threadIdx.x / CIN;
    float a = 0.f;
    for (int r=r0+sub; r<r1; r+=RP) a += ldf(H[(size_t)r*CIN + c]);
    atomicAdd(&sumh[c], a);
  } else {
    float a0=0.f, a1=0.f;
    for (int r=r0;r<r1;++r){
      a0 += ldf(H[(size_t)r*CIN + threadIdx.x]);
      a1 += ldf(H[(size_t)r*CIN + threadIdx.x + 256]);
    }
    atomicAdd(&sumh[threadIdx.x], a0);
    atomicAdd(&sumh[threadIdx.x+256], a1);
  }
}

// ---------------- P = G @ W ----------------
__global__ void kP_kernel(const float* __restrict__ G, const float* __restrict__ Wf,
                          float* __restrict__ P, int Cin, int Cout){
  int id = blockIdx.x*256 + threadIdx.x;
  if (id >= Cin*Cout) return;
  int i = id / Cout, j = id - i*Cout;
  float s = 0.f;
  for (int k=0;k<Cin;++k) s = fmaf(G[(size_t)i*Cin+k], Wf[(size_t)k*Cout+j], s);
  P[id] = s;
}

// ---------------- scale/shift from Gram-derived BN stats ----------------
__global__ void kFinal_kernel(const float* __restrict__ P, const float* __restrict__ sumh,
                              const float* __restrict__ Wf, const float* __restrict__ g,
                              const float* __restrict__ bb, float* __restrict__ scale,
                              float* __restrict__ shift, int Cin, int Cout, float invM){
  int j = blockIdx.x*256 + threadIdx.x;
  if (j >= Cout) return;
  float mean=0.f, e2=0.f;
  for (int i=0;i<Cin;++i){
    float w = Wf[(size_t)i*Cout + j];
    mean = fmaf(sumh[i], w, mean);
    e2   = fmaf(w, P[(size_t)i*Cout + j], e2);
  }
  mean *= invM; e2 *= invM;
  float var = e2 - mean*mean;
  float inv = rsqrtf(var + EPSf);
  float sc = g[j]*inv;
  scale[j]=sc;
  shift[j]=bb[j] - mean*sc;
}

// ---------------- layer-2 stats ----------------
__global__ __launch_bounds__(512) void stats2_kernel(const float* __restrict__ x,
    const int* __restrict__ idx, const float* __restrict__ W1f,
    const float* __restrict__ sc1v, const float* __restrict__ sh1v,
    float* __restrict__ G2, float* __restrict__ sum2){
  __shared__ float W1s[6][64];
  __shared__ float fsh[64][8];
  __shared__ short H1T[64*68];
  __shared__ float csum[64];
  int tid = threadIdx.x, lane = tid & 63, w = tid >> 6;   // 8 waves
  if (tid < 384) W1s[tid>>6][tid&63] = W1f[tid];
  if (tid < 64) csum[tid] = 0.f;
  int rp = tid >> 4, cq = tid & 15, c0 = cq*4;
  float sca[4], sha[4];
  #pragma unroll
  for (int k=0;k<4;++k){ sca[k]=sc1v[c0+k]; sha[k]=sh1v[c0+k]; }
  int mt = w & 1, nt = (w>>1) & 1, kh = w >> 2;
  int arow = (mt*32 + (lane&31))*68;
  int brow = (nt*32 + (lane&31))*68;
  int ko = (lane>>5)*8;
  floatx16 acc;
  #pragma unroll
  for (int q=0;q<16;++q) acc[q]=0.f;
  float cs[4] = {0.f,0.f,0.f,0.f};
  int rpc = Mrows / gridDim.x;
  int r0 = blockIdx.x * rpc;
  __syncthreads();
  for (int rb=r0; rb<r0+rpc; rb+=64){
    {
      int r = tid>>3, e = tid&7;
      if (e < 6){
        int grow = rb + r;
        int bn = grow / Kk;
        int b = bn >> 12, n = bn & 4095;
        int j = idx[grow];
        const float* xb = x + b*3*Nn;
        fsh[r][e] = (e<3) ? xb[e*Nn + j] : xb[(e-3)*Nn + n];
      }
    }
    __syncthreads();
    {
      float y0[4]={0,0,0,0}, y1[4]={0,0,0,0};
      int ra = rp*2, rbw = rp*2+1;
      #pragma unroll
      for (int i=0;i<6;++i){
        float fa = fsh[ra][i], fb = fsh[rbw][i];
        float4 wv = *(const float4*)&W1s[i][c0];
        y0[0]=fmaf(fa,wv.x,y0[0]); y0[1]=fmaf(fa,wv.y,y0[1]);
        y0[2]=fmaf(fa,wv.z,y0[2]); y0[3]=fmaf(fa,wv.w,y0[3]);
        y1[0]=fmaf(fb,wv.x,y1[0]); y1[1]=fmaf(fb,wv.y,y1[1]);
        y1[2]=fmaf(fb,wv.z,y1[2]); y1[3]=fmaf(fb,wv.w,y1[3]);
      }
      #pragma unroll
      for (int k=0;k<4;++k){
        float va = fmaxf(fmaf(y0[k],sca[k],sha[k]),0.f);
        float vb = fmaxf(fmaf(y1[k],sca[k],sha[k]),0.f);
        cs[k] += va; cs[k] += vb;
        unsigned int pk = f2bu(va) | ((unsigned)f2bu(vb)<<16);
        *(unsigned int*)&H1T[(c0+k)*68 + ra] = pk;
      }
    }
    __syncthreads();
    {
      int kc = kh*32;
      #pragma unroll
      for (int s=0;s<2;++s){
        Frag a, b;
        const short* ap = &H1T[arow + kc + s*16 + ko];
        const short* bp = &H1T[brow + kc + s*16 + ko];
        a.u2[0] = *(const uint2*)ap;  a.u2[1] = *(const uint2*)(ap+4);
        b.u2[0] = *(const uint2*)bp;  b.u2[1] = *(const uint2*)(bp+4);
        acc = __builtin_amdgcn_mfma_f32_32x32x16_bf16(a.v, b.v, acc, 0, 0, 0);
      }
    }
    __syncthreads();
  }
  int col = lane & 31, rbase = 4*(lane>>5);
  #pragma unroll
  for (int r=0;r<16;++r){
    int row = (r&3) + 8*(r>>2) + rbase;
    atomicAdd(&G2[(size_t)(mt*32+row)*64 + nt*32+col], acc[r]);
  }
  #pragma unroll
  for (int k=0;k<4;++k) atomicAdd(&csum[c0+k], cs[k]);
  __syncthreads();
  if (tid < 64) atomicAdd(&sum2[tid], csum[tid]);
}

// ---------------- fused layers 1+2 ----------------
__global__ __launch_bounds__(64) void fl12_kernel(const float* __restrict__ x,
    const int* __restrict__ idx, const float* __restrict__ W1f,
    const float* __restrict__ sc1v, const float* __restrict__ sh1v,
    const float* __restrict__ W2f, const float* __restrict__ sc2v,
    const float* __restrict__ sh2v, bf16* __restrict__ H2, bf16* __restrict__ cat){
  __shared__ float fsh[Kk][6];
  __shared__ float h1[Kk][64];
  __shared__ float mm[4][64];
  int bn = blockIdx.x, b = bn>>12, n = bn & 4095;
  int tid = threadIdx.x;
  if (tid < Kk){
    int j = idx[(size_t)bn*Kk + tid];
    const float* xb = x + b*3*Nn;
    fsh[tid][0]=xb[j]; fsh[tid][1]=xb[Nn+j]; fsh[tid][2]=xb[2*Nn+j];
    fsh[tid][3]=xb[n]; fsh[tid][4]=xb[Nn+n]; fsh[tid][5]=xb[2*Nn+n];
  }
  __syncthreads();
  {
    float sc=sc1v[tid], sh=sh1v[tid];
    float w[6];
    #pragma unroll
    for (int i=0;i<6;++i) w[i]=W1f[i*64+tid];
    float mx = 0.f;
    #pragma unroll
    for (int r=0;r<Kk;++r){
      float y=0.f;
      #pragma unroll
      for (int i=0;i<6;++i) y = fmaf(fsh[r][i], w[i], y);
      float v = fmaxf(fmaf(y,sc,sh),0.f);
      h1[r][tid]=v;
      mx = fmaxf(mx,v);
    }
    cat[(size_t)bn*512 + tid] = f2b(mx);
  }
  __syncthreads();
  int q = tid >> 4, c0 = (tid & 15)*4;
  float acc[5][4]={};
  for (int i0=0;i0<64;i0+=4){
    float hv[5][4];
    #pragma unroll
    for (int l=0;l<5;++l){
      float4 t4 = *(const float4*)&h1[q*5+l][i0];
      hv[l][0]=t4.x; hv[l][1]=t4.y; hv[l][2]=t4.z; hv[l][3]=t4.w;
    }
    #pragma unroll
    for (int ii=0;ii<4;++ii){
      const float* wp = W2f + (i0+ii)*64 + c0;
      float w0=wp[0],w1=wp[1],w2=wp[2],w3=wp[3];
      #pragma unroll
      for (int l=0;l<5;++l){
        float hvv=hv[l][ii];
        acc[l][0]=fmaf(hvv,w0,acc[l][0]);
        acc[l][1]=fmaf(hvv,w1,acc[l][1]);
        acc[l][2]=fmaf(hvv,w2,acc[l][2]);
        acc[l][3]=fmaf(hvv,w3,acc[l][3]);
      }
    }
  }
  float sc[4],sh[4];
  #pragma unroll
  for (int cb=0;cb<4;++cb){ sc[cb]=sc2v[c0+cb]; sh[cb]=sh2v[c0+cb]; }
  float mx[4]={0,0,0,0};
  #pragma unroll
  for (int l=0;l<5;++l){
    unsigned short us[4];
    #pragma unroll
    for (int cb=0;cb<4;++cb){
      float v=fmaxf(fmaf(acc[l][cb],sc[cb],sh[cb]),0.f);
      mx[cb]=fmaxf(mx[cb],v);
      us[cb]=f2bu(v);
    }
    uint2 v2; v2.x = us[0]|((unsigned)us[1]<<16); v2.y=us[2]|((unsigned)us[3]<<16);
    *(uint2*)(H2 + ((size_t)bn*Kk + q*5+l)*64 + c0) = v2;
  }
  #pragma unroll
  for (int cb=0;cb<4;++cb) mm[q][c0+cb]=mx[cb];
  __syncthreads();
  {
    float M0 = fmaxf(fmaxf(mm[0][tid],mm[1][tid]),fmaxf(mm[2][tid],mm[3][tid]));
    cat[(size_t)bn*512 + 64 + tid] = f2b(M0);
  }
}

// ---------------- layer-4 stats: MFMA produce + MFMA Gram ----------------
__global__ __launch_bounds__(512) void stats4_kernel(const bf16* __restrict__ H2,
    const bf16* __restrict__ W3T, const float* __restrict__ sc3v, const float* __restrict__ sh3v,
    float* __restrict__ G4, float* __restrict__ sum4){
  __shared__ short h2s[64*68];
  __shared__ short H3T[128*68];
  __shared__ float csum[128];
  int tid = threadIdx.x, lane = tid & 63, w = tid >> 6;   // 8 waves
  if (tid < 128) csum[tid] = 0.f;
  int trow = tid >> 3, tc0 = (tid & 7)*8;
  int pl  = lane & 31;
  int ko  = (lane >> 5)*8;
  int pmt = w >> 2, pnt = w & 3;
  int parow = (pmt*32 + pl)*68;
  int pcol  = pnt*32 + pl;
  float psc = sc3v[pcol], psh = sh3v[pcol];
  int prbase = 4*(lane>>5);
  FragQ bfr[4];
  #pragma unroll
  for (int kq=0;kq<4;++kq)
    bfr[kq].q = *(const uint4*)&W3T[(size_t)pcol*64 + kq*16 + ko];
  int gmt = w>>1, gnt0 = (w&1)*2, gnt1 = gnt0+1;
  int garow  = (gmt*32 + pl)*68;
  int gbrow0 = (gnt0*32 + pl)*68;
  int gbrow1 = (gnt1*32 + pl)*68;
  floatx16 acc0, acc1;
  #pragma unroll
  for (int q=0;q<16;++q){ acc0[q]=0.f; acc1[q]=0.f; }
  float cs = 0.f;
  int rpc = Mrows / gridDim.x;
  int r0 = blockIdx.x * rpc;
  uint4 hreg = *(const uint4*)&H2[(size_t)(r0+trow)*64 + tc0];
  for (int rb=r0; rb<r0+rpc; rb+=64){
    {
      short* dst = &h2s[trow*68 + tc0];
      *(uint2*)dst       = make_uint2(hreg.x, hreg.y);
      *(uint2*)(dst + 4) = make_uint2(hreg.z, hreg.w);
    }
    if (rb + 64 < r0 + rpc)
      hreg = *(const uint4*)&H2[(size_t)(rb+64+trow)*64 + tc0];
    __syncthreads();
    {
      floatx16 pacc;
      #pragma unroll
      for (int q=0;q<16;++q) pacc[q]=0.f;
      #pragma unroll
      for (int kq=0;kq<4;++kq){
        Frag a;
        const short* ap = &h2s[parow + kq*16 + ko];
        a.u2[0] = *(const uint2*)ap;  a.u2[1] = *(const uint2*)(ap+4);
        pacc = __builtin_amdgcn_mfma_f32_32x32x16_bf16(a.v, bfr[kq].v, pacc, 0, 0, 0);
      }
      #pragma unroll
      for (int g=0; g<4; ++g){
        unsigned short p[4];
        #pragma unroll
        for (int r=0;r<4;++r){
          float v = fmaxf(fmaf(pacc[g*4+r], psc, psh), 0.f);
          cs += v;
          p[r] = f2bu(v);
        }
        uint2 pk; pk.x = p[0] | ((unsigned)p[1]<<16); pk.y = p[2] | ((unsigned)p[3]<<16);
        *(uint2*)&H3T[pcol*68 + pmt*32 + 8*g + prbase] = pk;
      }
    }
    __syncthreads();
    #pragma unroll
    for (int kc=0;kc<64;kc+=16){
      Frag a, b0, b1;
      const short* ap  = &H3T[garow  + kc + ko];
      const short* bp0 = &H3T[gbrow0 + kc + ko];
      const short* bp1 = &H3T[gbrow1 + kc + ko];
      a.u2[0]  = *(const uint2*)ap;   a.u2[1]  = *(const uint2*)(ap+4);
      b0.u2[0] = *(const uint2*)bp0;  b0.u2[1] = *(const uint2*)(bp0+4);
      b1.u2[0] = *(const uint2*)bp1;  b1.u2[1] = *(const uint2*)(bp1+4);
      acc0 = __builtin_amdgcn_mfma_f32_32x32x16_bf16(a.v, b0.v, acc0, 0, 0, 0);
      acc1 = __builtin_amdgcn_mfma_f32_32x32x16_bf16(a.v, b1.v, acc1, 0, 0, 0);
    }
  }
  int col = pl;
  #pragma unroll
  for (int r=0;r<16;++r){
    int row = (r&3) + 8*(r>>2) + prbase;
    atomicAdd(&G4[(size_t)(gmt*32+row)*128 + gnt0*32+col], acc0[r]);
    atomicAdd(&G4[(size_t)(gmt*32+row)*128 + gnt1*32+col], acc1[r]);
  }
  atomicAdd(&csum[pcol], cs);
  __syncthreads();
  if (tid < 128) atomicAdd(&sum4[tid], csum[tid]);
}

// ---------------- fused layers 3+4: MFMA produce chain + col-owner maxpool ----------------
__global__ __launch_bounds__(512,4) void fl34_kernel(const bf16* __restrict__ H2,
    const bf16* __restrict__ W3T, const float* __restrict__ sc3v, const float* __restrict__ sh3v,
    const bf16* __restrict__ W4T, const float* __restrict__ sc4v, const float* __restrict__ sh4v,
    bf16* __restrict__ cat){
  __shared__ short h2s[64*68];             // 8.5 KB
  __shared__ short h3s[64*132];            // 16.5 KB
  __shared__ unsigned short h4s[64*256];   // 32 KB
  __shared__ unsigned short mx3u[16*128];  // 4 KB
  __shared__ unsigned short mx4u[16*256];  // 8 KB
  int tid = threadIdx.x, lane = tid & 63, w = tid >> 6;
  int pl = lane & 31;
  int ko = (lane >> 5)*8;
  int rbase = 4*(lane>>5);
  {
    unsigned* p4 = (unsigned*)mx4u;
    for (int u=tid; u<2048; u+=512) p4[u]=0u;
    unsigned* p3 = (unsigned*)mx3u;
    for (int u=tid; u<1024; u+=512) p3[u]=0u;
  }
  int mt3 = w >> 2, ct3 = w & 3;
  int c3 = ct3*32 + pl;
  float sc3 = sc3v[c3], sh3 = sh3v[c3];
  int a3row = (mt3*32 + pl)*68;
  int c4 = w*32 + pl;
  float sc4 = sc4v[c4], sh4 = sh4v[c4];
  int trow = tid >> 3, tc0 = (tid & 7)*8;
  int r0 = blockIdx.x * 320;
  uint4 hreg = *(const uint4*)&H2[(size_t)(r0+trow)*64 + tc0];
  {
    short* dst = &h2s[trow*68 + tc0];
    *(uint2*)dst       = make_uint2(hreg.x, hreg.y);
    *(uint2*)(dst + 4) = make_uint2(hreg.z, hreg.w);
  }
  hreg = *(const uint4*)&H2[(size_t)(r0 + 64 + trow)*64 + tc0];
  __syncthreads();
  for (int t=0; t<5; ++t){
    {
      floatx16 pa;
      #pragma unroll
      for (int q=0;q<16;++q) pa[q]=0.f;
      #pragma unroll
      for (int kq=0;kq<4;++kq){
        Frag a; FragQ b;
        const short* ap = &h2s[a3row + kq*16 + ko];
        a.u2[0] = *(const uint2*)ap;  a.u2[1] = *(const uint2*)(ap+4);
        b.q = *(const uint4*)&W3T[(size_t)c3*64 + kq*16 + ko];
        pa = __builtin_amdgcn_mfma_f32_32x32x16_bf16(a.v, b.v, pa, 0, 0, 0);
      }
      #pragma unroll
      for (int r=0;r<16;++r){
        int m = mt3*32 + (r&3) + 8*(r>>2) + rbase;
        float v = fmaxf(fmaf(pa[r], sc3, sh3), 0.f);
        h3s[m*132 + c3] = (short)f2bu(v);
      }
    }
    __syncthreads();
    #pragma unroll
    for (int mt4=0; mt4<2; ++mt4){
      floatx16 acc;
      #pragma unroll
      for (int q=0;q<16;++q) acc[q]=0.f;
      int a4row = (mt4*32 + pl)*132;
      #pragma unroll
      for (int kq=0;kq<8;++kq){
        Frag a; FragQ b;
        const short* ap = &h3s[a4row + kq*16 + ko];
        a.u2[0] = *(const uint2*)ap;  a.u2[1] = *(const uint2*)(ap+4);
        b.q = *(const uint4*)&W4T[(size_t)c4*128 + kq*16 + ko];
        acc = __builtin_amdgcn_mfma_f32_32x32x16_bf16(a.v, b.v, acc, 0, 0, 0);
      }
      #pragma unroll
      for (int r=0;r<16;++r){
        int m = mt4*32 + (r&3) + 8*(r>>2) + rbase;
        float v = fmaxf(fmaf(acc[r], sc4, sh4), 0.f);
        h4s[m*256 + c4] = f2bu(v);
      }
    }
    __syncthreads();
    if (t < 4){
      short* dst = &h2s[trow*68 + tc0];
      *(uint2*)dst       = make_uint2(hreg.x, hreg.y);
      *(uint2*)(dst + 4) = make_uint2(hreg.z, hreg.w);
      if (t < 3) hreg = *(const uint4*)&H2[(size_t)(r0 + (t+2)*64 + trow)*64 + tc0];
    }
    {
      int lr0 = t*64;
      if (tid < 256){
        int c = tid;
        int p = lr0/20;
        int nb = (p+1)*20 - lr0;
        unsigned ml = 0;
        for (int r=0;r<64;++r){
          unsigned v = h4s[r*256 + c];
          ml = v > ml ? v : ml;
          if (--nb == 0){
            unsigned short* mp = &mx4u[p*256 + c];
            unsigned cur = *mp;
            if (ml > cur) *mp = (unsigned short)ml;
            ml = 0; ++p; nb = 20;
          }
        }
        if (nb != 20){
          unsigned short* mp = &mx4u[p*256 + c];
          unsigned cur = *mp;
          if (ml > cur) *mp = (unsigned short)ml;
        }
      } else if (tid < 384){
        int c = tid - 256;
        int p = lr0/20;
        int nb = (p+1)*20 - lr0;
        unsigned ml = 0;
        for (int r=0;r<64;++r){
          unsigned v = (unsigned)(unsigned short)h3s[r*132 + c];
          ml = v > ml ? v : ml;
          if (--nb == 0){
            unsigned short* mp = &mx3u[p*128 + c];
            unsigned cur = *mp;
            if (ml > cur) *mp = (unsigned short)ml;
            ml = 0; ++p; nb = 20;
          }
        }
        if (nb != 20){
          unsigned short* mp = &mx3u[p*128 + c];
          unsigned cur = *mp;
          if (ml > cur) *mp = (unsigned short)ml;
        }
      }
    }
    __syncthreads();
  }
  int bn0 = blockIdx.x*16;
  {
    int p = tid >> 5, c0 = (tid & 31)*8;
    uint4 v = *(const uint4*)&mx4u[p*256 + c0];
    *(uint4*)&cat[(size_t)(bn0+p)*512 + 256 + c0] = v;
  }
  if (tid < 256){
    int p = tid >> 4, c0 = (tid & 15)*8;
    uint4 v = *(const uint4*)&mx3u[p*128 + c0];
    *(uint4*)&cat[(size_t)(bn0+p)*512 + 128 + c0] = v;
  }
}

// ---------------- layer 5: MFMA GEMM, direct transposed float4 epilogue ----------------
__global__ __launch_bounds__(512) void l5_kernel(const bf16* __restrict__ cat,
                                                const bf16* __restrict__ W5T,
                                                const float* __restrict__ scale,
                                                const float* __restrict__ shift,
                                                float* __restrict__ out){
  __shared__ short cs[64*68];
  int tid = threadIdx.x, lane = tid & 63, w = tid >> 6;
  int pl = lane & 31;
  int ko = (lane >> 5)*8;
  int rbase = 4*(lane>>5);
  int mt = w & 1, ntb = w >> 1;          // nt = ntb + 4*s, s=0..3
  int arow = (mt*32 + pl)*68;
  int trow = tid >> 3, tc0 = (tid & 7)*8;
  int r0 = blockIdx.x*64;
  floatx16 acc[4];
  #pragma unroll
  for (int s=0;s<4;++s)
    #pragma unroll
    for (int q=0;q<16;++q) acc[s][q]=0.f;
  const bf16* arow_g = cat + (size_t)(r0+trow)*512 + tc0;
  uint4 hreg = *(const uint4*)arow_g;
  for (int kc8=0; kc8<8; ++kc8){
    {
      short* dst = &cs[trow*68 + tc0];
      *(uint2*)dst       = make_uint2(hreg.x, hreg.y);
      *(uint2*)(dst + 4) = make_uint2(hreg.z, hreg.w);
    }
    if (kc8 < 7) hreg = *(const uint4*)(arow_g + (kc8+1)*64);
    __syncthreads();
    #pragma unroll
    for (int kq=0;kq<4;++kq){
      Frag a;
      const short* ap = &cs[arow + kq*16 + ko];
      a.u2[0] = *(const uint2*)ap;  a.u2[1] = *(const uint2*)(ap+4);
      #pragma unroll
      for (int s=0;s<4;++s){
        FragQ b;
        int col = (ntb + 4*s)*32 + pl;
        b.q = *(const uint4*)&W5T[(size_t)col*512 + kc8*64 + kq*16 + ko];
        acc[s] = __builtin_amdgcn_mfma_f32_32x32x16_bf16(a.v, b.v, acc[s], 0, 0, 0);
      }
    }
    __syncthreads();
  }
  int b = r0 >> 12, n0 = r0 & 4095;
  int mrow = mt*32 + rbase;
  #pragma unroll
  for (int s=0;s<4;++s){
    int col = (ntb + 4*s)*32 + pl;
    float sc = scale[col], sh = shift[col];
    float* op = out + ((size_t)b*512 + col)*4096 + n0 + mrow;
    #pragma unroll
    for (int g=0; g<4; ++g){
      float4 v;
      v.x = fmaxf(fmaf(acc[s][g*4+0], sc, sh), 0.f);
      v.y = fmaxf(fmaf(acc[s][g*4+1], sc, sh), 0.f);
      v.z = fmaxf(fmaf(acc[s][g*4+2], sc, sh), 0.f);
      v.w = fmaxf(fmaf(acc[s][g*4+3], sc, sh), 0.f);
      *(float4*)(op + 8*g) = v;
    }
  }
}

extern "C" void kernel_launch(void* const* d_in, const int* in_sizes, int n_in,
                              void* d_out, int out_size, void* d_ws, size_t ws_size,
                              hipStream_t stream){
  const float* x   = (const float*)d_in[0];
  const float* W1f = (const float*)d_in[1];
  const float* W2f = (const float*)d_in[2];
  const float* W3f = (const float*)d_in[3];
  const float* W4f = (const float*)d_in[4];
  const float* W5f = (const float*)d_in[5];
  const float* g1=(const float*)d_in[6],  *b1=(const float*)d_in[7];
  const float* g2=(const float*)d_in[8],  *b2=(const float*)d_in[9];
  const float* g3=(const float*)d_in[10], *b3=(const float*)d_in[11];
  const float* g4=(const float*)d_in[12], *b4=(const float*)d_in[13];
  const float* g5=(const float*)d_in[14], *b5=(const float*)d_in[15];
  float* out = (float*)d_out;

  char* w = (char*)d_ws;
  size_t off = 0;
  auto alloc = [&](size_t bytes)->void*{
    void* p = w + off;
    off = (off + bytes + 255) & ~(size_t)255;
    return p;
  };

  int*  idxb = (int*) alloc((size_t)BN*Kk*4);
  bf16* H2   = (bf16*)alloc((size_t)Mrows*64*2);
  bf16* catb = (bf16*)alloc((size_t)BN*512*2);
  bf16* W3T  = (bf16*)alloc((size_t)128*64*2);
  bf16* W4T  = (bf16*)alloc((size_t)256*128*2);
  bf16* W5T  = (bf16*)alloc((size_t)512*512*2);
  float* pv  = (float*)H2;
  int*   pib = (int*)((char*)H2 + (size_t)BN*8*Kk*4);

  size_t statsStart = off;
  float* partf=(float*)alloc(256*48*4);
  float* Gf=(float*)alloc(36*4);
  float* sumf=(float*)alloc(8*4);
  float* G2=(float*)alloc(4096*4);   float* sum2=(float*)alloc(64*4);
  float* G3=(float*)alloc(4096*4);   float* sum3=(float*)alloc(64*4);
  float* G4=(float*)alloc(16384*4);  float* sum4=(float*)alloc(128*4);
  float* G5=(float*)alloc(262144*4); float* sum5=(float*)alloc(512*4);
  float* P1=(float*)alloc(384*4);
  float* P2=(float*)alloc(4096*4);
  float* P3=(float*)alloc(8192*4);
  float* P4=(float*)alloc(32768*4);
  float* P5=(float*)alloc(262144*4);
  float* sc1=(float*)alloc(64*4);   float* sh1=(float*)alloc(64*4);
  float* sc2=(float*)alloc(64*4);   float* sh2=(float*)alloc(64*4);
  float* sc3=(float*)alloc(128*4);  float* sh3=(float*)alloc(128*4);
  float* sc4=(float*)alloc(256*4);  float* sh4=(float*)alloc(256*4);
  float* sc5=(float*)alloc(512*4);  float* sh5=(float*)alloc(512*4);
  size_t statsEnd = off;

  int statsFloats = (int)((statsEnd - statsStart)/4);
  zero_kernel<<<(statsFloats+255)/256,256,0,stream>>>((float*)(w+statsStart), statsFloats);
  w3t_kernel<<<32,256,0,stream>>>(W3f, W3T);
  w4t_kernel<<<128,256,0,stream>>>(W4f, W4T);
  w5t_kernel<<<1024,256,0,stream>>>(W5f, W5T);

  knnA_kernel<<<1024,256,0,stream>>>(x, pv, pib);
  knnB_kernel<<<BN/256,256,0,stream>>>(pv, pib, idxb);

  const float invM  = 1.0f/(float)Mrows;
  const float invM5 = 1.0f/(float)BN;

  gramf_kernel<<<256,256,0,stream>>>(x, idxb, partf);
  reducef_kernel<<<1,64,0,stream>>>(partf, Gf, sumf);
  kP_kernel<<<2,256,0,stream>>>(Gf, W1f, P1, 6, 64);
  kFinal_kernel<<<1,256,0,stream>>>(P1, sumf, W1f, g1, b1, sc1, sh1, 6, 64, invM);

  stats2_kernel<<<512,512,0,stream>>>(x, idxb, W1f, sc1, sh1, G2, sum2);
  kP_kernel<<<16,256,0,stream>>>(G2, W2f, P2, 64, 64);
  kFinal_kernel<<<1,256,0,stream>>>(P2, sum2, W2f, g2, b2, sc2, sh2, 64, 64, invM);

  fl12_kernel<<<BN,64,0,stream>>>(x, idxb, W1f, sc1, sh1, W2f, sc2, sh2, H2, catb);

  colsum_kernel<64,bf16><<<512,256,0,stream>>>(H2, Mrows, sum3);
  gramM_kernel<64><<<512,256,0,stream>>>(H2, Mrows, G3);
  kP_kernel<<<32,256,0,stream>>>(G3, W3f, P3, 64, 128);
  kFinal_kernel<<<1,256,0,stream>>>(P3, sum3, W3f, g3, b3, sc3, sh3, 64, 128, invM);

  stats4_kernel<<<512,512,0,stream>>>(H2, W3T, sc3, sh3, G4, sum4);
  kP_kernel<<<128,256,0,stream>>>(G4, W4f, P4, 128, 256);
  kFinal_kernel<<<1,256,0,stream>>>(P4, sum4, W4f, g4, b4, sc4, sh4, 128, 256, invM);

  fl34_kernel<<<Mrows/320,512,0,stream>>>(H2, W3T, sc3, sh3, W4T, sc4, sh4, catb);

  colsum_kernel<512,bf16><<<512,256,0,stream>>>(catb, BN, sum5);
  gramM_kernel<512><<<512,256,0,stream>>>(catb, BN, G5);
  kP_kernel<<<1024,256,0,stream>>>(G5, W5f, P5, 512, 512);
  kFinal_kernel<<<2,256,0,stream>>>(P5, sum5, W5f, g5, b5, sc5, sh5, 512, 512, invM5);
  l5_kernel<<<BN/64,512,0,stream>>>(catb, W5T, sc5, sh5, out);
}